// Round 12
// baseline (812.179 us; speedup 1.0000x reference)
//
#include <hip/hip_runtime.h>
#include <math.h>

#define BB   256
#define LL   100
#define CIN  38
#define COUT 38
#define DD   512
#define HH   8
#define EE   3
#define DFF  512
#define DHD  64
#define NTOK (BB*LL)     // 25600
#define WELEM (EE*DD*DD) // 786432 elements per weight family
#define QKVN 1536        // packed QKV width

typedef __attribute__((ext_vector_type(8))) short bf16x8;
typedef __attribute__((ext_vector_type(4))) float f32x4;

__device__ __forceinline__ unsigned short f2bf(float f) {
    unsigned int u = __float_as_uint(f);
    unsigned int r = (u + 0x7FFFu + ((u >> 16) & 1u)) >> 16;
    return (unsigned short)r;
}
__device__ __forceinline__ float bf2f(unsigned short s) {
    return __uint_as_float(((unsigned int)s) << 16);
}

__device__ __forceinline__ void gl2lds16(const unsigned short* g, unsigned short* l) {
    __builtin_amdgcn_global_load_lds(
        (const __attribute__((address_space(1))) void*)g,
        (__attribute__((address_space(3))) void*)l, 16, 0, 0);
}

// paired-row XOR swizzle: 16B-unit index for logical (row, chunk c in 0..3) of a [256][32]bf16 tile.
__device__ __forceinline__ int swz(int row, int c) {
    int rp = row >> 1;
    int ch = c + ((row & 1) << 2);
    return rp * 8 + (ch ^ (rp & 7));
}

// ---------------------------------------------------------------- PE table
__global__ __launch_bounds__(256) void pe_kernel(float* __restrict__ pe) {
    int idx = blockIdx.x * 256 + threadIdx.x;
    if (idx >= LL * DD) return;
    int l = idx / DD, d = idx % DD;
    float e = (float)(d & ~1) * (-9.210340371976184f / (float)DD);
    float ang = (float)l * expf(e);
    pe[idx] = (d & 1) ? cosf(ang) : sinf(ang);
}

// ------------------------------------------------- mask -> additive bias
__global__ void expand_mask_kernel(const unsigned char* __restrict__ mraw,
                                   float* __restrict__ mb) {
    int i = blockIdx.x * 256 + threadIdx.x;
    if (i >= LL * LL) return;
    unsigned char b0 = mraw[0], b1 = mraw[1], b2 = mraw[2], b3 = mraw[3];
    bool v;
    if (b0 == 1 && b1 == 1)                      v = mraw[i] != 0;
    else if (b0 == 1 && b1 == 0 && b2 == 0 && b3 == 0)
                                                 v = ((const int*)mraw)[i] != 0;
    else if (b0 == 0x80 && b1 == 0x3F)           v = ((const unsigned short*)mraw)[i] != 0;
    else if (b0 == 0 && b1 == 0x3C)              v = ((const unsigned short*)mraw)[i] != 0;
    else if (b0 == 0 && b1 == 0 && b2 == 0x80 && b3 == 0x3F)
                                                 v = ((const float*)mraw)[i] != 0.f;
    else                                         v = mraw[i] != 0;
    mb[i] = v ? 0.f : -1.0e30f;
}

// ------------------------------------------------- fp32 -> bf16 bulk convert
__global__ __launch_bounds__(256) void cvt_kernel(const float* __restrict__ in,
                                                  unsigned short* __restrict__ out,
                                                  int n4) {
    int i = blockIdx.x * 256 + threadIdx.x;
    if (i >= n4) return;
    float4 f = ((const float4*)in)[i];
    unsigned short o0 = f2bf(f.x), o1 = f2bf(f.y), o2 = f2bf(f.z), o3 = f2bf(f.w);
    unsigned long long packed = (unsigned long long)o0 | ((unsigned long long)o1 << 16)
                              | ((unsigned long long)o2 << 32) | ((unsigned long long)o3 << 48);
    ((unsigned long long*)out)[i] = packed;
}

// ------------------------------------------------- Wq/Wk/Wv -> packed [l][1536][512] bf16
__global__ __launch_bounds__(256) void cvt_pack(const float* __restrict__ in,
                                                unsigned short* __restrict__ out,
                                                int fam) {
    int i = blockIdx.x * 256 + threadIdx.x;      // over WELEM/4
    if (i >= WELEM / 4) return;
    int l = i >> 16;                              // / (DD*DD/4 = 65536)
    int j = i & 65535;
    float4 f = ((const float4*)in)[i];
    unsigned short o0 = f2bf(f.x), o1 = f2bf(f.y), o2 = f2bf(f.z), o3 = f2bf(f.w);
    unsigned long long packed = (unsigned long long)o0 | ((unsigned long long)o1 << 16)
                              | ((unsigned long long)o2 << 32) | ((unsigned long long)o3 << 48);
    ((unsigned long long*)out)[(size_t)l * (3 * 65536) + (size_t)fam * 65536 + j] = packed;
}

// ------------------------------------------------- bq/bk/bv -> packed [l][1536] fp32
__global__ __launch_bounds__(256) void pack_bias(const float* __restrict__ bq,
                                                 const float* __restrict__ bk,
                                                 const float* __restrict__ bv,
                                                 float* __restrict__ out) {
    int idx = blockIdx.x * 256 + threadIdx.x;    // EE*1536
    if (idx >= EE * QKVN) return;
    int l = idx / QKVN, r = idx % QKVN, f = r >> 9, d = r & 511;
    const float* src = (f == 0) ? bq : (f == 1) ? bk : bv;
    out[idx] = src[l * DD + d];
}

// ------------------------------------------------- proj weights -> bf16, padded [48][512]
__global__ __launch_bounds__(256) void proj_cvt(const float* __restrict__ in,
                                                unsigned short* __restrict__ outp) {
    int i = blockIdx.x * 256 + threadIdx.x;
    if (i >= 48 * DD / 4) return;
    if (i < COUT * DD / 4) {
        float4 f = ((const float4*)in)[i];
        unsigned short o0 = f2bf(f.x), o1 = f2bf(f.y), o2 = f2bf(f.z), o3 = f2bf(f.w);
        unsigned long long packed = (unsigned long long)o0 | ((unsigned long long)o1 << 16)
                                  | ((unsigned long long)o2 << 32) | ((unsigned long long)o3 << 48);
        ((unsigned long long*)outp)[i] = packed;
    } else {
        ((unsigned long long*)outp)[i] = 0ull;
    }
}

// ------------------------------------------------- emb_w [512][38*3] -> bf16 [512][128] (K-pad)
__global__ __launch_bounds__(256) void ewb_cvt(const float* __restrict__ ew,
                                               unsigned short* __restrict__ out) {
    int idx = blockIdx.x * 256 + threadIdx.x;    // 512*128
    if (idx >= DD * 128) return;
    int d = idx >> 7, k = idx & 127;
    out[idx] = (k < 114) ? f2bf(ew[d * 114 + k]) : (unsigned short)0;
}

// ------------------------------------------------- x -> ub[25600][128] bf16 (circular gather)
__global__ __launch_bounds__(256) void ub_build(const float* __restrict__ x,
                                               unsigned short* __restrict__ ub) {
    int idx = blockIdx.x * 256 + threadIdx.x;    // NTOK*128
    if (idx >= NTOK * 128) return;
    int n = idx >> 7, k = idx & 127;
    float v = 0.f;
    if (k < 114) {
        int c = k / 3, t = k - 3 * c;
        int l = n % LL, b = n / LL;
        int ls = l + t - 1;
        ls = (ls < 0) ? (LL - 1) : (ls >= LL ? ls - LL : ls);
        v = x[(size_t)(b * LL + ls) * CIN + c];
    }
    ub[idx] = f2bf(v);
}

// ------------------------------------------------- bf16 MFMA GEMM (128x128): embed only now
template<int EPI>
__global__ __launch_bounds__(256) void gemm_bf16(const unsigned short* __restrict__ A,
                                                 const unsigned short* __restrict__ W,
                                                 const float* __restrict__ bias,
                                                 const float* __restrict__ pe2,
                                                 unsigned short* __restrict__ C,
                                                 int M, int N, int K, int lda, int ldc,
                                                 int nbn) {
    __shared__ unsigned short As[128 * 32];
    __shared__ unsigned short Bs[128 * 32];
    const int tid  = threadIdx.x;
    const int tile = (blockIdx.x & 7) * ((int)gridDim.x >> 3) + (blockIdx.x >> 3);
    const int bn   = tile % nbn, bm = tile / nbn;
    const int w    = tid >> 6, lane = tid & 63;
    const int wr   = w >> 1,  wc   = w & 1;
    const int sRow = tid >> 2;
    const int sK   = (tid & 3) * 8;
    const unsigned short* Ag = A + (size_t)(bm * 128 + sRow) * lda + sK;
    const unsigned short* Wg = W + (size_t)(bn * 128 + sRow) * K + sK;
    unsigned short* AsD = As + tid * 8;
    unsigned short* BsD = Bs + tid * 8;
    const int fr = lane & 15, fq = lane >> 4;
    const int fo = fq * 8;

    f32x4 acc[4][4] = {};
    for (int k0 = 0; k0 < K; k0 += 32) {
        gl2lds16(Ag + k0, AsD);
        gl2lds16(Ag + k0 + (size_t)64 * lda, AsD + 64 * 32);
        gl2lds16(Wg + k0, BsD);
        gl2lds16(Wg + k0 + (size_t)64 * K, BsD + 64 * 32);
        __syncthreads();
        bf16x8 af[4], bfv[4];
        #pragma unroll
        for (int m = 0; m < 4; ++m)
            af[m] = *(const bf16x8*)(As + (wr * 64 + m * 16 + fr) * 32 + fo);
        #pragma unroll
        for (int n = 0; n < 4; ++n)
            bfv[n] = *(const bf16x8*)(Bs + (wc * 64 + n * 16 + fr) * 32 + fo);
        #pragma unroll
        for (int m = 0; m < 4; ++m)
            #pragma unroll
            for (int n = 0; n < 4; ++n)
                acc[m][n] = __builtin_amdgcn_mfma_f32_16x16x32_bf16(af[m], bfv[n], acc[m][n], 0, 0, 0);
        __syncthreads();
    }
    #pragma unroll
    for (int n = 0; n < 4; ++n) {
        int col = bn * 128 + wc * 64 + n * 16 + fr;
        float bv = (EPI != 2) ? bias[col] : 0.f;
        #pragma unroll
        for (int m = 0; m < 4; ++m) {
            #pragma unroll
            for (int j = 0; j < 4; ++j) {
                int row = bm * 128 + wr * 64 + m * 16 + fq * 4 + j;
                float v = acc[m][n][j] + bv;
                if (EPI == 1)
                    v = 0.5f * v * (1.f + erff(v * 0.70710678118654752f));
                if (EPI == 2)
                    v += pe2[(row % LL) * DD + col];
                C[(size_t)row * ldc + col] = f2bf(v);
            }
        }
    }
}

// ------------------------------------------------- pipelined 256x256 GEMM, K=512 fixed
// 2-slot ring (64 KB -> 2 blocks/CU). Stage t+2 into the computed slot AFTER all its reads
// (explicit lgkmcnt(0)+barrier). Boundary s_waitcnt vmcnt(4) (t+1 done, t+2's 4 in flight).
template<int EPI>
__global__ __launch_bounds__(512) void gemm_pipe(const unsigned short* __restrict__ A,
                                                 const unsigned short* __restrict__ W,
                                                 const float* __restrict__ bias,
                                                 unsigned short* __restrict__ C,
                                                 int ldc, int nbn) {
    __shared__ __align__(16) unsigned short lds[2 * 16384];   // 64 KB
    const int tid  = threadIdx.x;
    const int tile = ((int)blockIdx.x & 7) * ((int)gridDim.x >> 3) + ((int)blockIdx.x >> 3);
    const int bn   = tile % nbn, bm = tile / nbn;
    const int wid  = tid >> 6, lane = tid & 63;
    const int wr   = wid >> 2, wc = wid & 3;
    const int fr   = lane & 15, fq = lane >> 4;

    int rowS0, cS0, rowS1, cS1;
    { int u = tid;       int rp = u >> 3, q = u & 7, ch = q ^ (rp & 7); rowS0 = (rp << 1) + (ch >> 2); cS0 = ch & 3; }
    { int u = tid + 512; int rp = u >> 3, q = u & 7, ch = q ^ (rp & 7); rowS1 = (rp << 1) + (ch >> 2); cS1 = ch & 3; }
    const unsigned short* Ag0 = A + (size_t)(bm * 256 + rowS0) * 512 + cS0 * 8;
    const unsigned short* Ag1 = A + (size_t)(bm * 256 + rowS1) * 512 + cS1 * 8;
    const unsigned short* Wg0 = W + (size_t)(bn * 256 + rowS0) * 512 + cS0 * 8;
    const unsigned short* Wg1 = W + (size_t)(bn * 256 + rowS1) * 512 + cS1 * 8;
    unsigned short* dA0 = lds + tid * 8;   // issue1 +4096; B region +8192/+12288; slot stride 16384

    int aoff[8], boff[4];
    #pragma unroll
    for (int m = 0; m < 8; ++m) aoff[m] = swz(wr * 128 + m * 16 + fr, fq) * 8;
    #pragma unroll
    for (int n = 0; n < 4; ++n) boff[n] = 8192 + swz(wc * 64 + n * 16 + fr, fq) * 8;

    f32x4 acc[8][4] = {};

    // prologue: tile0 -> slot0, tile1 -> slot1 (4 loads each); wait tile0
    gl2lds16(Ag0,      dA0);
    gl2lds16(Ag1,      dA0 + 4096);
    gl2lds16(Wg0,      dA0 + 8192);
    gl2lds16(Wg1,      dA0 + 12288);
    gl2lds16(Ag0 + 32, dA0 + 16384);
    gl2lds16(Ag1 + 32, dA0 + 16384 + 4096);
    gl2lds16(Wg0 + 32, dA0 + 16384 + 8192);
    gl2lds16(Wg1 + 32, dA0 + 16384 + 12288);
    asm volatile("s_waitcnt vmcnt(4)" ::: "memory");
    __builtin_amdgcn_s_barrier();

    for (int t = 0; t < 16; ++t) {
        const int p = t & 1;
        const unsigned short* S = lds + p * 16384;
        unsigned short* D = dA0 + p * 16384;
        const int koff = (t + 2) * 32;
        bf16x8 bfv[4], af[4];
        #pragma unroll
        for (int n = 0; n < 4; ++n) bfv[n] = *(const bf16x8*)(S + boff[n]);
        #pragma unroll
        for (int m = 0; m < 4; ++m) af[m] = *(const bf16x8*)(S + aoff[m]);
        __builtin_amdgcn_s_barrier();
        __builtin_amdgcn_s_setprio(1);
        #pragma unroll
        for (int m = 0; m < 4; ++m)
            #pragma unroll
            for (int n = 0; n < 4; ++n)
                acc[m][n] = __builtin_amdgcn_mfma_f32_16x16x32_bf16(af[m], bfv[n], acc[m][n], 0, 0, 0);
        __builtin_amdgcn_s_setprio(0);
        __builtin_amdgcn_s_barrier();
        #pragma unroll
        for (int m = 0; m < 4; ++m) af[m] = *(const bf16x8*)(S + aoff[4 + m]);
        asm volatile("s_waitcnt lgkmcnt(0)" ::: "memory");   // this wave's slot-p reads done
        __builtin_amdgcn_s_barrier();                        // ALL waves done reading slot p
        __builtin_amdgcn_s_setprio(1);
        #pragma unroll
        for (int m = 0; m < 4; ++m)
            #pragma unroll
            for (int n = 0; n < 4; ++n)
                acc[4 + m][n] = __builtin_amdgcn_mfma_f32_16x16x32_bf16(af[m], bfv[n], acc[4 + m][n], 0, 0, 0);
        __builtin_amdgcn_s_setprio(0);
        if (t < 14) {
            gl2lds16(Ag0 + koff, D);
            gl2lds16(Ag1 + koff, D + 4096);
            gl2lds16(Wg0 + koff, D + 8192);
            gl2lds16(Wg1 + koff, D + 12288);
            asm volatile("s_waitcnt vmcnt(4)" ::: "memory"); // t+1 complete, t+2 in flight
        } else if (t == 14) {
            asm volatile("s_waitcnt vmcnt(0)" ::: "memory"); // last tile (15) complete
        }
        __builtin_amdgcn_s_barrier();
    }

    #pragma unroll
    for (int n = 0; n < 4; ++n) {
        int col = bn * 256 + wc * 64 + n * 16 + fr;
        float bv = bias[col];
        #pragma unroll
        for (int m = 0; m < 8; ++m) {
            #pragma unroll
            for (int j = 0; j < 4; ++j) {
                int row = bm * 256 + wr * 128 + m * 16 + fq * 4 + j;
                float v = acc[m][n][j] + bv;
                if (EPI == 1)
                    v = 0.5f * v * (1.f + erff(v * 0.70710678118654752f));
                C[(size_t)row * ldc + col] = f2bf(v);
            }
        }
    }
}

// ------------------------------------------------- fused GEMM + residual + LayerNorm
__global__ __launch_bounds__(512) void gemm_ln(const unsigned short* __restrict__ A,
                                               const unsigned short* __restrict__ W,
                                               const float* __restrict__ bias,
                                               unsigned short* __restrict__ h,
                                               const float* __restrict__ sc,
                                               const float* __restrict__ bi,
                                               int lda) {
    __shared__ unsigned short As[64 * 32];
    __shared__ unsigned short Bs[512 * 32];
    __shared__ float lnred[64][4];
    const int tid = threadIdx.x;
    const int w = tid >> 6, lane = tid & 63;
    const int wm = w >> 1, wn = w & 1;
    const int fr = lane & 15, fq = lane >> 4;
    const int row0 = blockIdx.x * 64;

    const unsigned short* Ag = A + (size_t)(row0 + (tid >> 2)) * lda + (tid & 3) * 8;
    const unsigned short* Wg = W + (size_t)(tid >> 2) * DD + (tid & 3) * 8;
    unsigned short* AsD = As + tid * 8;
    unsigned short* BsD = Bs + tid * 8;

    f32x4 acc[16] = {};
    for (int k0 = 0; k0 < DD; k0 += 32) {
        if (tid < 256) gl2lds16(Ag + k0, AsD);
        #pragma unroll
        for (int i = 0; i < 4; ++i)
            gl2lds16(Wg + k0 + (size_t)(i * 128) * DD, BsD + i * 4096);
        __syncthreads();
        bf16x8 af = *(const bf16x8*)(As + (wm * 16 + fr) * 32 + fq * 8);
        #pragma unroll
        for (int n = 0; n < 16; ++n) {
            bf16x8 bfv = *(const bf16x8*)(Bs + (wn * 256 + n * 16 + fr) * 32 + fq * 8);
            acc[n] = __builtin_amdgcn_mfma_f32_16x16x32_bf16(af, bfv, acc[n], 0, 0, 0);
        }
        __syncthreads();
    }
    const int rbase = wm * 16 + fq * 4;
    float s[4] = {0.f, 0.f, 0.f, 0.f}, ssq[4] = {0.f, 0.f, 0.f, 0.f};
    #pragma unroll
    for (int n = 0; n < 16; ++n) {
        int col = wn * 256 + n * 16 + fr;
        float bv = bias[col];
        #pragma unroll
        for (int j = 0; j < 4; ++j) {
            float v = acc[n][j] + bv + bf2f(h[(size_t)(row0 + rbase + j) * DD + col]);
            acc[n][j] = v;
            s[j] += v; ssq[j] += v * v;
        }
    }
    #pragma unroll
    for (int j = 0; j < 4; ++j) {
        #pragma unroll
        for (int off = 8; off; off >>= 1) {
            s[j]   += __shfl_xor(s[j], off, 64);
            ssq[j] += __shfl_xor(ssq[j], off, 64);
        }
    }
    if (fr == 0) {
        #pragma unroll
        for (int j = 0; j < 4; ++j) {
            lnred[rbase + j][wn * 2]     = s[j];
            lnred[rbase + j][wn * 2 + 1] = ssq[j];
        }
    }
    __syncthreads();
    float meanj[4], rstdj[4];
    #pragma unroll
    for (int j = 0; j < 4; ++j) {
        float st  = lnred[rbase + j][0] + lnred[rbase + j][2];
        float sst = lnred[rbase + j][1] + lnred[rbase + j][3];
        float mean = st * (1.f / (float)DD);
        float var  = sst * (1.f / (float)DD) - mean * mean;
        meanj[j] = mean;
        rstdj[j] = 1.f / sqrtf(var + 1e-5f);
    }
    #pragma unroll
    for (int n = 0; n < 16; ++n) {
        int col = wn * 256 + n * 16 + fr;
        float scv = sc[col], biv = bi[col];
        #pragma unroll
        for (int j = 0; j < 4; ++j)
            h[(size_t)(row0 + rbase + j) * DD + col] =
                f2bf((acc[n][j] - meanj[j]) * rstdj[j] * scv + biv);
    }
}

// ------------------------------------------------- MFMA attention on packed qkv[n][1536]
// Q no longer staged in LDS (read per-band from global, L2-hot): LDS 47104 B -> 3 blocks/CU.
__global__ __launch_bounds__(256) void attn_mfma(unsigned short* __restrict__ qkv,
                                                 const float* __restrict__ mbias) {
    __shared__ __align__(16) unsigned char lds[47104];
    const int KOFF = 0, VOFF = 14336, POFF = 30720;
    const int tid = threadIdx.x, wv = tid >> 6, lane = tid & 63;
    const int fr = lane & 15, fq = lane >> 4;
    const int b = blockIdx.x >> 3, hh = blockIdx.x & 7;
    unsigned short* qg = qkv + (size_t)(b * LL) * QKVN + hh * DHD;
    const unsigned short* kg = qg + 512;
    const unsigned short* vg = qg + 1024;

    for (int idx = tid; idx < 800; idx += 256) {
        int s = idx >> 3, c = idx & 7;
        uint4 kv = *(const uint4*)(kg + (size_t)s * QKVN + c * 8);
        uint4 vv = *(const uint4*)(vg + (size_t)s * QKVN + c * 8);
        int sw = (s & 7) << 4;
        *(uint4*)(lds + KOFF + s * 128 + ((c * 16) ^ sw)) = kv;
        unsigned int vs[4] = {vv.x, vv.y, vv.z, vv.w};
        #pragma unroll
        for (int e = 0; e < 4; ++e) {
            int d0 = c * 8 + e * 2, d1 = d0 + 1;
            *(unsigned short*)(lds + VOFF + d0 * 256 + ((s * 2) ^ ((d0 & 7) << 4))) = (unsigned short)(vs[e] & 0xFFFFu);
            *(unsigned short*)(lds + VOFF + d1 * 256 + ((s * 2) ^ ((d1 & 7) << 4))) = (unsigned short)(vs[e] >> 16);
        }
    }
    // zero pad rows 100..111 of Ks
    for (int idx = tid; idx < 96; idx += 256) {
        int r = 100 + (idx >> 3), c = idx & 7;
        *(uint4*)(lds + KOFF + r * 128 + ((c * 16) ^ ((r & 7) << 4))) = uint4{0u, 0u, 0u, 0u};
    }
    // zero pad cols 100..127 of Vt
    for (int idx = tid; idx < 896; idx += 256) {
        int d = idx / 14, s = 100 + 2 * (idx % 14);
        *(unsigned int*)(lds + VOFF + d * 256 + ((s * 2) ^ ((d & 7) << 4))) = 0u;
    }
    __syncthreads();

    const int pbase = POFF + wv * 4096;
    for (int bd = wv; bd < 7; bd += 4) {
        // Q fragments straight from global (row ownership per wave is disjoint; rows>=100 garbage, discarded)
        const unsigned short* qp = qg + (size_t)(bd * 16 + fr) * QKVN;
        bf16x8 aq0 = *(const bf16x8*)(qp + fq * 8);
        bf16x8 aq1 = *(const bf16x8*)(qp + 32 + fq * 8);
        f32x4 sv[7];
        #pragma unroll
        for (int ct = 0; ct < 7; ++ct) {
            int row = ct * 16 + fr, sw = (row & 7) << 4;
            bf16x8 bk0 = *(const bf16x8*)(lds + KOFF + row * 128 + ((fq * 16) ^ sw));
            bf16x8 bk1 = *(const bf16x8*)(lds + KOFF + row * 128 + ((64 + fq * 16) ^ sw));
            f32x4 a = {0.f, 0.f, 0.f, 0.f};
            a = __builtin_amdgcn_mfma_f32_16x16x32_bf16(aq0, bk0, a, 0, 0, 0);
            a = __builtin_amdgcn_mfma_f32_16x16x32_bf16(aq1, bk1, a, 0, 0, 0);
            sv[ct] = a;
        }
        const int rg0 = bd * 16 + fq * 4;
        #pragma unroll
        for (int ct = 0; ct < 7; ++ct) {
            int col = ct * 16 + fr;
            #pragma unroll
            for (int j = 0; j < 4; ++j) {
                int rg = rg0 + j;
                float bias = (rg < LL && col < LL) ? mbias[rg * LL + col] : -1.0e30f;
                sv[ct][j] = sv[ct][j] * 0.125f + bias;
            }
        }
        float inv[4];
        #pragma unroll
        for (int j = 0; j < 4; ++j) {
            float mx = sv[0][j];
            #pragma unroll
            for (int ct = 1; ct < 7; ++ct) mx = fmaxf(mx, sv[ct][j]);
            #pragma unroll
            for (int off = 8; off; off >>= 1) mx = fmaxf(mx, __shfl_xor(mx, off, 64));
            float sum = 0.f;
            #pragma unroll
            for (int ct = 0; ct < 7; ++ct) {
                float p = __expf(sv[ct][j] - mx);
                sv[ct][j] = p; sum += p;
            }
            #pragma unroll
            for (int off = 8; off; off >>= 1) sum += __shfl_xor(sum, off, 64);
            inv[j] = 1.f / sum;
        }
        asm volatile("s_waitcnt lgkmcnt(0)" ::: "memory");
        #pragma unroll
        for (int j = 0; j < 4; ++j) {
            int pr = fq * 4 + j, sw = (pr & 7) << 4;
            #pragma unroll
            for (int ct = 0; ct < 7; ++ct)
                *(unsigned short*)(lds + pbase + pr * 256 + ((ct * 32 + fr * 2) ^ sw)) = f2bf(sv[ct][j] * inv[j]);
            *(unsigned short*)(lds + pbase + pr * 256 + ((224 + fr * 2) ^ sw)) = 0;
        }
        asm volatile("s_waitcnt lgkmcnt(0)" ::: "memory");
        f32x4 oacc[4] = {};
        #pragma unroll
        for (int kt = 0; kt < 4; ++kt) {
            bf16x8 ap = *(const bf16x8*)(lds + pbase + fr * 256 + ((kt * 64 + fq * 16) ^ ((fr & 7) << 4)));
            #pragma unroll
            for (int n = 0; n < 4; ++n) {
                int d = n * 16 + fr, sw = (d & 7) << 4;
                bf16x8 bv = *(const bf16x8*)(lds + VOFF + d * 256 + ((kt * 64 + fq * 16) ^ sw));
                oacc[n] = __builtin_amdgcn_mfma_f32_16x16x32_bf16(ap, bv, oacc[n], 0, 0, 0);
            }
        }
        #pragma unroll
        for (int j = 0; j < 4; ++j) {
            int rg = rg0 + j;
            if (rg < LL) {
                #pragma unroll
                for (int n = 0; n < 4; ++n)
                    qg[(size_t)rg * QKVN + n * 16 + fr] = f2bf(oacc[n][j]);
            }
        }
    }
}

// ------------------------------------------------- residual + layernorm (bf16 in/out)
template<bool RES>
__global__ __launch_bounds__(256) void add_ln(unsigned short* __restrict__ h,
                                              const unsigned short* __restrict__ res,
                                              const float* __restrict__ sc,
                                              const float* __restrict__ bi) {
    int n = blockIdx.x, tid = threadIdx.x;
    size_t base = (size_t)n * DD;
    float x0 = bf2f(h[base + tid]), x1 = bf2f(h[base + 256 + tid]);
    if (RES) { x0 += bf2f(res[base + tid]); x1 += bf2f(res[base + 256 + tid]); }
    float s = x0 + x1, ss = x0 * x0 + x1 * x1;
    #pragma unroll
    for (int off = 32; off; off >>= 1) {
        s  += __shfl_xor(s, off, 64);
        ss += __shfl_xor(ss, off, 64);
    }
    __shared__ float rs[4], rss[4];
    int wv = tid >> 6, lane = tid & 63;
    if (lane == 0) { rs[wv] = s; rss[wv] = ss; }
    __syncthreads();
    s  = rs[0] + rs[1] + rs[2] + rs[3];
    ss = rss[0] + rss[1] + rss[2] + rss[3];
    float mean = s * (1.f / (float)DD);
    float var  = ss * (1.f / (float)DD) - mean * mean;
    float rstd = 1.f / sqrtf(var + 1e-5f);
    h[base + tid]       = f2bf((x0 - mean) * rstd * sc[tid]       + bi[tid]);
    h[base + 256 + tid] = f2bf((x1 - mean) * rstd * sc[256 + tid] + bi[256 + tid]);
}

// ------------------------------------------------- final projection via MFMA
__global__ __launch_bounds__(256) void proj_mfma(const unsigned short* __restrict__ hn,
                                                 const unsigned short* __restrict__ pwb,
                                                 const float* __restrict__ pb,
                                                 float* __restrict__ out) {
    const int tid = threadIdx.x, wv = tid >> 6, lane = tid & 63;
    const int fr = lane & 15, fq = lane >> 4;
    const int row0 = blockIdx.x * 64 + wv * 16;
    const unsigned short* aRow = hn + (size_t)(row0 + fr) * DD + fq * 8;
    f32x4 acc[3] = {};
    #pragma unroll 4
    for (int kt = 0; kt < 16; ++kt) {
        bf16x8 af = *(const bf16x8*)(aRow + kt * 32);
        #pragma unroll
        for (int n = 0; n < 3; ++n) {
            bf16x8 bfv = *(const bf16x8*)(pwb + (size_t)(n * 16 + fr) * DD + kt * 32 + fq * 8);
            acc[n] = __builtin_amdgcn_mfma_f32_16x16x32_bf16(af, bfv, acc[n], 0, 0, 0);
        }
    }
    #pragma unroll
    for (int n = 0; n < 3; ++n) {
        int col = n * 16 + fr;
        if (col < COUT) {
            float bias = pb[col];
            #pragma unroll
            for (int j = 0; j < 4; ++j) {
                int r = row0 + fq * 4 + j;
                out[(size_t)r * COUT + col] = acc[n][j] + bias;
            }
        }
    }
}

__global__ void sentinel_kernel(float* out, int n) {
    int i = blockIdx.x * 256 + threadIdx.x;
    if (i < n) out[i] = 1.0e4f;
}

extern "C" void kernel_launch(void* const* d_in, const int* in_sizes, int n_in,
                              void* d_out, int out_size, void* d_ws, size_t ws_size,
                              hipStream_t stream) {
    const float* x    = (const float*)d_in[0];
    const float* ew   = (const float*)d_in[1];
    const float* Wq   = (const float*)d_in[2];
    const float* bq   = (const float*)d_in[3];
    const float* Wk   = (const float*)d_in[4];
    const float* bk   = (const float*)d_in[5];
    const float* Wv   = (const float*)d_in[6];
    const float* bv   = (const float*)d_in[7];
    const float* Wo   = (const float*)d_in[8];
    const float* bo   = (const float*)d_in[9];
    const float* c1w  = (const float*)d_in[10];
    const float* c1b  = (const float*)d_in[11];
    const float* c2w  = (const float*)d_in[12];
    const float* c2b  = (const float*)d_in[13];
    const float* ln1s = (const float*)d_in[14];
    const float* ln1b = (const float*)d_in[15];
    const float* ln2s = (const float*)d_in[16];
    const float* ln2b = (const float*)d_in[17];
    const float* lnfs = (const float*)d_in[18];
    const float* lnfb = (const float*)d_in[19];
    const float* pw   = (const float*)d_in[20];
    const float* pb   = (const float*)d_in[21];
    const unsigned char* mraw = (const unsigned char*)d_in[22];

    const size_t NB   = (size_t)NTOK * DD;       // 13,107,200
    const size_t PWB  = 48 * DD;
    const size_t EWB  = (size_t)DD * 128;
    const size_t UB   = (size_t)NTOK * 128;
    const size_t need = (4 * NB + 6 * (size_t)WELEM + PWB + EWB + UB) * 2
                      + ((size_t)EE * QKVN + (size_t)LL * DD + (size_t)LL * LL) * 4;
    if (ws_size < need) {
        sentinel_kernel<<<(out_size + 255) / 256, 256, 0, stream>>>((float*)d_out, out_size);
        return;
    }
    unsigned short* h    = (unsigned short*)d_ws;
    unsigned short* qkv  = h + NB;               // 3*NB (QKV out; also FFN-mid scratch)
    unsigned short* wqkv = qkv + 3 * NB;         // 3*WELEM packed
    unsigned short* wo   = wqkv + 3 * WELEM;
    unsigned short* w1   = wo + WELEM;
    unsigned short* w2   = w1 + WELEM;
    unsigned short* pwb  = w2 + WELEM;
    unsigned short* ewb  = pwb + PWB;
    unsigned short* ub   = ewb + EWB;
    float* bqkv = (float*)(ub + UB);
    float* pe   = bqkv + EE * QKVN;
    float* mb   = pe + LL * DD;

    pe_kernel<<<(LL * DD + 255) / 256, 256, 0, stream>>>(pe);
    expand_mask_kernel<<<(LL * LL + 255) / 256, 256, 0, stream>>>(mraw, mb);
    const int cg = WELEM / 4 / 256;   // 768
    cvt_pack<<<cg, 256, 0, stream>>>(Wq, wqkv, 0);
    cvt_pack<<<cg, 256, 0, stream>>>(Wk, wqkv, 1);
    cvt_pack<<<cg, 256, 0, stream>>>(Wv, wqkv, 2);
    pack_bias<<<(EE * QKVN + 255) / 256, 256, 0, stream>>>(bq, bk, bv, bqkv);
    cvt_kernel<<<cg, 256, 0, stream>>>(Wo,  wo, WELEM / 4);
    cvt_kernel<<<cg, 256, 0, stream>>>(c1w, w1, WELEM / 4);
    cvt_kernel<<<cg, 256, 0, stream>>>(c2w, w2, WELEM / 4);
    proj_cvt<<<(48 * DD / 4 + 255) / 256, 256, 0, stream>>>(pw, pwb);
    ewb_cvt<<<(DD * 128 + 255) / 256, 256, 0, stream>>>(ew, ewb);
    ub_build<<<(NTOK * 128 + 255) / 256, 256, 0, stream>>>(x, ub);

    // embed as MFMA GEMM: h = ub @ ewb^T + PE  (128^2 kernel, K=128)
    gemm_bf16<2><<<800, 256, 0, stream>>>(ub, ewb, nullptr, pe, h, NTOK, DD, 128, 128, DD, 4);

    const int gl = NTOK / 64;                    // 400 blocks for fused gemm_ln
    for (int l = 0; l < EE; ++l) {
        const size_t wofs = (size_t)l * DD * DD;
        const size_t bof  = (size_t)l * DD;
        // QKV: pipelined 256^2, 600 blocks (T1-chunked), 2-slot ring
        gemm_pipe<0><<<600, 512, 0, stream>>>(h, wqkv + (size_t)l * 3 * DD * DD,
                                              bqkv + l * QKVN, qkv, QKVN, 6);
        attn_mfma<<<BB * HH, 256, 0, stream>>>(qkv, mb);
        // o-proj + residual + LN1
        gemm_ln<<<gl, 512, 0, stream>>>(qkv, wo + wofs, bo + bof, h, ln1s + bof, ln1b + bof, QKVN);
        // ffn1 + GELU: pipelined 256^2, 200 blocks
        gemm_pipe<1><<<200, 512, 0, stream>>>(h, w1 + wofs, c1b + bof, qkv, DFF, 2);
        // ffn2 + residual + LN2
        gemm_ln<<<gl, 512, 0, stream>>>(qkv, w2 + wofs, c2b + bof, h, ln2s + bof, ln2b + bof, DFF);
    }
    add_ln<false><<<NTOK, 256, 0, stream>>>(h, nullptr, lnfs, lnfb);
    proj_mfma<<<NTOK / 64, 256, 0, stream>>>(h, pwb, pb, (float*)d_out);
}

// Round 13
// 760.024 us; speedup vs baseline: 1.0686x; 1.0686x over previous
//
#include <hip/hip_runtime.h>
#include <math.h>

#define BB   256
#define LL   100
#define CIN  38
#define COUT 38
#define DD   512
#define HH   8
#define EE   3
#define DFF  512
#define DHD  64
#define NTOK (BB*LL)     // 25600
#define WELEM (EE*DD*DD) // 786432 elements per weight family
#define QKVN 1536        // packed QKV width

typedef __attribute__((ext_vector_type(8))) short bf16x8;
typedef __attribute__((ext_vector_type(4))) float f32x4;

__device__ __forceinline__ unsigned short f2bf(float f) {
    unsigned int u = __float_as_uint(f);
    unsigned int r = (u + 0x7FFFu + ((u >> 16) & 1u)) >> 16;
    return (unsigned short)r;
}
__device__ __forceinline__ float bf2f(unsigned short s) {
    return __uint_as_float(((unsigned int)s) << 16);
}

__device__ __forceinline__ void gl2lds16(const unsigned short* g, unsigned short* l) {
    __builtin_amdgcn_global_load_lds(
        (const __attribute__((address_space(1))) void*)g,
        (__attribute__((address_space(3))) void*)l, 16, 0, 0);
}

// paired-row XOR swizzle: 16B-unit index for logical (row, chunk c in 0..3) of a [256][32]bf16 tile.
__device__ __forceinline__ int swz(int row, int c) {
    int rp = row >> 1;
    int ch = c + ((row & 1) << 2);
    return rp * 8 + (ch ^ (rp & 7));
}

// ---------------------------------------------------------------- PE table
__global__ __launch_bounds__(256) void pe_kernel(float* __restrict__ pe) {
    int idx = blockIdx.x * 256 + threadIdx.x;
    if (idx >= LL * DD) return;
    int l = idx / DD, d = idx % DD;
    float e = (float)(d & ~1) * (-9.210340371976184f / (float)DD);
    float ang = (float)l * expf(e);
    pe[idx] = (d & 1) ? cosf(ang) : sinf(ang);
}

// ------------------------------------------------- mask -> additive bias
__global__ void expand_mask_kernel(const unsigned char* __restrict__ mraw,
                                   float* __restrict__ mb) {
    int i = blockIdx.x * 256 + threadIdx.x;
    if (i >= LL * LL) return;
    unsigned char b0 = mraw[0], b1 = mraw[1], b2 = mraw[2], b3 = mraw[3];
    bool v;
    if (b0 == 1 && b1 == 1)                      v = mraw[i] != 0;
    else if (b0 == 1 && b1 == 0 && b2 == 0 && b3 == 0)
                                                 v = ((const int*)mraw)[i] != 0;
    else if (b0 == 0x80 && b1 == 0x3F)           v = ((const unsigned short*)mraw)[i] != 0;
    else if (b0 == 0 && b1 == 0x3C)              v = ((const unsigned short*)mraw)[i] != 0;
    else if (b0 == 0 && b1 == 0 && b2 == 0x80 && b3 == 0x3F)
                                                 v = ((const float*)mraw)[i] != 0.f;
    else                                         v = mraw[i] != 0;
    mb[i] = v ? 0.f : -1.0e30f;
}

// ------------------------------------------------- fp32 -> bf16 bulk convert
__global__ __launch_bounds__(256) void cvt_kernel(const float* __restrict__ in,
                                                  unsigned short* __restrict__ out,
                                                  int n4) {
    int i = blockIdx.x * 256 + threadIdx.x;
    if (i >= n4) return;
    float4 f = ((const float4*)in)[i];
    unsigned short o0 = f2bf(f.x), o1 = f2bf(f.y), o2 = f2bf(f.z), o3 = f2bf(f.w);
    unsigned long long packed = (unsigned long long)o0 | ((unsigned long long)o1 << 16)
                              | ((unsigned long long)o2 << 32) | ((unsigned long long)o3 << 48);
    ((unsigned long long*)out)[i] = packed;
}

// ------------------------------------------------- Wq/Wk/Wv -> packed [l][1536][512] bf16
__global__ __launch_bounds__(256) void cvt_pack(const float* __restrict__ in,
                                                unsigned short* __restrict__ out,
                                                int fam) {
    int i = blockIdx.x * 256 + threadIdx.x;      // over WELEM/4
    if (i >= WELEM / 4) return;
    int l = i >> 16;                              // / (DD*DD/4 = 65536)
    int j = i & 65535;
    float4 f = ((const float4*)in)[i];
    unsigned short o0 = f2bf(f.x), o1 = f2bf(f.y), o2 = f2bf(f.z), o3 = f2bf(f.w);
    unsigned long long packed = (unsigned long long)o0 | ((unsigned long long)o1 << 16)
                              | ((unsigned long long)o2 << 32) | ((unsigned long long)o3 << 48);
    ((unsigned long long*)out)[(size_t)l * (3 * 65536) + (size_t)fam * 65536 + j] = packed;
}

// ------------------------------------------------- bq/bk/bv -> packed [l][1536] fp32
__global__ __launch_bounds__(256) void pack_bias(const float* __restrict__ bq,
                                                 const float* __restrict__ bk,
                                                 const float* __restrict__ bv,
                                                 float* __restrict__ out) {
    int idx = blockIdx.x * 256 + threadIdx.x;    // EE*1536
    if (idx >= EE * QKVN) return;
    int l = idx / QKVN, r = idx % QKVN, f = r >> 9, d = r & 511;
    const float* src = (f == 0) ? bq : (f == 1) ? bk : bv;
    out[idx] = src[l * DD + d];
}

// ------------------------------------------------- proj weights -> bf16, padded [48][512]
__global__ __launch_bounds__(256) void proj_cvt(const float* __restrict__ in,
                                                unsigned short* __restrict__ outp) {
    int i = blockIdx.x * 256 + threadIdx.x;
    if (i >= 48 * DD / 4) return;
    if (i < COUT * DD / 4) {
        float4 f = ((const float4*)in)[i];
        unsigned short o0 = f2bf(f.x), o1 = f2bf(f.y), o2 = f2bf(f.z), o3 = f2bf(f.w);
        unsigned long long packed = (unsigned long long)o0 | ((unsigned long long)o1 << 16)
                                  | ((unsigned long long)o2 << 32) | ((unsigned long long)o3 << 48);
        ((unsigned long long*)outp)[i] = packed;
    } else {
        ((unsigned long long*)outp)[i] = 0ull;
    }
}

// ------------------------------------------------- emb_w [512][38*3] -> bf16 [512][128] (K-pad)
__global__ __launch_bounds__(256) void ewb_cvt(const float* __restrict__ ew,
                                               unsigned short* __restrict__ out) {
    int idx = blockIdx.x * 256 + threadIdx.x;    // 512*128
    if (idx >= DD * 128) return;
    int d = idx >> 7, k = idx & 127;
    out[idx] = (k < 114) ? f2bf(ew[d * 114 + k]) : (unsigned short)0;
}

// ------------------------------------------------- x -> ub[25600][128] bf16 (circular gather)
__global__ __launch_bounds__(256) void ub_build(const float* __restrict__ x,
                                               unsigned short* __restrict__ ub) {
    int idx = blockIdx.x * 256 + threadIdx.x;    // NTOK*128
    if (idx >= NTOK * 128) return;
    int n = idx >> 7, k = idx & 127;
    float v = 0.f;
    if (k < 114) {
        int c = k / 3, t = k - 3 * c;
        int l = n % LL, b = n / LL;
        int ls = l + t - 1;
        ls = (ls < 0) ? (LL - 1) : (ls >= LL ? ls - LL : ls);
        v = x[(size_t)(b * LL + ls) * CIN + c];
    }
    ub[idx] = f2bf(v);
}

// ------------------------------------------------- bf16 MFMA GEMM (128x128), T1 1-D swizzled grid
// EPI: 0 = +bias, 1 = +bias+GELU, 2 = +pe[(row%LL)][col]
template<int EPI>
__global__ __launch_bounds__(256) void gemm_bf16(const unsigned short* __restrict__ A,
                                                 const unsigned short* __restrict__ W,
                                                 const float* __restrict__ bias,
                                                 const float* __restrict__ pe2,
                                                 unsigned short* __restrict__ C,
                                                 int M, int N, int K, int lda, int ldc,
                                                 int nbn) {
    __shared__ unsigned short As[128 * 32];
    __shared__ unsigned short Bs[128 * 32];
    const int tid  = threadIdx.x;
    const int tile = (blockIdx.x & 7) * ((int)gridDim.x >> 3) + (blockIdx.x >> 3);
    const int bn   = tile % nbn, bm = tile / nbn;
    const int w    = tid >> 6, lane = tid & 63;
    const int wr   = w >> 1,  wc   = w & 1;
    const int sRow = tid >> 2;
    const int sK   = (tid & 3) * 8;
    const unsigned short* Ag = A + (size_t)(bm * 128 + sRow) * lda + sK;
    const unsigned short* Wg = W + (size_t)(bn * 128 + sRow) * K + sK;
    unsigned short* AsD = As + tid * 8;
    unsigned short* BsD = Bs + tid * 8;
    const int fr = lane & 15, fq = lane >> 4;
    const int fo = fq * 8;

    f32x4 acc[4][4] = {};
    for (int k0 = 0; k0 < K; k0 += 32) {
        gl2lds16(Ag + k0, AsD);
        gl2lds16(Ag + k0 + (size_t)64 * lda, AsD + 64 * 32);
        gl2lds16(Wg + k0, BsD);
        gl2lds16(Wg + k0 + (size_t)64 * K, BsD + 64 * 32);
        __syncthreads();
        bf16x8 af[4], bfv[4];
        #pragma unroll
        for (int m = 0; m < 4; ++m)
            af[m] = *(const bf16x8*)(As + (wr * 64 + m * 16 + fr) * 32 + fo);
        #pragma unroll
        for (int n = 0; n < 4; ++n)
            bfv[n] = *(const bf16x8*)(Bs + (wc * 64 + n * 16 + fr) * 32 + fo);
        #pragma unroll
        for (int m = 0; m < 4; ++m)
            #pragma unroll
            for (int n = 0; n < 4; ++n)
                acc[m][n] = __builtin_amdgcn_mfma_f32_16x16x32_bf16(af[m], bfv[n], acc[m][n], 0, 0, 0);
        __syncthreads();
    }
    #pragma unroll
    for (int n = 0; n < 4; ++n) {
        int col = bn * 128 + wc * 64 + n * 16 + fr;
        float bv = (EPI != 2) ? bias[col] : 0.f;
        #pragma unroll
        for (int m = 0; m < 4; ++m) {
            #pragma unroll
            for (int j = 0; j < 4; ++j) {
                int row = bm * 128 + wr * 64 + m * 16 + fq * 4 + j;
                float v = acc[m][n][j] + bv;
                if (EPI == 1)
                    v = 0.5f * v * (1.f + erff(v * 0.70710678118654752f));
                if (EPI == 2)
                    v += pe2[(row % LL) * DD + col];
                C[(size_t)row * ldc + col] = f2bf(v);
            }
        }
    }
}

// ------------------------------------------------- pipelined 256x256 GEMM, K=512 fixed (r11 best)
// T2 swizzled LDS + counted vmcnt (3-slot ring, 2 phases/K-tile) + T5 setprio + T1 grid.
template<int EPI>
__global__ __launch_bounds__(512) void gemm_pipe(const unsigned short* __restrict__ A,
                                                 const unsigned short* __restrict__ W,
                                                 const float* __restrict__ bias,
                                                 unsigned short* __restrict__ C,
                                                 int ldc, int nbn) {
    __shared__ __align__(16) unsigned short lds[3 * 16384];
    const int tid  = threadIdx.x;
    const int tile = ((int)blockIdx.x & 7) * ((int)gridDim.x >> 3) + ((int)blockIdx.x >> 3);
    const int bn   = tile % nbn, bm = tile / nbn;
    const int wid  = tid >> 6, lane = tid & 63;
    const int wr   = wid >> 2, wc = wid & 3;
    const int fr   = lane & 15, fq = lane >> 4;

    int rowS0, cS0, rowS1, cS1;
    { int u = tid;       int rp = u >> 3, q = u & 7, ch = q ^ (rp & 7); rowS0 = (rp << 1) + (ch >> 2); cS0 = ch & 3; }
    { int u = tid + 512; int rp = u >> 3, q = u & 7, ch = q ^ (rp & 7); rowS1 = (rp << 1) + (ch >> 2); cS1 = ch & 3; }
    const unsigned short* Ag0 = A + (size_t)(bm * 256 + rowS0) * 512 + cS0 * 8;
    const unsigned short* Ag1 = A + (size_t)(bm * 256 + rowS1) * 512 + cS1 * 8;
    const unsigned short* Wg0 = W + (size_t)(bn * 256 + rowS0) * 512 + cS0 * 8;
    const unsigned short* Wg1 = W + (size_t)(bn * 256 + rowS1) * 512 + cS1 * 8;
    unsigned short* dA0 = lds + tid * 8;

    int aoff[8], boff[4];
    #pragma unroll
    for (int m = 0; m < 8; ++m) aoff[m] = swz(wr * 128 + m * 16 + fr, fq) * 8;
    #pragma unroll
    for (int n = 0; n < 4; ++n) boff[n] = 8192 + swz(wc * 64 + n * 16 + fr, fq) * 8;

    f32x4 acc[8][4] = {};

    gl2lds16(Ag0,      dA0);
    gl2lds16(Ag1,      dA0 + 4096);
    gl2lds16(Wg0,      dA0 + 8192);
    gl2lds16(Wg1,      dA0 + 12288);
    gl2lds16(Ag0 + 32, dA0 + 16384);
    gl2lds16(Ag1 + 32, dA0 + 16384 + 4096);
    gl2lds16(Wg0 + 32, dA0 + 16384 + 8192);
    gl2lds16(Wg1 + 32, dA0 + 16384 + 12288);
    asm volatile("s_waitcnt vmcnt(4)" ::: "memory");
    __builtin_amdgcn_s_barrier();

    int st = 0;
    for (int t = 0; t < 16; ++t) {
        const unsigned short* S = lds + st * 16384;
        int pt = st + 2; if (pt >= 3) pt -= 3;
        const int koff = (t + 2) * 32;
        bf16x8 bfv[4], af[4];
        #pragma unroll
        for (int n = 0; n < 4; ++n) bfv[n] = *(const bf16x8*)(S + boff[n]);
        #pragma unroll
        for (int m = 0; m < 4; ++m) af[m] = *(const bf16x8*)(S + aoff[m]);
        if (t < 14) {
            gl2lds16(Ag0 + koff, dA0 + pt * 16384);
            gl2lds16(Ag1 + koff, dA0 + pt * 16384 + 4096);
        }
        __builtin_amdgcn_s_barrier();
        __builtin_amdgcn_s_setprio(1);
        #pragma unroll
        for (int m = 0; m < 4; ++m)
            #pragma unroll
            for (int n = 0; n < 4; ++n)
                acc[m][n] = __builtin_amdgcn_mfma_f32_16x16x32_bf16(af[m], bfv[n], acc[m][n], 0, 0, 0);
        __builtin_amdgcn_s_setprio(0);
        __builtin_amdgcn_s_barrier();
        #pragma unroll
        for (int m = 0; m < 4; ++m) af[m] = *(const bf16x8*)(S + aoff[4 + m]);
        if (t < 14) {
            gl2lds16(Wg0 + koff, dA0 + pt * 16384 + 8192);
            gl2lds16(Wg1 + koff, dA0 + pt * 16384 + 12288);
        }
        __builtin_amdgcn_s_barrier();
        __builtin_amdgcn_s_setprio(1);
        #pragma unroll
        for (int m = 0; m < 4; ++m)
            #pragma unroll
            for (int n = 0; n < 4; ++n)
                acc[4 + m][n] = __builtin_amdgcn_mfma_f32_16x16x32_bf16(af[m], bfv[n], acc[4 + m][n], 0, 0, 0);
        __builtin_amdgcn_s_setprio(0);
        if (t < 14) { asm volatile("s_waitcnt vmcnt(4)" ::: "memory"); }
        else        { asm volatile("s_waitcnt vmcnt(0)" ::: "memory"); }
        __builtin_amdgcn_s_barrier();
        if (++st == 3) st = 0;
    }

    #pragma unroll
    for (int n = 0; n < 4; ++n) {
        int col = bn * 256 + wc * 64 + n * 16 + fr;
        float bv = bias[col];
        #pragma unroll
        for (int m = 0; m < 8; ++m) {
            #pragma unroll
            for (int j = 0; j < 4; ++j) {
                int row = bm * 256 + wr * 128 + m * 16 + fq * 4 + j;
                float v = acc[m][n][j] + bv;
                if (EPI == 1)
                    v = 0.5f * v * (1.f + erff(v * 0.70710678118654752f));
                C[(size_t)row * ldc + col] = f2bf(v);
            }
        }
    }
}

// ------------------------------------------------- MFMA attention on packed qkv[n][1536]
// Q read from global per band (L2-hot); LDS 47104 B -> 3 blocks/CU.
__global__ __launch_bounds__(256) void attn_mfma(unsigned short* __restrict__ qkv,
                                                 const float* __restrict__ mbias) {
    __shared__ __align__(16) unsigned char lds[47104];
    const int KOFF = 0, VOFF = 14336, POFF = 30720;
    const int tid = threadIdx.x, wv = tid >> 6, lane = tid & 63;
    const int fr = lane & 15, fq = lane >> 4;
    const int b = blockIdx.x >> 3, hh = blockIdx.x & 7;
    unsigned short* qg = qkv + (size_t)(b * LL) * QKVN + hh * DHD;
    const unsigned short* kg = qg + 512;
    const unsigned short* vg = qg + 1024;

    for (int idx = tid; idx < 800; idx += 256) {
        int s = idx >> 3, c = idx & 7;
        uint4 kv = *(const uint4*)(kg + (size_t)s * QKVN + c * 8);
        uint4 vv = *(const uint4*)(vg + (size_t)s * QKVN + c * 8);
        int sw = (s & 7) << 4;
        *(uint4*)(lds + KOFF + s * 128 + ((c * 16) ^ sw)) = kv;
        unsigned int vs[4] = {vv.x, vv.y, vv.z, vv.w};
        #pragma unroll
        for (int e = 0; e < 4; ++e) {
            int d0 = c * 8 + e * 2, d1 = d0 + 1;
            *(unsigned short*)(lds + VOFF + d0 * 256 + ((s * 2) ^ ((d0 & 7) << 4))) = (unsigned short)(vs[e] & 0xFFFFu);
            *(unsigned short*)(lds + VOFF + d1 * 256 + ((s * 2) ^ ((d1 & 7) << 4))) = (unsigned short)(vs[e] >> 16);
        }
    }
    for (int idx = tid; idx < 96; idx += 256) {
        int r = 100 + (idx >> 3), c = idx & 7;
        *(uint4*)(lds + KOFF + r * 128 + ((c * 16) ^ ((r & 7) << 4))) = uint4{0u, 0u, 0u, 0u};
    }
    for (int idx = tid; idx < 896; idx += 256) {
        int d = idx / 14, s = 100 + 2 * (idx % 14);
        *(unsigned int*)(lds + VOFF + d * 256 + ((s * 2) ^ ((d & 7) << 4))) = 0u;
    }
    __syncthreads();

    const int pbase = POFF + wv * 4096;
    for (int bd = wv; bd < 7; bd += 4) {
        const unsigned short* qp = qg + (size_t)(bd * 16 + fr) * QKVN;
        bf16x8 aq0 = *(const bf16x8*)(qp + fq * 8);
        bf16x8 aq1 = *(const bf16x8*)(qp + 32 + fq * 8);
        f32x4 sv[7];
        #pragma unroll
        for (int ct = 0; ct < 7; ++ct) {
            int row = ct * 16 + fr, sw = (row & 7) << 4;
            bf16x8 bk0 = *(const bf16x8*)(lds + KOFF + row * 128 + ((fq * 16) ^ sw));
            bf16x8 bk1 = *(const bf16x8*)(lds + KOFF + row * 128 + ((64 + fq * 16) ^ sw));
            f32x4 a = {0.f, 0.f, 0.f, 0.f};
            a = __builtin_amdgcn_mfma_f32_16x16x32_bf16(aq0, bk0, a, 0, 0, 0);
            a = __builtin_amdgcn_mfma_f32_16x16x32_bf16(aq1, bk1, a, 0, 0, 0);
            sv[ct] = a;
        }
        const int rg0 = bd * 16 + fq * 4;
        #pragma unroll
        for (int ct = 0; ct < 7; ++ct) {
            int col = ct * 16 + fr;
            #pragma unroll
            for (int j = 0; j < 4; ++j) {
                int rg = rg0 + j;
                float bias = (rg < LL && col < LL) ? mbias[rg * LL + col] : -1.0e30f;
                sv[ct][j] = sv[ct][j] * 0.125f + bias;
            }
        }
        float inv[4];
        #pragma unroll
        for (int j = 0; j < 4; ++j) {
            float mx = sv[0][j];
            #pragma unroll
            for (int ct = 1; ct < 7; ++ct) mx = fmaxf(mx, sv[ct][j]);
            #pragma unroll
            for (int off = 8; off; off >>= 1) mx = fmaxf(mx, __shfl_xor(mx, off, 64));
            float sum = 0.f;
            #pragma unroll
            for (int ct = 0; ct < 7; ++ct) {
                float p = __expf(sv[ct][j] - mx);
                sv[ct][j] = p; sum += p;
            }
            #pragma unroll
            for (int off = 8; off; off >>= 1) sum += __shfl_xor(sum, off, 64);
            inv[j] = 1.f / sum;
        }
        asm volatile("s_waitcnt lgkmcnt(0)" ::: "memory");
        #pragma unroll
        for (int j = 0; j < 4; ++j) {
            int pr = fq * 4 + j, sw = (pr & 7) << 4;
            #pragma unroll
            for (int ct = 0; ct < 7; ++ct)
                *(unsigned short*)(lds + pbase + pr * 256 + ((ct * 32 + fr * 2) ^ sw)) = f2bf(sv[ct][j] * inv[j]);
            *(unsigned short*)(lds + pbase + pr * 256 + ((224 + fr * 2) ^ sw)) = 0;
        }
        asm volatile("s_waitcnt lgkmcnt(0)" ::: "memory");
        f32x4 oacc[4] = {};
        #pragma unroll
        for (int kt = 0; kt < 4; ++kt) {
            bf16x8 ap = *(const bf16x8*)(lds + pbase + fr * 256 + ((kt * 64 + fq * 16) ^ ((fr & 7) << 4)));
            #pragma unroll
            for (int n = 0; n < 4; ++n) {
                int d = n * 16 + fr, sw = (d & 7) << 4;
                bf16x8 bv = *(const bf16x8*)(lds + VOFF + d * 256 + ((kt * 64 + fq * 16) ^ sw));
                oacc[n] = __builtin_amdgcn_mfma_f32_16x16x32_bf16(ap, bv, oacc[n], 0, 0, 0);
            }
        }
        #pragma unroll
        for (int j = 0; j < 4; ++j) {
            int rg = rg0 + j;
            if (rg < LL) {
                #pragma unroll
                for (int n = 0; n < 4; ++n)
                    qg[(size_t)rg * QKVN + n * 16 + fr] = f2bf(oacc[n][j]);
            }
        }
    }
}

// ------------------------------------------------- residual + layernorm (bf16 in/out)
template<bool RES>
__global__ __launch_bounds__(256) void add_ln(unsigned short* __restrict__ h,
                                              const unsigned short* __restrict__ res,
                                              const float* __restrict__ sc,
                                              const float* __restrict__ bi) {
    int n = blockIdx.x, tid = threadIdx.x;
    size_t base = (size_t)n * DD;
    float x0 = bf2f(h[base + tid]), x1 = bf2f(h[base + 256 + tid]);
    if (RES) { x0 += bf2f(res[base + tid]); x1 += bf2f(res[base + 256 + tid]); }
    float s = x0 + x1, ss = x0 * x0 + x1 * x1;
    #pragma unroll
    for (int off = 32; off; off >>= 1) {
        s  += __shfl_xor(s, off, 64);
        ss += __shfl_xor(ss, off, 64);
    }
    __shared__ float rs[4], rss[4];
    int wv = tid >> 6, lane = tid & 63;
    if (lane == 0) { rs[wv] = s; rss[wv] = ss; }
    __syncthreads();
    s  = rs[0] + rs[1] + rs[2] + rs[3];
    ss = rss[0] + rss[1] + rss[2] + rss[3];
    float mean = s * (1.f / (float)DD);
    float var  = ss * (1.f / (float)DD) - mean * mean;
    float rstd = 1.f / sqrtf(var + 1e-5f);
    h[base + tid]       = f2bf((x0 - mean) * rstd * sc[tid]       + bi[tid]);
    h[base + 256 + tid] = f2bf((x1 - mean) * rstd * sc[256 + tid] + bi[256 + tid]);
}

// ------------------------------------------------- final projection via MFMA
__global__ __launch_bounds__(256) void proj_mfma(const unsigned short* __restrict__ hn,
                                                 const unsigned short* __restrict__ pwb,
                                                 const float* __restrict__ pb,
                                                 float* __restrict__ out) {
    const int tid = threadIdx.x, wv = tid >> 6, lane = tid & 63;
    const int fr = lane & 15, fq = lane >> 4;
    const int row0 = blockIdx.x * 64 + wv * 16;
    const unsigned short* aRow = hn + (size_t)(row0 + fr) * DD + fq * 8;
    f32x4 acc[3] = {};
    #pragma unroll 4
    for (int kt = 0; kt < 16; ++kt) {
        bf16x8 af = *(const bf16x8*)(aRow + kt * 32);
        #pragma unroll
        for (int n = 0; n < 3; ++n) {
            bf16x8 bfv = *(const bf16x8*)(pwb + (size_t)(n * 16 + fr) * DD + kt * 32 + fq * 8);
            acc[n] = __builtin_amdgcn_mfma_f32_16x16x32_bf16(af, bfv, acc[n], 0, 0, 0);
        }
    }
    #pragma unroll
    for (int n = 0; n < 3; ++n) {
        int col = n * 16 + fr;
        if (col < COUT) {
            float bias = pb[col];
            #pragma unroll
            for (int j = 0; j < 4; ++j) {
                int r = row0 + fq * 4 + j;
                out[(size_t)r * COUT + col] = acc[n][j] + bias;
            }
        }
    }
}

__global__ void sentinel_kernel(float* out, int n) {
    int i = blockIdx.x * 256 + threadIdx.x;
    if (i < n) out[i] = 1.0e4f;
}

extern "C" void kernel_launch(void* const* d_in, const int* in_sizes, int n_in,
                              void* d_out, int out_size, void* d_ws, size_t ws_size,
                              hipStream_t stream) {
    const float* x    = (const float*)d_in[0];
    const float* ew   = (const float*)d_in[1];
    const float* Wq   = (const float*)d_in[2];
    const float* bq   = (const float*)d_in[3];
    const float* Wk   = (const float*)d_in[4];
    const float* bk   = (const float*)d_in[5];
    const float* Wv   = (const float*)d_in[6];
    const float* bv   = (const float*)d_in[7];
    const float* Wo   = (const float*)d_in[8];
    const float* bo   = (const float*)d_in[9];
    const float* c1w  = (const float*)d_in[10];
    const float* c1b  = (const float*)d_in[11];
    const float* c2w  = (const float*)d_in[12];
    const float* c2b  = (const float*)d_in[13];
    const float* ln1s = (const float*)d_in[14];
    const float* ln1b = (const float*)d_in[15];
    const float* ln2s = (const float*)d_in[16];
    const float* ln2b = (const float*)d_in[17];
    const float* lnfs = (const float*)d_in[18];
    const float* lnfb = (const float*)d_in[19];
    const float* pw   = (const float*)d_in[20];
    const float* pb   = (const float*)d_in[21];
    const unsigned char* mraw = (const unsigned char*)d_in[22];

    const size_t NB   = (size_t)NTOK * DD;       // 13,107,200
    const size_t PWB  = 48 * DD;
    const size_t EWB  = (size_t)DD * 128;
    const size_t UB   = (size_t)NTOK * 128;
    const size_t need = (5 * NB + 6 * (size_t)WELEM + PWB + EWB + UB) * 2
                      + ((size_t)EE * QKVN + (size_t)LL * DD + (size_t)LL * LL) * 4;
    if (ws_size < need) {
        sentinel_kernel<<<(out_size + 255) / 256, 256, 0, stream>>>((float*)d_out, out_size);
        return;
    }
    unsigned short* h    = (unsigned short*)d_ws;
    unsigned short* qkv  = h + NB;               // 3*NB (QKV out; also FFN-mid scratch)
    unsigned short* t1   = qkv + 3 * NB;         // o-proj / ffn2 output
    unsigned short* wqkv = t1 + NB;              // 3*WELEM packed
    unsigned short* wo   = wqkv + 3 * WELEM;
    unsigned short* w1   = wo + WELEM;
    unsigned short* w2   = w1 + WELEM;
    unsigned short* pwb  = w2 + WELEM;
    unsigned short* ewb  = pwb + PWB;
    unsigned short* ub   = ewb + EWB;
    float* bqkv = (float*)(ub + UB);
    float* pe   = bqkv + EE * QKVN;
    float* mb   = pe + LL * DD;

    pe_kernel<<<(LL * DD + 255) / 256, 256, 0, stream>>>(pe);
    expand_mask_kernel<<<(LL * LL + 255) / 256, 256, 0, stream>>>(mraw, mb);
    const int cg = WELEM / 4 / 256;   // 768
    cvt_pack<<<cg, 256, 0, stream>>>(Wq, wqkv, 0);
    cvt_pack<<<cg, 256, 0, stream>>>(Wk, wqkv, 1);
    cvt_pack<<<cg, 256, 0, stream>>>(Wv, wqkv, 2);
    pack_bias<<<(EE * QKVN + 255) / 256, 256, 0, stream>>>(bq, bk, bv, bqkv);
    cvt_kernel<<<cg, 256, 0, stream>>>(Wo,  wo, WELEM / 4);
    cvt_kernel<<<cg, 256, 0, stream>>>(c1w, w1, WELEM / 4);
    cvt_kernel<<<cg, 256, 0, stream>>>(c2w, w2, WELEM / 4);
    proj_cvt<<<(48 * DD / 4 + 255) / 256, 256, 0, stream>>>(pw, pwb);
    ewb_cvt<<<(DD * 128 + 255) / 256, 256, 0, stream>>>(ew, ewb);
    ub_build<<<(NTOK * 128 + 255) / 256, 256, 0, stream>>>(x, ub);

    // embed as MFMA GEMM: h = ub @ ewb^T + PE  (128^2 kernel, K=128)
    gemm_bf16<2><<<800, 256, 0, stream>>>(ub, ewb, nullptr, pe, h, NTOK, DD, 128, 128, DD, 4);

    for (int l = 0; l < EE; ++l) {
        const size_t wofs = (size_t)l * DD * DD;
        const size_t bof  = (size_t)l * DD;
        // QKV: pipelined 256^2, 600 blocks (T1-chunked), 3-slot ring (r11 best)
        gemm_pipe<0><<<600, 512, 0, stream>>>(h, wqkv + (size_t)l * 3 * DD * DD,
                                              bqkv + l * QKVN, qkv, QKVN, 6);
        attn_mfma<<<BB * HH, 256, 0, stream>>>(qkv, mb);
        // o-proj (128^2 + T1 grid), then residual+LN1
        gemm_bf16<0><<<800, 256, 0, stream>>>(qkv, wo + wofs, bo + bof, nullptr, t1,
                                              NTOK, DD, DD, QKVN, DD, 4);
        add_ln<true><<<NTOK, 256, 0, stream>>>(h, t1, ln1s + bof, ln1b + bof);
        // ffn1 + GELU: pipelined 256^2, 200 blocks
        gemm_pipe<1><<<200, 512, 0, stream>>>(h, w1 + wofs, c1b + bof, qkv, DFF, 2);
        // ffn2 (128^2 + T1 grid), then residual+LN2
        gemm_bf16<0><<<800, 256, 0, stream>>>(qkv, w2 + wofs, c2b + bof, nullptr, t1,
                                              NTOK, DD, DFF, DFF, DD, 4);
        add_ln<true><<<NTOK, 256, 0, stream>>>(h, t1, ln2s + bof, ln2b + bof);
    }
    add_ln<false><<<NTOK, 256, 0, stream>>>(h, nullptr, lnfs, lnfb);
    proj_mfma<<<NTOK / 64, 256, 0, stream>>>(h, pwb, pb, (float*)d_out);
}

// Round 14
// 680.565 us; speedup vs baseline: 1.1934x; 1.1168x over previous
//
#include <hip/hip_runtime.h>
#include <math.h>

#define BB   256
#define LL   100
#define CIN  38
#define COUT 38
#define DD   512
#define HH   8
#define EE   3
#define DFF  512
#define DHD  64
#define NTOK (BB*LL)     // 25600
#define WELEM (EE*DD*DD) // 786432 elements per weight family
#define QKVN 1536        // packed QKV width

typedef __attribute__((ext_vector_type(8))) short bf16x8;
typedef __attribute__((ext_vector_type(4))) float f32x4;

__device__ __forceinline__ unsigned short f2bf(float f) {
    unsigned int u = __float_as_uint(f);
    unsigned int r = (u + 0x7FFFu + ((u >> 16) & 1u)) >> 16;
    return (unsigned short)r;
}
__device__ __forceinline__ float bf2f(unsigned short s) {
    return __uint_as_float(((unsigned int)s) << 16);
}

__device__ __forceinline__ void gl2lds16(const unsigned short* g, unsigned short* l) {
    __builtin_amdgcn_global_load_lds(
        (const __attribute__((address_space(1))) void*)g,
        (__attribute__((address_space(3))) void*)l, 16, 0, 0);
}

// paired-row XOR swizzle: 16B-unit index for logical (row, chunk c in 0..3) of a [256][32]bf16 tile.
__device__ __forceinline__ int swz(int row, int c) {
    int rp = row >> 1;
    int ch = c + ((row & 1) << 2);
    return rp * 8 + (ch ^ (rp & 7));
}

// ---------------------------------------------------------------- PE table
__global__ __launch_bounds__(256) void pe_kernel(float* __restrict__ pe) {
    int idx = blockIdx.x * 256 + threadIdx.x;
    if (idx >= LL * DD) return;
    int l = idx / DD, d = idx % DD;
    float e = (float)(d & ~1) * (-9.210340371976184f / (float)DD);
    float ang = (float)l * expf(e);
    pe[idx] = (d & 1) ? cosf(ang) : sinf(ang);
}

// ------------------------------------------------- mask -> additive bias
__global__ void expand_mask_kernel(const unsigned char* __restrict__ mraw,
                                   float* __restrict__ mb) {
    int i = blockIdx.x * 256 + threadIdx.x;
    if (i >= LL * LL) return;
    unsigned char b0 = mraw[0], b1 = mraw[1], b2 = mraw[2], b3 = mraw[3];
    bool v;
    if (b0 == 1 && b1 == 1)                      v = mraw[i] != 0;
    else if (b0 == 1 && b1 == 0 && b2 == 0 && b3 == 0)
                                                 v = ((const int*)mraw)[i] != 0;
    else if (b0 == 0x80 && b1 == 0x3F)           v = ((const unsigned short*)mraw)[i] != 0;
    else if (b0 == 0 && b1 == 0x3C)              v = ((const unsigned short*)mraw)[i] != 0;
    else if (b0 == 0 && b1 == 0 && b2 == 0x80 && b3 == 0x3F)
                                                 v = ((const float*)mraw)[i] != 0.f;
    else                                         v = mraw[i] != 0;
    mb[i] = v ? 0.f : -1.0e30f;
}

// ------------------------------------------------- fp32 -> bf16 bulk convert
__global__ __launch_bounds__(256) void cvt_kernel(const float* __restrict__ in,
                                                  unsigned short* __restrict__ out,
                                                  int n4) {
    int i = blockIdx.x * 256 + threadIdx.x;
    if (i >= n4) return;
    float4 f = ((const float4*)in)[i];
    unsigned short o0 = f2bf(f.x), o1 = f2bf(f.y), o2 = f2bf(f.z), o3 = f2bf(f.w);
    unsigned long long packed = (unsigned long long)o0 | ((unsigned long long)o1 << 16)
                              | ((unsigned long long)o2 << 32) | ((unsigned long long)o3 << 48);
    ((unsigned long long*)out)[i] = packed;
}

// ------------------------------------------------- Wq/Wk/Wv -> packed [l][1536][512] bf16
__global__ __launch_bounds__(256) void cvt_pack(const float* __restrict__ in,
                                                unsigned short* __restrict__ out,
                                                int fam) {
    int i = blockIdx.x * 256 + threadIdx.x;      // over WELEM/4
    if (i >= WELEM / 4) return;
    int l = i >> 16;                              // / (DD*DD/4 = 65536)
    int j = i & 65535;
    float4 f = ((const float4*)in)[i];
    unsigned short o0 = f2bf(f.x), o1 = f2bf(f.y), o2 = f2bf(f.z), o3 = f2bf(f.w);
    unsigned long long packed = (unsigned long long)o0 | ((unsigned long long)o1 << 16)
                              | ((unsigned long long)o2 << 32) | ((unsigned long long)o3 << 48);
    ((unsigned long long*)out)[(size_t)l * (3 * 65536) + (size_t)fam * 65536 + j] = packed;
}

// ------------------------------------------------- bq/bk/bv -> packed [l][1536] fp32
__global__ __launch_bounds__(256) void pack_bias(const float* __restrict__ bq,
                                                 const float* __restrict__ bk,
                                                 const float* __restrict__ bv,
                                                 float* __restrict__ out) {
    int idx = blockIdx.x * 256 + threadIdx.x;    // EE*1536
    if (idx >= EE * QKVN) return;
    int l = idx / QKVN, r = idx % QKVN, f = r >> 9, d = r & 511;
    const float* src = (f == 0) ? bq : (f == 1) ? bk : bv;
    out[idx] = src[l * DD + d];
}

// ------------------------------------------------- proj weights -> bf16, padded [48][512]
__global__ __launch_bounds__(256) void proj_cvt(const float* __restrict__ in,
                                                unsigned short* __restrict__ outp) {
    int i = blockIdx.x * 256 + threadIdx.x;
    if (i >= 48 * DD / 4) return;
    if (i < COUT * DD / 4) {
        float4 f = ((const float4*)in)[i];
        unsigned short o0 = f2bf(f.x), o1 = f2bf(f.y), o2 = f2bf(f.z), o3 = f2bf(f.w);
        unsigned long long packed = (unsigned long long)o0 | ((unsigned long long)o1 << 16)
                                  | ((unsigned long long)o2 << 32) | ((unsigned long long)o3 << 48);
        ((unsigned long long*)outp)[i] = packed;
    } else {
        ((unsigned long long*)outp)[i] = 0ull;
    }
}

// ------------------------------------------------- emb_w [512][38*3] -> bf16 [512][128] (K-pad)
__global__ __launch_bounds__(256) void ewb_cvt(const float* __restrict__ ew,
                                               unsigned short* __restrict__ out) {
    int idx = blockIdx.x * 256 + threadIdx.x;    // 512*128
    if (idx >= DD * 128) return;
    int d = idx >> 7, k = idx & 127;
    out[idx] = (k < 114) ? f2bf(ew[d * 114 + k]) : (unsigned short)0;
}

// ------------------------------------------------- x -> ub[25600][128] bf16 (circular gather)
__global__ __launch_bounds__(256) void ub_build(const float* __restrict__ x,
                                               unsigned short* __restrict__ ub) {
    int idx = blockIdx.x * 256 + threadIdx.x;    // NTOK*128
    if (idx >= NTOK * 128) return;
    int n = idx >> 7, k = idx & 127;
    float v = 0.f;
    if (k < 114) {
        int c = k / 3, t = k - 3 * c;
        int l = n % LL, b = n / LL;
        int ls = l + t - 1;
        ls = (ls < 0) ? (LL - 1) : (ls >= LL ? ls - LL : ls);
        v = x[(size_t)(b * LL + ls) * CIN + c];
    }
    ub[idx] = f2bf(v);
}

// ------------------------------------------------- bf16 MFMA GEMM (128x128), T1 1-D swizzled grid
// EPI: 0 = +bias, 1 = +bias+GELU, 2 = +pe[(row%LL)][col]
template<int EPI>
__global__ __launch_bounds__(256) void gemm_bf16(const unsigned short* __restrict__ A,
                                                 const unsigned short* __restrict__ W,
                                                 const float* __restrict__ bias,
                                                 const float* __restrict__ pe2,
                                                 unsigned short* __restrict__ C,
                                                 int M, int N, int K, int lda, int ldc,
                                                 int nbn) {
    __shared__ unsigned short As[128 * 32];
    __shared__ unsigned short Bs[128 * 32];
    const int tid  = threadIdx.x;
    const int tile = (blockIdx.x & 7) * ((int)gridDim.x >> 3) + (blockIdx.x >> 3);
    const int bn   = tile % nbn, bm = tile / nbn;
    const int w    = tid >> 6, lane = tid & 63;
    const int wr   = w >> 1,  wc   = w & 1;
    const int sRow = tid >> 2;
    const int sK   = (tid & 3) * 8;
    const unsigned short* Ag = A + (size_t)(bm * 128 + sRow) * lda + sK;
    const unsigned short* Wg = W + (size_t)(bn * 128 + sRow) * K + sK;
    unsigned short* AsD = As + tid * 8;
    unsigned short* BsD = Bs + tid * 8;
    const int fr = lane & 15, fq = lane >> 4;
    const int fo = fq * 8;

    f32x4 acc[4][4] = {};
    for (int k0 = 0; k0 < K; k0 += 32) {
        gl2lds16(Ag + k0, AsD);
        gl2lds16(Ag + k0 + (size_t)64 * lda, AsD + 64 * 32);
        gl2lds16(Wg + k0, BsD);
        gl2lds16(Wg + k0 + (size_t)64 * K, BsD + 64 * 32);
        __syncthreads();
        bf16x8 af[4], bfv[4];
        #pragma unroll
        for (int m = 0; m < 4; ++m)
            af[m] = *(const bf16x8*)(As + (wr * 64 + m * 16 + fr) * 32 + fo);
        #pragma unroll
        for (int n = 0; n < 4; ++n)
            bfv[n] = *(const bf16x8*)(Bs + (wc * 64 + n * 16 + fr) * 32 + fo);
        #pragma unroll
        for (int m = 0; m < 4; ++m)
            #pragma unroll
            for (int n = 0; n < 4; ++n)
                acc[m][n] = __builtin_amdgcn_mfma_f32_16x16x32_bf16(af[m], bfv[n], acc[m][n], 0, 0, 0);
        __syncthreads();
    }
    #pragma unroll
    for (int n = 0; n < 4; ++n) {
        int col = bn * 128 + wc * 64 + n * 16 + fr;
        float bv = (EPI != 2) ? bias[col] : 0.f;
        #pragma unroll
        for (int m = 0; m < 4; ++m) {
            #pragma unroll
            for (int j = 0; j < 4; ++j) {
                int row = bm * 128 + wr * 64 + m * 16 + fq * 4 + j;
                float v = acc[m][n][j] + bv;
                if (EPI == 1)
                    v = 0.5f * v * (1.f + erff(v * 0.70710678118654752f));
                if (EPI == 2)
                    v += pe2[(row % LL) * DD + col];
                C[(size_t)row * ldc + col] = f2bf(v);
            }
        }
    }
}

// ------------------------------------------------- pipelined 256x256 GEMM, K=512 fixed (r11 best)
// T2 swizzled LDS + counted vmcnt (3-slot ring, 2 phases/K-tile) + T5 setprio + T1 grid.
// Epilogue reordered m,j-outer / n-inner: the 4x32B segments of each row are written
// back-to-back so 64B HBM sectors merge in L2 before eviction (fixes 1.78x write amp).
template<int EPI>
__global__ __launch_bounds__(512) void gemm_pipe(const unsigned short* __restrict__ A,
                                                 const unsigned short* __restrict__ W,
                                                 const float* __restrict__ bias,
                                                 unsigned short* __restrict__ C,
                                                 int ldc, int nbn) {
    __shared__ __align__(16) unsigned short lds[3 * 16384];
    const int tid  = threadIdx.x;
    const int tile = ((int)blockIdx.x & 7) * ((int)gridDim.x >> 3) + ((int)blockIdx.x >> 3);
    const int bn   = tile % nbn, bm = tile / nbn;
    const int wid  = tid >> 6, lane = tid & 63;
    const int wr   = wid >> 2, wc = wid & 3;
    const int fr   = lane & 15, fq = lane >> 4;

    int rowS0, cS0, rowS1, cS1;
    { int u = tid;       int rp = u >> 3, q = u & 7, ch = q ^ (rp & 7); rowS0 = (rp << 1) + (ch >> 2); cS0 = ch & 3; }
    { int u = tid + 512; int rp = u >> 3, q = u & 7, ch = q ^ (rp & 7); rowS1 = (rp << 1) + (ch >> 2); cS1 = ch & 3; }
    const unsigned short* Ag0 = A + (size_t)(bm * 256 + rowS0) * 512 + cS0 * 8;
    const unsigned short* Ag1 = A + (size_t)(bm * 256 + rowS1) * 512 + cS1 * 8;
    const unsigned short* Wg0 = W + (size_t)(bn * 256 + rowS0) * 512 + cS0 * 8;
    const unsigned short* Wg1 = W + (size_t)(bn * 256 + rowS1) * 512 + cS1 * 8;
    unsigned short* dA0 = lds + tid * 8;

    int aoff[8], boff[4];
    #pragma unroll
    for (int m = 0; m < 8; ++m) aoff[m] = swz(wr * 128 + m * 16 + fr, fq) * 8;
    #pragma unroll
    for (int n = 0; n < 4; ++n) boff[n] = 8192 + swz(wc * 64 + n * 16 + fr, fq) * 8;

    f32x4 acc[8][4] = {};

    gl2lds16(Ag0,      dA0);
    gl2lds16(Ag1,      dA0 + 4096);
    gl2lds16(Wg0,      dA0 + 8192);
    gl2lds16(Wg1,      dA0 + 12288);
    gl2lds16(Ag0 + 32, dA0 + 16384);
    gl2lds16(Ag1 + 32, dA0 + 16384 + 4096);
    gl2lds16(Wg0 + 32, dA0 + 16384 + 8192);
    gl2lds16(Wg1 + 32, dA0 + 16384 + 12288);
    asm volatile("s_waitcnt vmcnt(4)" ::: "memory");
    __builtin_amdgcn_s_barrier();

    int st = 0;
    for (int t = 0; t < 16; ++t) {
        const unsigned short* S = lds + st * 16384;
        int pt = st + 2; if (pt >= 3) pt -= 3;
        const int koff = (t + 2) * 32;
        bf16x8 bfv[4], af[4];
        #pragma unroll
        for (int n = 0; n < 4; ++n) bfv[n] = *(const bf16x8*)(S + boff[n]);
        #pragma unroll
        for (int m = 0; m < 4; ++m) af[m] = *(const bf16x8*)(S + aoff[m]);
        if (t < 14) {
            gl2lds16(Ag0 + koff, dA0 + pt * 16384);
            gl2lds16(Ag1 + koff, dA0 + pt * 16384 + 4096);
        }
        __builtin_amdgcn_s_barrier();
        __builtin_amdgcn_s_setprio(1);
        #pragma unroll
        for (int m = 0; m < 4; ++m)
            #pragma unroll
            for (int n = 0; n < 4; ++n)
                acc[m][n] = __builtin_amdgcn_mfma_f32_16x16x32_bf16(af[m], bfv[n], acc[m][n], 0, 0, 0);
        __builtin_amdgcn_s_setprio(0);
        __builtin_amdgcn_s_barrier();
        #pragma unroll
        for (int m = 0; m < 4; ++m) af[m] = *(const bf16x8*)(S + aoff[4 + m]);
        if (t < 14) {
            gl2lds16(Wg0 + koff, dA0 + pt * 16384 + 8192);
            gl2lds16(Wg1 + koff, dA0 + pt * 16384 + 12288);
        }
        __builtin_amdgcn_s_barrier();
        __builtin_amdgcn_s_setprio(1);
        #pragma unroll
        for (int m = 0; m < 4; ++m)
            #pragma unroll
            for (int n = 0; n < 4; ++n)
                acc[4 + m][n] = __builtin_amdgcn_mfma_f32_16x16x32_bf16(af[m], bfv[n], acc[4 + m][n], 0, 0, 0);
        __builtin_amdgcn_s_setprio(0);
        if (t < 14) { asm volatile("s_waitcnt vmcnt(4)" ::: "memory"); }
        else        { asm volatile("s_waitcnt vmcnt(0)" ::: "memory"); }
        __builtin_amdgcn_s_barrier();
        if (++st == 3) st = 0;
    }

    float bvv[4];
    #pragma unroll
    for (int n = 0; n < 4; ++n) bvv[n] = bias[bn * 256 + wc * 64 + n * 16 + fr];
    #pragma unroll
    for (int m = 0; m < 8; ++m) {
        #pragma unroll
        for (int j = 0; j < 4; ++j) {
            int row = bm * 256 + wr * 128 + m * 16 + fq * 4 + j;
            unsigned short* Crow = C + (size_t)row * ldc + bn * 256 + wc * 64 + fr;
            #pragma unroll
            for (int n = 0; n < 4; ++n) {
                float v = acc[m][n][j] + bvv[n];
                if (EPI == 1)
                    v = 0.5f * v * (1.f + erff(v * 0.70710678118654752f));
                Crow[n * 16] = f2bf(v);
            }
        }
    }
}

// ------------------------------------------------- MFMA attention on packed qkv[n][1536]
// Q read from global per band (L2-hot); LDS 47104 B -> 3 blocks/CU.
__global__ __launch_bounds__(256) void attn_mfma(unsigned short* __restrict__ qkv,
                                                 const float* __restrict__ mbias) {
    __shared__ __align__(16) unsigned char lds[47104];
    const int KOFF = 0, VOFF = 14336, POFF = 30720;
    const int tid = threadIdx.x, wv = tid >> 6, lane = tid & 63;
    const int fr = lane & 15, fq = lane >> 4;
    const int b = blockIdx.x >> 3, hh = blockIdx.x & 7;
    unsigned short* qg = qkv + (size_t)(b * LL) * QKVN + hh * DHD;
    const unsigned short* kg = qg + 512;
    const unsigned short* vg = qg + 1024;

    for (int idx = tid; idx < 800; idx += 256) {
        int s = idx >> 3, c = idx & 7;
        uint4 kv = *(const uint4*)(kg + (size_t)s * QKVN + c * 8);
        uint4 vv = *(const uint4*)(vg + (size_t)s * QKVN + c * 8);
        int sw = (s & 7) << 4;
        *(uint4*)(lds + KOFF + s * 128 + ((c * 16) ^ sw)) = kv;
        unsigned int vs[4] = {vv.x, vv.y, vv.z, vv.w};
        #pragma unroll
        for (int e = 0; e < 4; ++e) {
            int d0 = c * 8 + e * 2, d1 = d0 + 1;
            *(unsigned short*)(lds + VOFF + d0 * 256 + ((s * 2) ^ ((d0 & 7) << 4))) = (unsigned short)(vs[e] & 0xFFFFu);
            *(unsigned short*)(lds + VOFF + d1 * 256 + ((s * 2) ^ ((d1 & 7) << 4))) = (unsigned short)(vs[e] >> 16);
        }
    }
    for (int idx = tid; idx < 96; idx += 256) {
        int r = 100 + (idx >> 3), c = idx & 7;
        *(uint4*)(lds + KOFF + r * 128 + ((c * 16) ^ ((r & 7) << 4))) = uint4{0u, 0u, 0u, 0u};
    }
    for (int idx = tid; idx < 896; idx += 256) {
        int d = idx / 14, s = 100 + 2 * (idx % 14);
        *(unsigned int*)(lds + VOFF + d * 256 + ((s * 2) ^ ((d & 7) << 4))) = 0u;
    }
    __syncthreads();

    const int pbase = POFF + wv * 4096;
    for (int bd = wv; bd < 7; bd += 4) {
        const unsigned short* qp = qg + (size_t)(bd * 16 + fr) * QKVN;
        bf16x8 aq0 = *(const bf16x8*)(qp + fq * 8);
        bf16x8 aq1 = *(const bf16x8*)(qp + 32 + fq * 8);
        f32x4 sv[7];
        #pragma unroll
        for (int ct = 0; ct < 7; ++ct) {
            int row = ct * 16 + fr, sw = (row & 7) << 4;
            bf16x8 bk0 = *(const bf16x8*)(lds + KOFF + row * 128 + ((fq * 16) ^ sw));
            bf16x8 bk1 = *(const bf16x8*)(lds + KOFF + row * 128 + ((64 + fq * 16) ^ sw));
            f32x4 a = {0.f, 0.f, 0.f, 0.f};
            a = __builtin_amdgcn_mfma_f32_16x16x32_bf16(aq0, bk0, a, 0, 0, 0);
            a = __builtin_amdgcn_mfma_f32_16x16x32_bf16(aq1, bk1, a, 0, 0, 0);
            sv[ct] = a;
        }
        const int rg0 = bd * 16 + fq * 4;
        #pragma unroll
        for (int ct = 0; ct < 7; ++ct) {
            int col = ct * 16 + fr;
            #pragma unroll
            for (int j = 0; j < 4; ++j) {
                int rg = rg0 + j;
                float bias = (rg < LL && col < LL) ? mbias[rg * LL + col] : -1.0e30f;
                sv[ct][j] = sv[ct][j] * 0.125f + bias;
            }
        }
        float inv[4];
        #pragma unroll
        for (int j = 0; j < 4; ++j) {
            float mx = sv[0][j];
            #pragma unroll
            for (int ct = 1; ct < 7; ++ct) mx = fmaxf(mx, sv[ct][j]);
            #pragma unroll
            for (int off = 8; off; off >>= 1) mx = fmaxf(mx, __shfl_xor(mx, off, 64));
            float sum = 0.f;
            #pragma unroll
            for (int ct = 0; ct < 7; ++ct) {
                float p = __expf(sv[ct][j] - mx);
                sv[ct][j] = p; sum += p;
            }
            #pragma unroll
            for (int off = 8; off; off >>= 1) sum += __shfl_xor(sum, off, 64);
            inv[j] = 1.f / sum;
        }
        asm volatile("s_waitcnt lgkmcnt(0)" ::: "memory");
        #pragma unroll
        for (int j = 0; j < 4; ++j) {
            int pr = fq * 4 + j, sw = (pr & 7) << 4;
            #pragma unroll
            for (int ct = 0; ct < 7; ++ct)
                *(unsigned short*)(lds + pbase + pr * 256 + ((ct * 32 + fr * 2) ^ sw)) = f2bf(sv[ct][j] * inv[j]);
            *(unsigned short*)(lds + pbase + pr * 256 + ((224 + fr * 2) ^ sw)) = 0;
        }
        asm volatile("s_waitcnt lgkmcnt(0)" ::: "memory");
        f32x4 oacc[4] = {};
        #pragma unroll
        for (int kt = 0; kt < 4; ++kt) {
            bf16x8 ap = *(const bf16x8*)(lds + pbase + fr * 256 + ((kt * 64 + fq * 16) ^ ((fr & 7) << 4)));
            #pragma unroll
            for (int n = 0; n < 4; ++n) {
                int d = n * 16 + fr, sw = (d & 7) << 4;
                bf16x8 bv = *(const bf16x8*)(lds + VOFF + d * 256 + ((kt * 64 + fq * 16) ^ sw));
                oacc[n] = __builtin_amdgcn_mfma_f32_16x16x32_bf16(ap, bv, oacc[n], 0, 0, 0);
            }
        }
        #pragma unroll
        for (int j = 0; j < 4; ++j) {
            int rg = rg0 + j;
            if (rg < LL) {
                #pragma unroll
                for (int n = 0; n < 4; ++n)
                    qg[(size_t)rg * QKVN + n * 16 + fr] = f2bf(oacc[n][j]);
            }
        }
    }
}

// ------------------------------------------------- residual + layernorm: wave-per-row, 4 rows/block
template<bool RES>
__global__ __launch_bounds__(256) void add_ln(unsigned short* __restrict__ h,
                                              const unsigned short* __restrict__ res,
                                              const float* __restrict__ sc,
                                              const float* __restrict__ bi) {
    const int wv = threadIdx.x >> 6, lane = threadIdx.x & 63;
    const int n = blockIdx.x * 4 + wv;
    unsigned short* hp = h + (size_t)n * DD + lane * 8;
    unsigned int u[4];
    *(uint4*)u = *(const uint4*)hp;
    float x[8];
    #pragma unroll
    for (int e = 0; e < 4; ++e) {
        x[2 * e]     = __uint_as_float(u[e] << 16);
        x[2 * e + 1] = __uint_as_float(u[e] & 0xFFFF0000u);
    }
    if (RES) {
        const unsigned short* rp = res + (size_t)n * DD + lane * 8;
        unsigned int r[4];
        *(uint4*)r = *(const uint4*)rp;
        #pragma unroll
        for (int e = 0; e < 4; ++e) {
            x[2 * e]     += __uint_as_float(r[e] << 16);
            x[2 * e + 1] += __uint_as_float(r[e] & 0xFFFF0000u);
        }
    }
    float s = 0.f, ss = 0.f;
    #pragma unroll
    for (int e = 0; e < 8; ++e) { s += x[e]; ss += x[e] * x[e]; }
    #pragma unroll
    for (int off = 32; off; off >>= 1) {
        s  += __shfl_xor(s, off, 64);
        ss += __shfl_xor(ss, off, 64);
    }
    float mean = s * (1.f / (float)DD);
    float var  = ss * (1.f / (float)DD) - mean * mean;
    float rstd = 1.f / sqrtf(var + 1e-5f);
    float4 s0 = *(const float4*)(sc + lane * 8), s1 = *(const float4*)(sc + lane * 8 + 4);
    float4 b0 = *(const float4*)(bi + lane * 8), b1 = *(const float4*)(bi + lane * 8 + 4);
    float scv[8] = {s0.x, s0.y, s0.z, s0.w, s1.x, s1.y, s1.z, s1.w};
    float biv[8] = {b0.x, b0.y, b0.z, b0.w, b1.x, b1.y, b1.z, b1.w};
    unsigned int o[4];
    #pragma unroll
    for (int e = 0; e < 4; ++e) {
        unsigned short lo = f2bf((x[2 * e]     - mean) * rstd * scv[2 * e]     + biv[2 * e]);
        unsigned short hi = f2bf((x[2 * e + 1] - mean) * rstd * scv[2 * e + 1] + biv[2 * e + 1]);
        o[e] = (unsigned int)lo | ((unsigned int)hi << 16);
    }
    *(uint4*)hp = *(uint4*)o;
}

// ------------------------------------------------- final projection via MFMA
__global__ __launch_bounds__(256) void proj_mfma(const unsigned short* __restrict__ hn,
                                                 const unsigned short* __restrict__ pwb,
                                                 const float* __restrict__ pb,
                                                 float* __restrict__ out) {
    const int tid = threadIdx.x, wv = tid >> 6, lane = tid & 63;
    const int fr = lane & 15, fq = lane >> 4;
    const int row0 = blockIdx.x * 64 + wv * 16;
    const unsigned short* aRow = hn + (size_t)(row0 + fr) * DD + fq * 8;
    f32x4 acc[3] = {};
    #pragma unroll 4
    for (int kt = 0; kt < 16; ++kt) {
        bf16x8 af = *(const bf16x8*)(aRow + kt * 32);
        #pragma unroll
        for (int n = 0; n < 3; ++n) {
            bf16x8 bfv = *(const bf16x8*)(pwb + (size_t)(n * 16 + fr) * DD + kt * 32 + fq * 8);
            acc[n] = __builtin_amdgcn_mfma_f32_16x16x32_bf16(af, bfv, acc[n], 0, 0, 0);
        }
    }
    #pragma unroll
    for (int n = 0; n < 3; ++n) {
        int col = n * 16 + fr;
        if (col < COUT) {
            float bias = pb[col];
            #pragma unroll
            for (int j = 0; j < 4; ++j) {
                int r = row0 + fq * 4 + j;
                out[(size_t)r * COUT + col] = acc[n][j] + bias;
            }
        }
    }
}

__global__ void sentinel_kernel(float* out, int n) {
    int i = blockIdx.x * 256 + threadIdx.x;
    if (i < n) out[i] = 1.0e4f;
}

extern "C" void kernel_launch(void* const* d_in, const int* in_sizes, int n_in,
                              void* d_out, int out_size, void* d_ws, size_t ws_size,
                              hipStream_t stream) {
    const float* x    = (const float*)d_in[0];
    const float* ew   = (const float*)d_in[1];
    const float* Wq   = (const float*)d_in[2];
    const float* bq   = (const float*)d_in[3];
    const float* Wk   = (const float*)d_in[4];
    const float* bk   = (const float*)d_in[5];
    const float* Wv   = (const float*)d_in[6];
    const float* bv   = (const float*)d_in[7];
    const float* Wo   = (const float*)d_in[8];
    const float* bo   = (const float*)d_in[9];
    const float* c1w  = (const float*)d_in[10];
    const float* c1b  = (const float*)d_in[11];
    const float* c2w  = (const float*)d_in[12];
    const float* c2b  = (const float*)d_in[13];
    const float* ln1s = (const float*)d_in[14];
    const float* ln1b = (const float*)d_in[15];
    const float* ln2s = (const float*)d_in[16];
    const float* ln2b = (const float*)d_in[17];
    const float* lnfs = (const float*)d_in[18];
    const float* lnfb = (const float*)d_in[19];
    const float* pw   = (const float*)d_in[20];
    const float* pb   = (const float*)d_in[21];
    const unsigned char* mraw = (const unsigned char*)d_in[22];

    const size_t NB   = (size_t)NTOK * DD;       // 13,107,200
    const size_t PWB  = 48 * DD;
    const size_t EWB  = (size_t)DD * 128;
    const size_t UB   = (size_t)NTOK * 128;
    const size_t need = (5 * NB + 6 * (size_t)WELEM + PWB + EWB + UB) * 2
                      + ((size_t)EE * QKVN + (size_t)LL * DD + (size_t)LL * LL) * 4;
    if (ws_size < need) {
        sentinel_kernel<<<(out_size + 255) / 256, 256, 0, stream>>>((float*)d_out, out_size);
        return;
    }
    unsigned short* h    = (unsigned short*)d_ws;
    unsigned short* qkv  = h + NB;               // 3*NB (QKV out; also FFN-mid scratch)
    unsigned short* t1   = qkv + 3 * NB;         // o-proj / ffn2 output
    unsigned short* wqkv = t1 + NB;              // 3*WELEM packed
    unsigned short* wo   = wqkv + 3 * WELEM;
    unsigned short* w1   = wo + WELEM;
    unsigned short* w2   = w1 + WELEM;
    unsigned short* pwb  = w2 + WELEM;
    unsigned short* ewb  = pwb + PWB;
    unsigned short* ub   = ewb + EWB;
    float* bqkv = (float*)(ub + UB);
    float* pe   = bqkv + EE * QKVN;
    float* mb   = pe + LL * DD;

    pe_kernel<<<(LL * DD + 255) / 256, 256, 0, stream>>>(pe);
    expand_mask_kernel<<<(LL * LL + 255) / 256, 256, 0, stream>>>(mraw, mb);
    const int cg = WELEM / 4 / 256;   // 768
    cvt_pack<<<cg, 256, 0, stream>>>(Wq, wqkv, 0);
    cvt_pack<<<cg, 256, 0, stream>>>(Wk, wqkv, 1);
    cvt_pack<<<cg, 256, 0, stream>>>(Wv, wqkv, 2);
    pack_bias<<<(EE * QKVN + 255) / 256, 256, 0, stream>>>(bq, bk, bv, bqkv);
    cvt_kernel<<<cg, 256, 0, stream>>>(Wo,  wo, WELEM / 4);
    cvt_kernel<<<cg, 256, 0, stream>>>(c1w, w1, WELEM / 4);
    cvt_kernel<<<cg, 256, 0, stream>>>(c2w, w2, WELEM / 4);
    proj_cvt<<<(48 * DD / 4 + 255) / 256, 256, 0, stream>>>(pw, pwb);
    ewb_cvt<<<(DD * 128 + 255) / 256, 256, 0, stream>>>(ew, ewb);
    ub_build<<<(NTOK * 128 + 255) / 256, 256, 0, stream>>>(x, ub);

    // embed as MFMA GEMM: h = ub @ ewb^T + PE  (128^2 kernel, K=128)
    gemm_bf16<2><<<800, 256, 0, stream>>>(ub, ewb, nullptr, pe, h, NTOK, DD, 128, 128, DD, 4);

    for (int l = 0; l < EE; ++l) {
        const size_t wofs = (size_t)l * DD * DD;
        const size_t bof  = (size_t)l * DD;
        // QKV: pipelined 256^2, 600 blocks (T1-chunked), 3-slot ring
        gemm_pipe<0><<<600, 512, 0, stream>>>(h, wqkv + (size_t)l * 3 * DD * DD,
                                              bqkv + l * QKVN, qkv, QKVN, 6);
        attn_mfma<<<BB * HH, 256, 0, stream>>>(qkv, mb);
        // o-proj (128^2 + T1 grid), then residual+LN1
        gemm_bf16<0><<<800, 256, 0, stream>>>(qkv, wo + wofs, bo + bof, nullptr, t1,
                                              NTOK, DD, DD, QKVN, DD, 4);
        add_ln<true><<<NTOK / 4, 256, 0, stream>>>(h, t1, ln1s + bof, ln1b + bof);
        // ffn1 + GELU: pipelined 256^2, 200 blocks
        gemm_pipe<1><<<200, 512, 0, stream>>>(h, w1 + wofs, c1b + bof, qkv, DFF, 2);
        // ffn2 (128^2 + T1 grid), then residual+LN2
        gemm_bf16<0><<<800, 256, 0, stream>>>(qkv, w2 + wofs, c2b + bof, nullptr, t1,
                                              NTOK, DD, DFF, DFF, DD, 4);
        add_ln<true><<<NTOK / 4, 256, 0, stream>>>(h, t1, ln2s + bof, ln2b + bof);
    }
    add_ln<false><<<NTOK / 4, 256, 0, stream>>>(h, nullptr, lnfs, lnfb);
    proj_mfma<<<NTOK / 64, 256, 0, stream>>>(h, pwb, pb, (float*)d_out);
}

// Round 15
// 617.490 us; speedup vs baseline: 1.3153x; 1.1021x over previous
//
#include <hip/hip_runtime.h>
#include <math.h>

#define BB   256
#define LL   100
#define CIN  38
#define COUT 38
#define DD   512
#define HH   8
#define EE   3
#define DFF  512
#define DHD  64
#define NTOK (BB*LL)     // 25600
#define WELEM (EE*DD*DD) // 786432 elements per weight family
#define QKVN 1536        // packed QKV width

typedef __attribute__((ext_vector_type(8))) short bf16x8;
typedef __attribute__((ext_vector_type(4))) float f32x4;

__device__ __forceinline__ unsigned short f2bf(float f) {
    unsigned int u = __float_as_uint(f);
    unsigned int r = (u + 0x7FFFu + ((u >> 16) & 1u)) >> 16;
    return (unsigned short)r;
}
__device__ __forceinline__ float bf2f(unsigned short s) {
    return __uint_as_float(((unsigned int)s) << 16);
}

__device__ __forceinline__ void gl2lds16(const unsigned short* g, unsigned short* l) {
    __builtin_amdgcn_global_load_lds(
        (const __attribute__((address_space(1))) void*)g,
        (__attribute__((address_space(3))) void*)l, 16, 0, 0);
}

// paired-row XOR swizzle: 16B-unit index for logical (row, chunk c in 0..3) of a [256][32]bf16 tile.
__device__ __forceinline__ int swz(int row, int c) {
    int rp = row >> 1;
    int ch = c + ((row & 1) << 2);
    return rp * 8 + (ch ^ (rp & 7));
}

// ---------------------------------------------------------------- PE table
__global__ __launch_bounds__(256) void pe_kernel(float* __restrict__ pe) {
    int idx = blockIdx.x * 256 + threadIdx.x;
    if (idx >= LL * DD) return;
    int l = idx / DD, d = idx % DD;
    float e = (float)(d & ~1) * (-9.210340371976184f / (float)DD);
    float ang = (float)l * expf(e);
    pe[idx] = (d & 1) ? cosf(ang) : sinf(ang);
}

// ------------------------------------------------- mask -> additive bias
__global__ void expand_mask_kernel(const unsigned char* __restrict__ mraw,
                                   float* __restrict__ mb) {
    int i = blockIdx.x * 256 + threadIdx.x;
    if (i >= LL * LL) return;
    unsigned char b0 = mraw[0], b1 = mraw[1], b2 = mraw[2], b3 = mraw[3];
    bool v;
    if (b0 == 1 && b1 == 1)                      v = mraw[i] != 0;
    else if (b0 == 1 && b1 == 0 && b2 == 0 && b3 == 0)
                                                 v = ((const int*)mraw)[i] != 0;
    else if (b0 == 0x80 && b1 == 0x3F)           v = ((const unsigned short*)mraw)[i] != 0;
    else if (b0 == 0 && b1 == 0x3C)              v = ((const unsigned short*)mraw)[i] != 0;
    else if (b0 == 0 && b1 == 0 && b2 == 0x80 && b3 == 0x3F)
                                                 v = ((const float*)mraw)[i] != 0.f;
    else                                         v = mraw[i] != 0;
    mb[i] = v ? 0.f : -1.0e30f;
}

// ------------------------------------------------- fp32 -> bf16 bulk convert
__global__ __launch_bounds__(256) void cvt_kernel(const float* __restrict__ in,
                                                  unsigned short* __restrict__ out,
                                                  int n4) {
    int i = blockIdx.x * 256 + threadIdx.x;
    if (i >= n4) return;
    float4 f = ((const float4*)in)[i];
    unsigned short o0 = f2bf(f.x), o1 = f2bf(f.y), o2 = f2bf(f.z), o3 = f2bf(f.w);
    unsigned long long packed = (unsigned long long)o0 | ((unsigned long long)o1 << 16)
                              | ((unsigned long long)o2 << 32) | ((unsigned long long)o3 << 48);
    ((unsigned long long*)out)[i] = packed;
}

// ------------------------------------------------- Wq/Wk/Wv -> packed [l][1536][512] bf16
__global__ __launch_bounds__(256) void cvt_pack(const float* __restrict__ in,
                                                unsigned short* __restrict__ out,
                                                int fam) {
    int i = blockIdx.x * 256 + threadIdx.x;      // over WELEM/4
    if (i >= WELEM / 4) return;
    int l = i >> 16;                              // / (DD*DD/4 = 65536)
    int j = i & 65535;
    float4 f = ((const float4*)in)[i];
    unsigned short o0 = f2bf(f.x), o1 = f2bf(f.y), o2 = f2bf(f.z), o3 = f2bf(f.w);
    unsigned long long packed = (unsigned long long)o0 | ((unsigned long long)o1 << 16)
                              | ((unsigned long long)o2 << 32) | ((unsigned long long)o3 << 48);
    ((unsigned long long*)out)[(size_t)l * (3 * 65536) + (size_t)fam * 65536 + j] = packed;
}

// ------------------------------------------------- bq/bk/bv -> packed [l][1536] fp32
__global__ __launch_bounds__(256) void pack_bias(const float* __restrict__ bq,
                                                 const float* __restrict__ bk,
                                                 const float* __restrict__ bv,
                                                 float* __restrict__ out) {
    int idx = blockIdx.x * 256 + threadIdx.x;    // EE*1536
    if (idx >= EE * QKVN) return;
    int l = idx / QKVN, r = idx % QKVN, f = r >> 9, d = r & 511;
    const float* src = (f == 0) ? bq : (f == 1) ? bk : bv;
    out[idx] = src[l * DD + d];
}

// ------------------------------------------------- proj weights -> bf16, padded [48][512]
__global__ __launch_bounds__(256) void proj_cvt(const float* __restrict__ in,
                                                unsigned short* __restrict__ outp) {
    int i = blockIdx.x * 256 + threadIdx.x;
    if (i >= 48 * DD / 4) return;
    if (i < COUT * DD / 4) {
        float4 f = ((const float4*)in)[i];
        unsigned short o0 = f2bf(f.x), o1 = f2bf(f.y), o2 = f2bf(f.z), o3 = f2bf(f.w);
        unsigned long long packed = (unsigned long long)o0 | ((unsigned long long)o1 << 16)
                                  | ((unsigned long long)o2 << 32) | ((unsigned long long)o3 << 48);
        ((unsigned long long*)outp)[i] = packed;
    } else {
        ((unsigned long long*)outp)[i] = 0ull;
    }
}

// ------------------------------------------------- emb_w [512][38*3] -> bf16 [512][128] (K-pad)
__global__ __launch_bounds__(256) void ewb_cvt(const float* __restrict__ ew,
                                               unsigned short* __restrict__ out) {
    int idx = blockIdx.x * 256 + threadIdx.x;    // 512*128
    if (idx >= DD * 128) return;
    int d = idx >> 7, k = idx & 127;
    out[idx] = (k < 114) ? f2bf(ew[d * 114 + k]) : (unsigned short)0;
}

// ------------------------------------------------- x -> ub[25600][128] bf16 (circular gather)
__global__ __launch_bounds__(256) void ub_build(const float* __restrict__ x,
                                               unsigned short* __restrict__ ub) {
    int idx = blockIdx.x * 256 + threadIdx.x;    // NTOK*128
    if (idx >= NTOK * 128) return;
    int n = idx >> 7, k = idx & 127;
    float v = 0.f;
    if (k < 114) {
        int c = k / 3, t = k - 3 * c;
        int l = n % LL, b = n / LL;
        int ls = l + t - 1;
        ls = (ls < 0) ? (LL - 1) : (ls >= LL ? ls - LL : ls);
        v = x[(size_t)(b * LL + ls) * CIN + c];
    }
    ub[idx] = f2bf(v);
}

// ------------------------------------------------- bf16 MFMA GEMM (128x128), T1 1-D swizzled grid
// EPI: 0 = +bias, 1 = +bias+GELU, 2 = +pe[(row%LL)][col]
template<int EPI>
__global__ __launch_bounds__(256) void gemm_bf16(const unsigned short* __restrict__ A,
                                                 const unsigned short* __restrict__ W,
                                                 const float* __restrict__ bias,
                                                 const float* __restrict__ pe2,
                                                 unsigned short* __restrict__ C,
                                                 int M, int N, int K, int lda, int ldc,
                                                 int nbn) {
    __shared__ unsigned short As[128 * 32];
    __shared__ unsigned short Bs[128 * 32];
    const int tid  = threadIdx.x;
    const int tile = (blockIdx.x & 7) * ((int)gridDim.x >> 3) + (blockIdx.x >> 3);
    const int bn   = tile % nbn, bm = tile / nbn;
    const int w    = tid >> 6, lane = tid & 63;
    const int wr   = w >> 1,  wc   = w & 1;
    const int sRow = tid >> 2;
    const int sK   = (tid & 3) * 8;
    const unsigned short* Ag = A + (size_t)(bm * 128 + sRow) * lda + sK;
    const unsigned short* Wg = W + (size_t)(bn * 128 + sRow) * K + sK;
    unsigned short* AsD = As + tid * 8;
    unsigned short* BsD = Bs + tid * 8;
    const int fr = lane & 15, fq = lane >> 4;
    const int fo = fq * 8;

    f32x4 acc[4][4] = {};
    for (int k0 = 0; k0 < K; k0 += 32) {
        gl2lds16(Ag + k0, AsD);
        gl2lds16(Ag + k0 + (size_t)64 * lda, AsD + 64 * 32);
        gl2lds16(Wg + k0, BsD);
        gl2lds16(Wg + k0 + (size_t)64 * K, BsD + 64 * 32);
        __syncthreads();
        bf16x8 af[4], bfv[4];
        #pragma unroll
        for (int m = 0; m < 4; ++m)
            af[m] = *(const bf16x8*)(As + (wr * 64 + m * 16 + fr) * 32 + fo);
        #pragma unroll
        for (int n = 0; n < 4; ++n)
            bfv[n] = *(const bf16x8*)(Bs + (wc * 64 + n * 16 + fr) * 32 + fo);
        #pragma unroll
        for (int m = 0; m < 4; ++m)
            #pragma unroll
            for (int n = 0; n < 4; ++n)
                acc[m][n] = __builtin_amdgcn_mfma_f32_16x16x32_bf16(af[m], bfv[n], acc[m][n], 0, 0, 0);
        __syncthreads();
    }
    #pragma unroll
    for (int n = 0; n < 4; ++n) {
        int col = bn * 128 + wc * 64 + n * 16 + fr;
        float bv = (EPI != 2) ? bias[col] : 0.f;
        #pragma unroll
        for (int m = 0; m < 4; ++m) {
            #pragma unroll
            for (int j = 0; j < 4; ++j) {
                int row = bm * 128 + wr * 64 + m * 16 + fq * 4 + j;
                float v = acc[m][n][j] + bv;
                if (EPI == 1)
                    v = 0.5f * v * (1.f + erff(v * 0.70710678118654752f));
                if (EPI == 2)
                    v += pe2[(row % LL) * DD + col];
                C[(size_t)row * ldc + col] = f2bf(v);
            }
        }
    }
}

// ------------------------------------------------- pipelined 256x256 GEMM, K=512 fixed
// T2 swizzled LDS + counted vmcnt (3-slot ring) + T5 setprio + T1 grid; sector-merged epilogue.
template<int EPI>
__global__ __launch_bounds__(512) void gemm_pipe(const unsigned short* __restrict__ A,
                                                 const unsigned short* __restrict__ W,
                                                 const float* __restrict__ bias,
                                                 unsigned short* __restrict__ C,
                                                 int lda, int ldc, int nbn) {
    __shared__ __align__(16) unsigned short lds[3 * 16384];
    const int tid  = threadIdx.x;
    const int tile = ((int)blockIdx.x & 7) * ((int)gridDim.x >> 3) + ((int)blockIdx.x >> 3);
    const int bn   = tile % nbn, bm = tile / nbn;
    const int wid  = tid >> 6, lane = tid & 63;
    const int wr   = wid >> 2, wc = wid & 3;
    const int fr   = lane & 15, fq = lane >> 4;

    int rowS0, cS0, rowS1, cS1;
    { int u = tid;       int rp = u >> 3, q = u & 7, ch = q ^ (rp & 7); rowS0 = (rp << 1) + (ch >> 2); cS0 = ch & 3; }
    { int u = tid + 512; int rp = u >> 3, q = u & 7, ch = q ^ (rp & 7); rowS1 = (rp << 1) + (ch >> 2); cS1 = ch & 3; }
    const unsigned short* Ag0 = A + (size_t)(bm * 256 + rowS0) * lda + cS0 * 8;
    const unsigned short* Ag1 = A + (size_t)(bm * 256 + rowS1) * lda + cS1 * 8;
    const unsigned short* Wg0 = W + (size_t)(bn * 256 + rowS0) * 512 + cS0 * 8;
    const unsigned short* Wg1 = W + (size_t)(bn * 256 + rowS1) * 512 + cS1 * 8;
    unsigned short* dA0 = lds + tid * 8;

    int aoff[8], boff[4];
    #pragma unroll
    for (int m = 0; m < 8; ++m) aoff[m] = swz(wr * 128 + m * 16 + fr, fq) * 8;
    #pragma unroll
    for (int n = 0; n < 4; ++n) boff[n] = 8192 + swz(wc * 64 + n * 16 + fr, fq) * 8;

    f32x4 acc[8][4] = {};

    gl2lds16(Ag0,      dA0);
    gl2lds16(Ag1,      dA0 + 4096);
    gl2lds16(Wg0,      dA0 + 8192);
    gl2lds16(Wg1,      dA0 + 12288);
    gl2lds16(Ag0 + 32, dA0 + 16384);
    gl2lds16(Ag1 + 32, dA0 + 16384 + 4096);
    gl2lds16(Wg0 + 32, dA0 + 16384 + 8192);
    gl2lds16(Wg1 + 32, dA0 + 16384 + 12288);
    asm volatile("s_waitcnt vmcnt(4)" ::: "memory");
    __builtin_amdgcn_s_barrier();

    int st = 0;
    for (int t = 0; t < 16; ++t) {
        const unsigned short* S = lds + st * 16384;
        int pt = st + 2; if (pt >= 3) pt -= 3;
        const int koff = (t + 2) * 32;
        bf16x8 bfv[4], af[4];
        #pragma unroll
        for (int n = 0; n < 4; ++n) bfv[n] = *(const bf16x8*)(S + boff[n]);
        #pragma unroll
        for (int m = 0; m < 4; ++m) af[m] = *(const bf16x8*)(S + aoff[m]);
        if (t < 14) {
            gl2lds16(Ag0 + koff, dA0 + pt * 16384);
            gl2lds16(Ag1 + koff, dA0 + pt * 16384 + 4096);
        }
        __builtin_amdgcn_s_barrier();
        __builtin_amdgcn_s_setprio(1);
        #pragma unroll
        for (int m = 0; m < 4; ++m)
            #pragma unroll
            for (int n = 0; n < 4; ++n)
                acc[m][n] = __builtin_amdgcn_mfma_f32_16x16x32_bf16(af[m], bfv[n], acc[m][n], 0, 0, 0);
        __builtin_amdgcn_s_setprio(0);
        __builtin_amdgcn_s_barrier();
        #pragma unroll
        for (int m = 0; m < 4; ++m) af[m] = *(const bf16x8*)(S + aoff[4 + m]);
        if (t < 14) {
            gl2lds16(Wg0 + koff, dA0 + pt * 16384 + 8192);
            gl2lds16(Wg1 + koff, dA0 + pt * 16384 + 12288);
        }
        __builtin_amdgcn_s_barrier();
        __builtin_amdgcn_s_setprio(1);
        #pragma unroll
        for (int m = 0; m < 4; ++m)
            #pragma unroll
            for (int n = 0; n < 4; ++n)
                acc[4 + m][n] = __builtin_amdgcn_mfma_f32_16x16x32_bf16(af[m], bfv[n], acc[4 + m][n], 0, 0, 0);
        __builtin_amdgcn_s_setprio(0);
        if (t < 14) { asm volatile("s_waitcnt vmcnt(4)" ::: "memory"); }
        else        { asm volatile("s_waitcnt vmcnt(0)" ::: "memory"); }
        __builtin_amdgcn_s_barrier();
        if (++st == 3) st = 0;
    }

    float bvv[4];
    #pragma unroll
    for (int n = 0; n < 4; ++n) bvv[n] = bias[bn * 256 + wc * 64 + n * 16 + fr];
    #pragma unroll
    for (int m = 0; m < 8; ++m) {
        #pragma unroll
        for (int j = 0; j < 4; ++j) {
            int row = bm * 256 + wr * 128 + m * 16 + fq * 4 + j;
            unsigned short* Crow = C + (size_t)row * ldc + bn * 256 + wc * 64 + fr;
            #pragma unroll
            for (int n = 0; n < 4; ++n) {
                float v = acc[m][n][j] + bvv[n];
                if (EPI == 1)
                    v = 0.5f * v * (1.f + erff(v * 0.70710678118654752f));
                Crow[n * 16] = f2bf(v);
            }
        }
    }
}

// ------------------------------------------------- MFMA attention on packed qkv[n][1536]
// Q read from global per band (L2-hot); LDS 47104 B -> 3 blocks/CU.
__global__ __launch_bounds__(256) void attn_mfma(unsigned short* __restrict__ qkv,
                                                 const float* __restrict__ mbias) {
    __shared__ __align__(16) unsigned char lds[47104];
    const int KOFF = 0, VOFF = 14336, POFF = 30720;
    const int tid = threadIdx.x, wv = tid >> 6, lane = tid & 63;
    const int fr = lane & 15, fq = lane >> 4;
    const int b = blockIdx.x >> 3, hh = blockIdx.x & 7;
    unsigned short* qg = qkv + (size_t)(b * LL) * QKVN + hh * DHD;
    const unsigned short* kg = qg + 512;
    const unsigned short* vg = qg + 1024;

    for (int idx = tid; idx < 800; idx += 256) {
        int s = idx >> 3, c = idx & 7;
        uint4 kv = *(const uint4*)(kg + (size_t)s * QKVN + c * 8);
        uint4 vv = *(const uint4*)(vg + (size_t)s * QKVN + c * 8);
        int sw = (s & 7) << 4;
        *(uint4*)(lds + KOFF + s * 128 + ((c * 16) ^ sw)) = kv;
        unsigned int vs[4] = {vv.x, vv.y, vv.z, vv.w};
        #pragma unroll
        for (int e = 0; e < 4; ++e) {
            int d0 = c * 8 + e * 2, d1 = d0 + 1;
            *(unsigned short*)(lds + VOFF + d0 * 256 + ((s * 2) ^ ((d0 & 7) << 4))) = (unsigned short)(vs[e] & 0xFFFFu);
            *(unsigned short*)(lds + VOFF + d1 * 256 + ((s * 2) ^ ((d1 & 7) << 4))) = (unsigned short)(vs[e] >> 16);
        }
    }
    for (int idx = tid; idx < 96; idx += 256) {
        int r = 100 + (idx >> 3), c = idx & 7;
        *(uint4*)(lds + KOFF + r * 128 + ((c * 16) ^ ((r & 7) << 4))) = uint4{0u, 0u, 0u, 0u};
    }
    for (int idx = tid; idx < 896; idx += 256) {
        int d = idx / 14, s = 100 + 2 * (idx % 14);
        *(unsigned int*)(lds + VOFF + d * 256 + ((s * 2) ^ ((d & 7) << 4))) = 0u;
    }
    __syncthreads();

    const int pbase = POFF + wv * 4096;
    for (int bd = wv; bd < 7; bd += 4) {
        const unsigned short* qp = qg + (size_t)(bd * 16 + fr) * QKVN;
        bf16x8 aq0 = *(const bf16x8*)(qp + fq * 8);
        bf16x8 aq1 = *(const bf16x8*)(qp + 32 + fq * 8);
        f32x4 sv[7];
        #pragma unroll
        for (int ct = 0; ct < 7; ++ct) {
            int row = ct * 16 + fr, sw = (row & 7) << 4;
            bf16x8 bk0 = *(const bf16x8*)(lds + KOFF + row * 128 + ((fq * 16) ^ sw));
            bf16x8 bk1 = *(const bf16x8*)(lds + KOFF + row * 128 + ((64 + fq * 16) ^ sw));
            f32x4 a = {0.f, 0.f, 0.f, 0.f};
            a = __builtin_amdgcn_mfma_f32_16x16x32_bf16(aq0, bk0, a, 0, 0, 0);
            a = __builtin_amdgcn_mfma_f32_16x16x32_bf16(aq1, bk1, a, 0, 0, 0);
            sv[ct] = a;
        }
        const int rg0 = bd * 16 + fq * 4;
        #pragma unroll
        for (int ct = 0; ct < 7; ++ct) {
            int col = ct * 16 + fr;
            #pragma unroll
            for (int j = 0; j < 4; ++j) {
                int rg = rg0 + j;
                float bias = (rg < LL && col < LL) ? mbias[rg * LL + col] : -1.0e30f;
                sv[ct][j] = sv[ct][j] * 0.125f + bias;
            }
        }
        float inv[4];
        #pragma unroll
        for (int j = 0; j < 4; ++j) {
            float mx = sv[0][j];
            #pragma unroll
            for (int ct = 1; ct < 7; ++ct) mx = fmaxf(mx, sv[ct][j]);
            #pragma unroll
            for (int off = 8; off; off >>= 1) mx = fmaxf(mx, __shfl_xor(mx, off, 64));
            float sum = 0.f;
            #pragma unroll
            for (int ct = 0; ct < 7; ++ct) {
                float p = __expf(sv[ct][j] - mx);
                sv[ct][j] = p; sum += p;
            }
            #pragma unroll
            for (int off = 8; off; off >>= 1) sum += __shfl_xor(sum, off, 64);
            inv[j] = 1.f / sum;
        }
        asm volatile("s_waitcnt lgkmcnt(0)" ::: "memory");
        #pragma unroll
        for (int j = 0; j < 4; ++j) {
            int pr = fq * 4 + j, sw = (pr & 7) << 4;
            #pragma unroll
            for (int ct = 0; ct < 7; ++ct)
                *(unsigned short*)(lds + pbase + pr * 256 + ((ct * 32 + fr * 2) ^ sw)) = f2bf(sv[ct][j] * inv[j]);
            *(unsigned short*)(lds + pbase + pr * 256 + ((224 + fr * 2) ^ sw)) = 0;
        }
        asm volatile("s_waitcnt lgkmcnt(0)" ::: "memory");
        f32x4 oacc[4] = {};
        #pragma unroll
        for (int kt = 0; kt < 4; ++kt) {
            bf16x8 ap = *(const bf16x8*)(lds + pbase + fr * 256 + ((kt * 64 + fq * 16) ^ ((fr & 7) << 4)));
            #pragma unroll
            for (int n = 0; n < 4; ++n) {
                int d = n * 16 + fr, sw = (d & 7) << 4;
                bf16x8 bv = *(const bf16x8*)(lds + VOFF + d * 256 + ((kt * 64 + fq * 16) ^ sw));
                oacc[n] = __builtin_amdgcn_mfma_f32_16x16x32_bf16(ap, bv, oacc[n], 0, 0, 0);
            }
        }
        #pragma unroll
        for (int j = 0; j < 4; ++j) {
            int rg = rg0 + j;
            if (rg < LL) {
                #pragma unroll
                for (int n = 0; n < 4; ++n)
                    qg[(size_t)rg * QKVN + n * 16 + fr] = f2bf(oacc[n][j]);
            }
        }
    }
}

// ------------------------------------------------- residual + layernorm: wave-per-row, 4 rows/block
template<bool RES>
__global__ __launch_bounds__(256) void add_ln(unsigned short* __restrict__ h,
                                              const unsigned short* __restrict__ res,
                                              const float* __restrict__ sc,
                                              const float* __restrict__ bi) {
    const int wv = threadIdx.x >> 6, lane = threadIdx.x & 63;
    const int n = blockIdx.x * 4 + wv;
    unsigned short* hp = h + (size_t)n * DD + lane * 8;
    unsigned int u[4];
    *(uint4*)u = *(const uint4*)hp;
    float x[8];
    #pragma unroll
    for (int e = 0; e < 4; ++e) {
        x[2 * e]     = __uint_as_float(u[e] << 16);
        x[2 * e + 1] = __uint_as_float(u[e] & 0xFFFF0000u);
    }
    if (RES) {
        const unsigned short* rp = res + (size_t)n * DD + lane * 8;
        unsigned int r[4];
        *(uint4*)r = *(const uint4*)rp;
        #pragma unroll
        for (int e = 0; e < 4; ++e) {
            x[2 * e]     += __uint_as_float(r[e] << 16);
            x[2 * e + 1] += __uint_as_float(r[e] & 0xFFFF0000u);
        }
    }
    float s = 0.f, ss = 0.f;
    #pragma unroll
    for (int e = 0; e < 8; ++e) { s += x[e]; ss += x[e] * x[e]; }
    #pragma unroll
    for (int off = 32; off; off >>= 1) {
        s  += __shfl_xor(s, off, 64);
        ss += __shfl_xor(ss, off, 64);
    }
    float mean = s * (1.f / (float)DD);
    float var  = ss * (1.f / (float)DD) - mean * mean;
    float rstd = 1.f / sqrtf(var + 1e-5f);
    float4 s0 = *(const float4*)(sc + lane * 8), s1 = *(const float4*)(sc + lane * 8 + 4);
    float4 b0 = *(const float4*)(bi + lane * 8), b1 = *(const float4*)(bi + lane * 8 + 4);
    float scv[8] = {s0.x, s0.y, s0.z, s0.w, s1.x, s1.y, s1.z, s1.w};
    float biv[8] = {b0.x, b0.y, b0.z, b0.w, b1.x, b1.y, b1.z, b1.w};
    unsigned int o[4];
    #pragma unroll
    for (int e = 0; e < 4; ++e) {
        unsigned short lo = f2bf((x[2 * e]     - mean) * rstd * scv[2 * e]     + biv[2 * e]);
        unsigned short hi = f2bf((x[2 * e + 1] - mean) * rstd * scv[2 * e + 1] + biv[2 * e + 1]);
        o[e] = (unsigned int)lo | ((unsigned int)hi << 16);
    }
    *(uint4*)hp = *(uint4*)o;
}

// ------------------------------------------------- final projection via MFMA
__global__ __launch_bounds__(256) void proj_mfma(const unsigned short* __restrict__ hn,
                                                 const unsigned short* __restrict__ pwb,
                                                 const float* __restrict__ pb,
                                                 float* __restrict__ out) {
    const int tid = threadIdx.x, wv = tid >> 6, lane = tid & 63;
    const int fr = lane & 15, fq = lane >> 4;
    const int row0 = blockIdx.x * 64 + wv * 16;
    const unsigned short* aRow = hn + (size_t)(row0 + fr) * DD + fq * 8;
    f32x4 acc[3] = {};
    #pragma unroll 4
    for (int kt = 0; kt < 16; ++kt) {
        bf16x8 af = *(const bf16x8*)(aRow + kt * 32);
        #pragma unroll
        for (int n = 0; n < 3; ++n) {
            bf16x8 bfv = *(const bf16x8*)(pwb + (size_t)(n * 16 + fr) * DD + kt * 32 + fq * 8);
            acc[n] = __builtin_amdgcn_mfma_f32_16x16x32_bf16(af, bfv, acc[n], 0, 0, 0);
        }
    }
    #pragma unroll
    for (int n = 0; n < 3; ++n) {
        int col = n * 16 + fr;
        if (col < COUT) {
            float bias = pb[col];
            #pragma unroll
            for (int j = 0; j < 4; ++j) {
                int r = row0 + fq * 4 + j;
                out[(size_t)r * COUT + col] = acc[n][j] + bias;
            }
        }
    }
}

__global__ void sentinel_kernel(float* out, int n) {
    int i = blockIdx.x * 256 + threadIdx.x;
    if (i < n) out[i] = 1.0e4f;
}

extern "C" void kernel_launch(void* const* d_in, const int* in_sizes, int n_in,
                              void* d_out, int out_size, void* d_ws, size_t ws_size,
                              hipStream_t stream) {
    const float* x    = (const float*)d_in[0];
    const float* ew   = (const float*)d_in[1];
    const float* Wq   = (const float*)d_in[2];
    const float* bq   = (const float*)d_in[3];
    const float* Wk   = (const float*)d_in[4];
    const float* bk   = (const float*)d_in[5];
    const float* Wv   = (const float*)d_in[6];
    const float* bv   = (const float*)d_in[7];
    const float* Wo   = (const float*)d_in[8];
    const float* bo   = (const float*)d_in[9];
    const float* c1w  = (const float*)d_in[10];
    const float* c1b  = (const float*)d_in[11];
    const float* c2w  = (const float*)d_in[12];
    const float* c2b  = (const float*)d_in[13];
    const float* ln1s = (const float*)d_in[14];
    const float* ln1b = (const float*)d_in[15];
    const float* ln2s = (const float*)d_in[16];
    const float* ln2b = (const float*)d_in[17];
    const float* lnfs = (const float*)d_in[18];
    const float* lnfb = (const float*)d_in[19];
    const float* pw   = (const float*)d_in[20];
    const float* pb   = (const float*)d_in[21];
    const unsigned char* mraw = (const unsigned char*)d_in[22];

    const size_t NB   = (size_t)NTOK * DD;       // 13,107,200
    const size_t PWB  = 48 * DD;
    const size_t EWB  = (size_t)DD * 128;
    const size_t UB   = (size_t)NTOK * 128;
    const size_t need = (5 * NB + 6 * (size_t)WELEM + PWB + EWB + UB) * 2
                      + ((size_t)EE * QKVN + (size_t)LL * DD + (size_t)LL * LL) * 4;
    if (ws_size < need) {
        sentinel_kernel<<<(out_size + 255) / 256, 256, 0, stream>>>((float*)d_out, out_size);
        return;
    }
    unsigned short* h    = (unsigned short*)d_ws;
    unsigned short* qkv  = h + NB;               // 3*NB (QKV out; also FFN-mid scratch)
    unsigned short* t1   = qkv + 3 * NB;         // o-proj / ffn2 output
    unsigned short* wqkv = t1 + NB;              // 3*WELEM packed
    unsigned short* wo   = wqkv + 3 * WELEM;
    unsigned short* w1   = wo + WELEM;
    unsigned short* w2   = w1 + WELEM;
    unsigned short* pwb  = w2 + WELEM;
    unsigned short* ewb  = pwb + PWB;
    unsigned short* ub   = ewb + EWB;
    float* bqkv = (float*)(ub + UB);
    float* pe   = bqkv + EE * QKVN;
    float* mb   = pe + LL * DD;

    pe_kernel<<<(LL * DD + 255) / 256, 256, 0, stream>>>(pe);
    expand_mask_kernel<<<(LL * LL + 255) / 256, 256, 0, stream>>>(mraw, mb);
    const int cg = WELEM / 4 / 256;   // 768
    cvt_pack<<<cg, 256, 0, stream>>>(Wq, wqkv, 0);
    cvt_pack<<<cg, 256, 0, stream>>>(Wk, wqkv, 1);
    cvt_pack<<<cg, 256, 0, stream>>>(Wv, wqkv, 2);
    pack_bias<<<(EE * QKVN + 255) / 256, 256, 0, stream>>>(bq, bk, bv, bqkv);
    cvt_kernel<<<cg, 256, 0, stream>>>(Wo,  wo, WELEM / 4);
    cvt_kernel<<<cg, 256, 0, stream>>>(c1w, w1, WELEM / 4);
    cvt_kernel<<<cg, 256, 0, stream>>>(c2w, w2, WELEM / 4);
    proj_cvt<<<(48 * DD / 4 + 255) / 256, 256, 0, stream>>>(pw, pwb);
    ewb_cvt<<<(DD * 128 + 255) / 256, 256, 0, stream>>>(ew, ewb);
    ub_build<<<(NTOK * 128 + 255) / 256, 256, 0, stream>>>(x, ub);

    // embed as MFMA GEMM: h = ub @ ewb^T + PE  (128^2 kernel, K=128)
    gemm_bf16<2><<<800, 256, 0, stream>>>(ub, ewb, nullptr, pe, h, NTOK, DD, 128, 128, DD, 4);

    for (int l = 0; l < EE; ++l) {
        const size_t wofs = (size_t)l * DD * DD;
        const size_t bof  = (size_t)l * DD;
        // QKV: pipelined 256^2, 600 blocks (T1-chunked), 3-slot ring
        gemm_pipe<0><<<600, 512, 0, stream>>>(h, wqkv + (size_t)l * 3 * DD * DD,
                                              bqkv + l * QKVN, qkv, DD, QKVN, 6);
        attn_mfma<<<BB * HH, 256, 0, stream>>>(qkv, mb);
        // o-proj: pipelined 256^2, 200 blocks (A = attn-out slice of qkv, lda=1536)
        gemm_pipe<0><<<200, 512, 0, stream>>>(qkv, wo + wofs, bo + bof, t1, QKVN, DD, 2);
        add_ln<true><<<NTOK / 4, 256, 0, stream>>>(h, t1, ln1s + bof, ln1b + bof);
        // ffn1 + GELU: pipelined 256^2, 200 blocks
        gemm_pipe<1><<<200, 512, 0, stream>>>(h, w1 + wofs, c1b + bof, qkv, DD, DFF, 2);
        // ffn2: pipelined 256^2, 200 blocks
        gemm_pipe<0><<<200, 512, 0, stream>>>(qkv, w2 + wofs, c2b + bof, t1, DFF, DD, 2);
        add_ln<true><<<NTOK / 4, 256, 0, stream>>>(h, t1, ln2s + bof, ln2b + bof);
    }
    add_ln<false><<<NTOK / 4, 256, 0, stream>>>(h, nullptr, lnfs, lnfb);
    proj_mfma<<<NTOK / 64, 256, 0, stream>>>(h, pwb, pb, (float*)d_out);
}

// Round 16
// 597.968 us; speedup vs baseline: 1.3582x; 1.0326x over previous
//
#include <hip/hip_runtime.h>
#include <math.h>

#define BB   256
#define LL   100
#define CIN  38
#define COUT 38
#define DD   512
#define HH   8
#define EE   3
#define DFF  512
#define DHD  64
#define NTOK (BB*LL)     // 25600
#define WELEM (EE*DD*DD) // 786432 elements per weight family
#define QKVN 1536        // packed QKV width

typedef __attribute__((ext_vector_type(8))) short bf16x8;
typedef __attribute__((ext_vector_type(4))) float f32x4;

__device__ __forceinline__ unsigned short f2bf(float f) {
    unsigned int u = __float_as_uint(f);
    unsigned int r = (u + 0x7FFFu + ((u >> 16) & 1u)) >> 16;
    return (unsigned short)r;
}
__device__ __forceinline__ float bf2f(unsigned short s) {
    return __uint_as_float(((unsigned int)s) << 16);
}

__device__ __forceinline__ void gl2lds16(const unsigned short* g, unsigned short* l) {
    __builtin_amdgcn_global_load_lds(
        (const __attribute__((address_space(1))) void*)g,
        (__attribute__((address_space(3))) void*)l, 16, 0, 0);
}

// paired-row XOR swizzle: 16B-unit index for logical (row, chunk c in 0..3) of a [*][32]bf16 tile.
__device__ __forceinline__ int swz(int row, int c) {
    int rp = row >> 1;
    int ch = c + ((row & 1) << 2);
    return rp * 8 + (ch ^ (rp & 7));
}

// ---------------------------------------------------------------- PE table
__global__ __launch_bounds__(256) void pe_kernel(float* __restrict__ pe) {
    int idx = blockIdx.x * 256 + threadIdx.x;
    if (idx >= LL * DD) return;
    int l = idx / DD, d = idx % DD;
    float e = (float)(d & ~1) * (-9.210340371976184f / (float)DD);
    float ang = (float)l * expf(e);
    pe[idx] = (d & 1) ? cosf(ang) : sinf(ang);
}

// ------------------------------------------------- mask -> additive bias
__global__ void expand_mask_kernel(const unsigned char* __restrict__ mraw,
                                   float* __restrict__ mb) {
    int i = blockIdx.x * 256 + threadIdx.x;
    if (i >= LL * LL) return;
    unsigned char b0 = mraw[0], b1 = mraw[1], b2 = mraw[2], b3 = mraw[3];
    bool v;
    if (b0 == 1 && b1 == 1)                      v = mraw[i] != 0;
    else if (b0 == 1 && b1 == 0 && b2 == 0 && b3 == 0)
                                                 v = ((const int*)mraw)[i] != 0;
    else if (b0 == 0x80 && b1 == 0x3F)           v = ((const unsigned short*)mraw)[i] != 0;
    else if (b0 == 0 && b1 == 0x3C)              v = ((const unsigned short*)mraw)[i] != 0;
    else if (b0 == 0 && b1 == 0 && b2 == 0x80 && b3 == 0x3F)
                                                 v = ((const float*)mraw)[i] != 0.f;
    else                                         v = mraw[i] != 0;
    mb[i] = v ? 0.f : -1.0e30f;
}

// ------------------------------------------------- all six weight families -> bf16 (one dispatch)
__global__ __launch_bounds__(256) void cvt6(const float* __restrict__ Wq,
                                            const float* __restrict__ Wk,
                                            const float* __restrict__ Wv,
                                            const float* __restrict__ Wo,
                                            const float* __restrict__ c1w,
                                            const float* __restrict__ c2w,
                                            unsigned short* __restrict__ wqkv,
                                            unsigned short* __restrict__ wo,
                                            unsigned short* __restrict__ w1,
                                            unsigned short* __restrict__ w2) {
    const int Q4 = WELEM / 4;                    // 196608 8B-chunks per family
    int i = blockIdx.x * 256 + threadIdx.x;
    if (i >= 6 * Q4) return;
    int fam = i / Q4, j = i - fam * Q4;
    const float* src = (fam == 0) ? Wq : (fam == 1) ? Wk : (fam == 2) ? Wv
                     : (fam == 3) ? Wo : (fam == 4) ? c1w : c2w;
    float4 f = ((const float4*)src)[j];
    unsigned short o0 = f2bf(f.x), o1 = f2bf(f.y), o2 = f2bf(f.z), o3 = f2bf(f.w);
    unsigned long long packed = (unsigned long long)o0 | ((unsigned long long)o1 << 16)
                              | ((unsigned long long)o2 << 32) | ((unsigned long long)o3 << 48);
    if (fam < 3) {
        int l = j >> 16, jj = j & 65535;         // DD*DD/4 = 65536 chunks per layer
        ((unsigned long long*)wqkv)[(size_t)l * (3 * 65536) + (size_t)fam * 65536 + jj] = packed;
    } else {
        unsigned long long* dst = (fam == 3) ? (unsigned long long*)wo
                                : (fam == 4) ? (unsigned long long*)w1
                                             : (unsigned long long*)w2;
        dst[j] = packed;
    }
}

// ------------------------------------------------- bq/bk/bv -> packed [l][1536] fp32
__global__ __launch_bounds__(256) void pack_bias(const float* __restrict__ bq,
                                                 const float* __restrict__ bk,
                                                 const float* __restrict__ bv,
                                                 float* __restrict__ out) {
    int idx = blockIdx.x * 256 + threadIdx.x;    // EE*1536
    if (idx >= EE * QKVN) return;
    int l = idx / QKVN, r = idx % QKVN, f = r >> 9, d = r & 511;
    const float* src = (f == 0) ? bq : (f == 1) ? bk : bv;
    out[idx] = src[l * DD + d];
}

// ------------------------------------------------- proj weights -> bf16, padded [48][512]
__global__ __launch_bounds__(256) void proj_cvt(const float* __restrict__ in,
                                                unsigned short* __restrict__ outp) {
    int i = blockIdx.x * 256 + threadIdx.x;
    if (i >= 48 * DD / 4) return;
    if (i < COUT * DD / 4) {
        float4 f = ((const float4*)in)[i];
        unsigned short o0 = f2bf(f.x), o1 = f2bf(f.y), o2 = f2bf(f.z), o3 = f2bf(f.w);
        unsigned long long packed = (unsigned long long)o0 | ((unsigned long long)o1 << 16)
                                  | ((unsigned long long)o2 << 32) | ((unsigned long long)o3 << 48);
        ((unsigned long long*)outp)[i] = packed;
    } else {
        ((unsigned long long*)outp)[i] = 0ull;
    }
}

// ------------------------------------------------- emb_w [512][38*3] -> bf16 [512][128] (K-pad)
__global__ __launch_bounds__(256) void ewb_cvt(const float* __restrict__ ew,
                                               unsigned short* __restrict__ out) {
    int idx = blockIdx.x * 256 + threadIdx.x;    // 512*128
    if (idx >= DD * 128) return;
    int d = idx >> 7, k = idx & 127;
    out[idx] = (k < 114) ? f2bf(ew[d * 114 + k]) : (unsigned short)0;
}

// ------------------------------------------------- x -> ub[25600][128] bf16 (circular gather)
__global__ __launch_bounds__(256) void ub_build(const float* __restrict__ x,
                                               unsigned short* __restrict__ ub) {
    int idx = blockIdx.x * 256 + threadIdx.x;    // NTOK*128
    if (idx >= NTOK * 128) return;
    int n = idx >> 7, k = idx & 127;
    float v = 0.f;
    if (k < 114) {
        int c = k / 3, t = k - 3 * c;
        int l = n % LL, b = n / LL;
        int ls = l + t - 1;
        ls = (ls < 0) ? (LL - 1) : (ls >= LL ? ls - LL : ls);
        v = x[(size_t)(b * LL + ls) * CIN + c];
    }
    ub[idx] = f2bf(v);
}

// ------------------------------------------------- bf16 MFMA GEMM (128x128), T1 grid (embed)
template<int EPI>
__global__ __launch_bounds__(256) void gemm_bf16(const unsigned short* __restrict__ A,
                                                 const unsigned short* __restrict__ W,
                                                 const float* __restrict__ bias,
                                                 const float* __restrict__ pe2,
                                                 unsigned short* __restrict__ C,
                                                 int M, int N, int K, int lda, int ldc,
                                                 int nbn) {
    __shared__ unsigned short As[128 * 32];
    __shared__ unsigned short Bs[128 * 32];
    const int tid  = threadIdx.x;
    const int tile = (blockIdx.x & 7) * ((int)gridDim.x >> 3) + (blockIdx.x >> 3);
    const int bn   = tile % nbn, bm = tile / nbn;
    const int w    = tid >> 6, lane = tid & 63;
    const int wr   = w >> 1,  wc   = w & 1;
    const int sRow = tid >> 2;
    const int sK   = (tid & 3) * 8;
    const unsigned short* Ag = A + (size_t)(bm * 128 + sRow) * lda + sK;
    const unsigned short* Wg = W + (size_t)(bn * 128 + sRow) * K + sK;
    unsigned short* AsD = As + tid * 8;
    unsigned short* BsD = Bs + tid * 8;
    const int fr = lane & 15, fq = lane >> 4;
    const int fo = fq * 8;

    f32x4 acc[4][4] = {};
    for (int k0 = 0; k0 < K; k0 += 32) {
        gl2lds16(Ag + k0, AsD);
        gl2lds16(Ag + k0 + (size_t)64 * lda, AsD + 64 * 32);
        gl2lds16(Wg + k0, BsD);
        gl2lds16(Wg + k0 + (size_t)64 * K, BsD + 64 * 32);
        __syncthreads();
        bf16x8 af[4], bfv[4];
        #pragma unroll
        for (int m = 0; m < 4; ++m)
            af[m] = *(const bf16x8*)(As + (wr * 64 + m * 16 + fr) * 32 + fo);
        #pragma unroll
        for (int n = 0; n < 4; ++n)
            bfv[n] = *(const bf16x8*)(Bs + (wc * 64 + n * 16 + fr) * 32 + fo);
        #pragma unroll
        for (int m = 0; m < 4; ++m)
            #pragma unroll
            for (int n = 0; n < 4; ++n)
                acc[m][n] = __builtin_amdgcn_mfma_f32_16x16x32_bf16(af[m], bfv[n], acc[m][n], 0, 0, 0);
        __syncthreads();
    }
    #pragma unroll
    for (int n = 0; n < 4; ++n) {
        int col = bn * 128 + wc * 64 + n * 16 + fr;
        float bv = (EPI != 2) ? bias[col] : 0.f;
        #pragma unroll
        for (int m = 0; m < 4; ++m) {
            #pragma unroll
            for (int j = 0; j < 4; ++j) {
                int row = bm * 128 + wr * 64 + m * 16 + fq * 4 + j;
                float v = acc[m][n][j] + bv;
                if (EPI == 1)
                    v = 0.5f * v * (1.f + erff(v * 0.70710678118654752f));
                if (EPI == 2)
                    v += pe2[(row % LL) * DD + col];
                C[(size_t)row * ldc + col] = f2bf(v);
            }
        }
    }
}

// ------------------------------------------------- pipelined 256x256 GEMM, K=512 (QKV; r11 best)
template<int EPI>
__global__ __launch_bounds__(512) void gemm_pipe(const unsigned short* __restrict__ A,
                                                 const unsigned short* __restrict__ W,
                                                 const float* __restrict__ bias,
                                                 unsigned short* __restrict__ C,
                                                 int lda, int ldc, int nbn) {
    __shared__ __align__(16) unsigned short lds[3 * 16384];
    const int tid  = threadIdx.x;
    const int tile = ((int)blockIdx.x & 7) * ((int)gridDim.x >> 3) + ((int)blockIdx.x >> 3);
    const int bn   = tile % nbn, bm = tile / nbn;
    const int wid  = tid >> 6, lane = tid & 63;
    const int wr   = wid >> 2, wc = wid & 3;
    const int fr   = lane & 15, fq = lane >> 4;

    int rowS0, cS0, rowS1, cS1;
    { int u = tid;       int rp = u >> 3, q = u & 7, ch = q ^ (rp & 7); rowS0 = (rp << 1) + (ch >> 2); cS0 = ch & 3; }
    { int u = tid + 512; int rp = u >> 3, q = u & 7, ch = q ^ (rp & 7); rowS1 = (rp << 1) + (ch >> 2); cS1 = ch & 3; }
    const unsigned short* Ag0 = A + (size_t)(bm * 256 + rowS0) * lda + cS0 * 8;
    const unsigned short* Ag1 = A + (size_t)(bm * 256 + rowS1) * lda + cS1 * 8;
    const unsigned short* Wg0 = W + (size_t)(bn * 256 + rowS0) * 512 + cS0 * 8;
    const unsigned short* Wg1 = W + (size_t)(bn * 256 + rowS1) * 512 + cS1 * 8;
    unsigned short* dA0 = lds + tid * 8;

    int aoff[8], boff[4];
    #pragma unroll
    for (int m = 0; m < 8; ++m) aoff[m] = swz(wr * 128 + m * 16 + fr, fq) * 8;
    #pragma unroll
    for (int n = 0; n < 4; ++n) boff[n] = 8192 + swz(wc * 64 + n * 16 + fr, fq) * 8;

    f32x4 acc[8][4] = {};

    gl2lds16(Ag0,      dA0);
    gl2lds16(Ag1,      dA0 + 4096);
    gl2lds16(Wg0,      dA0 + 8192);
    gl2lds16(Wg1,      dA0 + 12288);
    gl2lds16(Ag0 + 32, dA0 + 16384);
    gl2lds16(Ag1 + 32, dA0 + 16384 + 4096);
    gl2lds16(Wg0 + 32, dA0 + 16384 + 8192);
    gl2lds16(Wg1 + 32, dA0 + 16384 + 12288);
    asm volatile("s_waitcnt vmcnt(4)" ::: "memory");
    __builtin_amdgcn_s_barrier();

    int st = 0;
    for (int t = 0; t < 16; ++t) {
        const unsigned short* S = lds + st * 16384;
        int pt = st + 2; if (pt >= 3) pt -= 3;
        const int koff = (t + 2) * 32;
        bf16x8 bfv[4], af[4];
        #pragma unroll
        for (int n = 0; n < 4; ++n) bfv[n] = *(const bf16x8*)(S + boff[n]);
        #pragma unroll
        for (int m = 0; m < 4; ++m) af[m] = *(const bf16x8*)(S + aoff[m]);
        if (t < 14) {
            gl2lds16(Ag0 + koff, dA0 + pt * 16384);
            gl2lds16(Ag1 + koff, dA0 + pt * 16384 + 4096);
        }
        __builtin_amdgcn_s_barrier();
        __builtin_amdgcn_s_setprio(1);
        #pragma unroll
        for (int m = 0; m < 4; ++m)
            #pragma unroll
            for (int n = 0; n < 4; ++n)
                acc[m][n] = __builtin_amdgcn_mfma_f32_16x16x32_bf16(af[m], bfv[n], acc[m][n], 0, 0, 0);
        __builtin_amdgcn_s_setprio(0);
        __builtin_amdgcn_s_barrier();
        #pragma unroll
        for (int m = 0; m < 4; ++m) af[m] = *(const bf16x8*)(S + aoff[4 + m]);
        if (t < 14) {
            gl2lds16(Wg0 + koff, dA0 + pt * 16384 + 8192);
            gl2lds16(Wg1 + koff, dA0 + pt * 16384 + 12288);
        }
        __builtin_amdgcn_s_barrier();
        __builtin_amdgcn_s_setprio(1);
        #pragma unroll
        for (int m = 0; m < 4; ++m)
            #pragma unroll
            for (int n = 0; n < 4; ++n)
                acc[4 + m][n] = __builtin_amdgcn_mfma_f32_16x16x32_bf16(af[m], bfv[n], acc[4 + m][n], 0, 0, 0);
        __builtin_amdgcn_s_setprio(0);
        if (t < 14) { asm volatile("s_waitcnt vmcnt(4)" ::: "memory"); }
        else        { asm volatile("s_waitcnt vmcnt(0)" ::: "memory"); }
        __builtin_amdgcn_s_barrier();
        if (++st == 3) st = 0;
    }

    float bvv[4];
    #pragma unroll
    for (int n = 0; n < 4; ++n) bvv[n] = bias[bn * 256 + wc * 64 + n * 16 + fr];
    #pragma unroll
    for (int m = 0; m < 8; ++m) {
        #pragma unroll
        for (int j = 0; j < 4; ++j) {
            int row = bm * 256 + wr * 128 + m * 16 + fq * 4 + j;
            unsigned short* Crow = C + (size_t)row * ldc + bn * 256 + wc * 64 + fr;
            #pragma unroll
            for (int n = 0; n < 4; ++n) {
                float v = acc[m][n][j] + bvv[n];
                if (EPI == 1)
                    v = 0.5f * v * (1.f + erff(v * 0.70710678118654752f));
                Crow[n * 16] = f2bf(v);
            }
        }
    }
}

// ------------------------------------------------- pipelined 128x256 GEMM, K=512 (N=512 ops)
// Same r11 ring discipline; 24KB/slot x3 = 72KB -> 2 blocks/CU. 3 loads/K-tile -> vmcnt(3).
// 8 waves (2M x 4N), per-wave 64x64 out, single 16-MFMA phase per K-tile.
template<int EPI>
__global__ __launch_bounds__(512) void gemm_pipe2(const unsigned short* __restrict__ A,
                                                  const unsigned short* __restrict__ W,
                                                  const float* __restrict__ bias,
                                                  unsigned short* __restrict__ C,
                                                  int lda, int ldc, int nbn) {
    __shared__ __align__(16) unsigned short lds[3 * 12288];   // 72 KB
    const int tid  = threadIdx.x;
    const int tile = ((int)blockIdx.x & 7) * ((int)gridDim.x >> 3) + ((int)blockIdx.x >> 3);
    const int bn   = tile % nbn, bm = tile / nbn;
    const int wid  = tid >> 6, lane = tid & 63;
    const int wr   = wid >> 2, wc = wid & 3;       // 2 x 4
    const int fr   = lane & 15, fq = lane >> 4;

    // staging decode (inverse swizzle): A unit = tid (128 rows); B units = tid, tid+512 (256 rows)
    int rowA, cA, rowB0, cB0, rowB1, cB1;
    { int u = tid;       int rp = u >> 3, q = u & 7, ch = q ^ (rp & 7); rowA  = (rp << 1) + (ch >> 2); cA  = ch & 3; }
    { int u = tid;       int rp = u >> 3, q = u & 7, ch = q ^ (rp & 7); rowB0 = (rp << 1) + (ch >> 2); cB0 = ch & 3; }
    { int u = tid + 512; int rp = u >> 3, q = u & 7, ch = q ^ (rp & 7); rowB1 = (rp << 1) + (ch >> 2); cB1 = ch & 3; }
    const unsigned short* Ag  = A + (size_t)(bm * 128 + rowA)  * lda + cA  * 8;
    const unsigned short* Wg0 = W + (size_t)(bn * 256 + rowB0) * 512 + cB0 * 8;
    const unsigned short* Wg1 = W + (size_t)(bn * 256 + rowB1) * 512 + cB1 * 8;
    unsigned short* dA = lds + tid * 8;            // A region [0,4096); B at +4096 (tid), +8192 (tid+512)

    int aoff[4], boff[4];
    #pragma unroll
    for (int m = 0; m < 4; ++m) aoff[m] = swz(wr * 64 + m * 16 + fr, fq) * 8;
    #pragma unroll
    for (int n = 0; n < 4; ++n) boff[n] = 4096 + swz(wc * 64 + n * 16 + fr, fq) * 8;

    f32x4 acc[4][4] = {};

    // prologue: tiles 0,1 (3 loads each); wait tile0, leave tile1's 3 in flight
    gl2lds16(Ag,       dA);
    gl2lds16(Wg0,      dA + 4096);
    gl2lds16(Wg1,      dA + 8192);
    gl2lds16(Ag  + 32, dA + 12288);
    gl2lds16(Wg0 + 32, dA + 12288 + 4096);
    gl2lds16(Wg1 + 32, dA + 12288 + 8192);
    asm volatile("s_waitcnt vmcnt(3)" ::: "memory");
    __builtin_amdgcn_s_barrier();

    int st = 0;
    for (int t = 0; t < 16; ++t) {
        const unsigned short* S = lds + st * 12288;
        int pt = st + 2; if (pt >= 3) pt -= 3;
        const int koff = (t + 2) * 32;
        bf16x8 bfv[4], af[4];
        #pragma unroll
        for (int n = 0; n < 4; ++n) bfv[n] = *(const bf16x8*)(S + boff[n]);
        #pragma unroll
        for (int m = 0; m < 4; ++m) af[m] = *(const bf16x8*)(S + aoff[m]);
        if (t < 14) {
            gl2lds16(Ag  + koff, dA + pt * 12288);
            gl2lds16(Wg0 + koff, dA + pt * 12288 + 4096);
            gl2lds16(Wg1 + koff, dA + pt * 12288 + 8192);
        }
        __builtin_amdgcn_s_barrier();
        __builtin_amdgcn_s_setprio(1);
        #pragma unroll
        for (int m = 0; m < 4; ++m)
            #pragma unroll
            for (int n = 0; n < 4; ++n)
                acc[m][n] = __builtin_amdgcn_mfma_f32_16x16x32_bf16(af[m], bfv[n], acc[m][n], 0, 0, 0);
        __builtin_amdgcn_s_setprio(0);
        if (t < 14) { asm volatile("s_waitcnt vmcnt(3)" ::: "memory"); }
        else        { asm volatile("s_waitcnt vmcnt(0)" ::: "memory"); }
        __builtin_amdgcn_s_barrier();
        if (++st == 3) st = 0;
    }

    float bvv[4];
    #pragma unroll
    for (int n = 0; n < 4; ++n) bvv[n] = bias[bn * 256 + wc * 64 + n * 16 + fr];
    #pragma unroll
    for (int m = 0; m < 4; ++m) {
        #pragma unroll
        for (int j = 0; j < 4; ++j) {
            int row = bm * 128 + wr * 64 + m * 16 + fq * 4 + j;
            unsigned short* Crow = C + (size_t)row * ldc + bn * 256 + wc * 64 + fr;
            #pragma unroll
            for (int n = 0; n < 4; ++n) {
                float v = acc[m][n][j] + bvv[n];
                if (EPI == 1)
                    v = 0.5f * v * (1.f + erff(v * 0.70710678118654752f));
                Crow[n * 16] = f2bf(v);
            }
        }
    }
}

// ------------------------------------------------- MFMA attention on packed qkv[n][1536]
__global__ __launch_bounds__(256) void attn_mfma(unsigned short* __restrict__ qkv,
                                                 const float* __restrict__ mbias) {
    __shared__ __align__(16) unsigned char lds[47104];
    const int KOFF = 0, VOFF = 14336, POFF = 30720;
    const int tid = threadIdx.x, wv = tid >> 6, lane = tid & 63;
    const int fr = lane & 15, fq = lane >> 4;
    const int b = blockIdx.x >> 3, hh = blockIdx.x & 7;
    unsigned short* qg = qkv + (size_t)(b * LL) * QKVN + hh * DHD;
    const unsigned short* kg = qg + 512;
    const unsigned short* vg = qg + 1024;

    for (int idx = tid; idx < 800; idx += 256) {
        int s = idx >> 3, c = idx & 7;
        uint4 kv = *(const uint4*)(kg + (size_t)s * QKVN + c * 8);
        uint4 vv = *(const uint4*)(vg + (size_t)s * QKVN + c * 8);
        int sw = (s & 7) << 4;
        *(uint4*)(lds + KOFF + s * 128 + ((c * 16) ^ sw)) = kv;
        unsigned int vs[4] = {vv.x, vv.y, vv.z, vv.w};
        #pragma unroll
        for (int e = 0; e < 4; ++e) {
            int d0 = c * 8 + e * 2, d1 = d0 + 1;
            *(unsigned short*)(lds + VOFF + d0 * 256 + ((s * 2) ^ ((d0 & 7) << 4))) = (unsigned short)(vs[e] & 0xFFFFu);
            *(unsigned short*)(lds + VOFF + d1 * 256 + ((s * 2) ^ ((d1 & 7) << 4))) = (unsigned short)(vs[e] >> 16);
        }
    }
    for (int idx = tid; idx < 96; idx += 256) {
        int r = 100 + (idx >> 3), c = idx & 7;
        *(uint4*)(lds + KOFF + r * 128 + ((c * 16) ^ ((r & 7) << 4))) = uint4{0u, 0u, 0u, 0u};
    }
    for (int idx = tid; idx < 896; idx += 256) {
        int d = idx / 14, s = 100 + 2 * (idx % 14);
        *(unsigned int*)(lds + VOFF + d * 256 + ((s * 2) ^ ((d & 7) << 4))) = 0u;
    }
    __syncthreads();

    const int pbase = POFF + wv * 4096;
    for (int bd = wv; bd < 7; bd += 4) {
        const unsigned short* qp = qg + (size_t)(bd * 16 + fr) * QKVN;
        bf16x8 aq0 = *(const bf16x8*)(qp + fq * 8);
        bf16x8 aq1 = *(const bf16x8*)(qp + 32 + fq * 8);
        f32x4 sv[7];
        #pragma unroll
        for (int ct = 0; ct < 7; ++ct) {
            int row = ct * 16 + fr, sw = (row & 7) << 4;
            bf16x8 bk0 = *(const bf16x8*)(lds + KOFF + row * 128 + ((fq * 16) ^ sw));
            bf16x8 bk1 = *(const bf16x8*)(lds + KOFF + row * 128 + ((64 + fq * 16) ^ sw));
            f32x4 a = {0.f, 0.f, 0.f, 0.f};
            a = __builtin_amdgcn_mfma_f32_16x16x32_bf16(aq0, bk0, a, 0, 0, 0);
            a = __builtin_amdgcn_mfma_f32_16x16x32_bf16(aq1, bk1, a, 0, 0, 0);
            sv[ct] = a;
        }
        const int rg0 = bd * 16 + fq * 4;
        #pragma unroll
        for (int ct = 0; ct < 7; ++ct) {
            int col = ct * 16 + fr;
            #pragma unroll
            for (int j = 0; j < 4; ++j) {
                int rg = rg0 + j;
                float bias = (rg < LL && col < LL) ? mbias[rg * LL + col] : -1.0e30f;
                sv[ct][j] = sv[ct][j] * 0.125f + bias;
            }
        }
        float inv[4];
        #pragma unroll
        for (int j = 0; j < 4; ++j) {
            float mx = sv[0][j];
            #pragma unroll
            for (int ct = 1; ct < 7; ++ct) mx = fmaxf(mx, sv[ct][j]);
            #pragma unroll
            for (int off = 8; off; off >>= 1) mx = fmaxf(mx, __shfl_xor(mx, off, 64));
            float sum = 0.f;
            #pragma unroll
            for (int ct = 0; ct < 7; ++ct) {
                float p = __expf(sv[ct][j] - mx);
                sv[ct][j] = p; sum += p;
            }
            #pragma unroll
            for (int off = 8; off; off >>= 1) sum += __shfl_xor(sum, off, 64);
            inv[j] = 1.f / sum;
        }
        asm volatile("s_waitcnt lgkmcnt(0)" ::: "memory");
        #pragma unroll
        for (int j = 0; j < 4; ++j) {
            int pr = fq * 4 + j, sw = (pr & 7) << 4;
            #pragma unroll
            for (int ct = 0; ct < 7; ++ct)
                *(unsigned short*)(lds + pbase + pr * 256 + ((ct * 32 + fr * 2) ^ sw)) = f2bf(sv[ct][j] * inv[j]);
            *(unsigned short*)(lds + pbase + pr * 256 + ((224 + fr * 2) ^ sw)) = 0;
        }
        asm volatile("s_waitcnt lgkmcnt(0)" ::: "memory");
        f32x4 oacc[4] = {};
        #pragma unroll
        for (int kt = 0; kt < 4; ++kt) {
            bf16x8 ap = *(const bf16x8*)(lds + pbase + fr * 256 + ((kt * 64 + fq * 16) ^ ((fr & 7) << 4)));
            #pragma unroll
            for (int n = 0; n < 4; ++n) {
                int d = n * 16 + fr, sw = (d & 7) << 4;
                bf16x8 bv = *(const bf16x8*)(lds + VOFF + d * 256 + ((kt * 64 + fq * 16) ^ sw));
                oacc[n] = __builtin_amdgcn_mfma_f32_16x16x32_bf16(ap, bv, oacc[n], 0, 0, 0);
            }
        }
        #pragma unroll
        for (int j = 0; j < 4; ++j) {
            int rg = rg0 + j;
            if (rg < LL) {
                #pragma unroll
                for (int n = 0; n < 4; ++n)
                    qg[(size_t)rg * QKVN + n * 16 + fr] = f2bf(oacc[n][j]);
            }
        }
    }
}

// ------------------------------------------------- residual + layernorm: wave-per-row, 4 rows/block
template<bool RES>
__global__ __launch_bounds__(256) void add_ln(unsigned short* __restrict__ h,
                                              const unsigned short* __restrict__ res,
                                              const float* __restrict__ sc,
                                              const float* __restrict__ bi) {
    const int wv = threadIdx.x >> 6, lane = threadIdx.x & 63;
    const int n = blockIdx.x * 4 + wv;
    unsigned short* hp = h + (size_t)n * DD + lane * 8;
    unsigned int u[4];
    *(uint4*)u = *(const uint4*)hp;
    float x[8];
    #pragma unroll
    for (int e = 0; e < 4; ++e) {
        x[2 * e]     = __uint_as_float(u[e] << 16);
        x[2 * e + 1] = __uint_as_float(u[e] & 0xFFFF0000u);
    }
    if (RES) {
        const unsigned short* rp = res + (size_t)n * DD + lane * 8;
        unsigned int r[4];
        *(uint4*)r = *(const uint4*)rp;
        #pragma unroll
        for (int e = 0; e < 4; ++e) {
            x[2 * e]     += __uint_as_float(r[e] << 16);
            x[2 * e + 1] += __uint_as_float(r[e] & 0xFFFF0000u);
        }
    }
    float s = 0.f, ss = 0.f;
    #pragma unroll
    for (int e = 0; e < 8; ++e) { s += x[e]; ss += x[e] * x[e]; }
    #pragma unroll
    for (int off = 32; off; off >>= 1) {
        s  += __shfl_xor(s, off, 64);
        ss += __shfl_xor(ss, off, 64);
    }
    float mean = s * (1.f / (float)DD);
    float var  = ss * (1.f / (float)DD) - mean * mean;
    float rstd = 1.f / sqrtf(var + 1e-5f);
    float4 s0 = *(const float4*)(sc + lane * 8), s1 = *(const float4*)(sc + lane * 8 + 4);
    float4 b0 = *(const float4*)(bi + lane * 8), b1 = *(const float4*)(bi + lane * 8 + 4);
    float scv[8] = {s0.x, s0.y, s0.z, s0.w, s1.x, s1.y, s1.z, s1.w};
    float biv[8] = {b0.x, b0.y, b0.z, b0.w, b1.x, b1.y, b1.z, b1.w};
    unsigned int o[4];
    #pragma unroll
    for (int e = 0; e < 4; ++e) {
        unsigned short lo = f2bf((x[2 * e]     - mean) * rstd * scv[2 * e]     + biv[2 * e]);
        unsigned short hi = f2bf((x[2 * e + 1] - mean) * rstd * scv[2 * e + 1] + biv[2 * e + 1]);
        o[e] = (unsigned int)lo | ((unsigned int)hi << 16);
    }
    *(uint4*)hp = *(uint4*)o;
}

// ------------------------------------------------- final projection via MFMA
__global__ __launch_bounds__(256) void proj_mfma(const unsigned short* __restrict__ hn,
                                                 const unsigned short* __restrict__ pwb,
                                                 const float* __restrict__ pb,
                                                 float* __restrict__ out) {
    const int tid = threadIdx.x, wv = tid >> 6, lane = tid & 63;
    const int fr = lane & 15, fq = lane >> 4;
    const int row0 = blockIdx.x * 64 + wv * 16;
    const unsigned short* aRow = hn + (size_t)(row0 + fr) * DD + fq * 8;
    f32x4 acc[3] = {};
    #pragma unroll 4
    for (int kt = 0; kt < 16; ++kt) {
        bf16x8 af = *(const bf16x8*)(aRow + kt * 32);
        #pragma unroll
        for (int n = 0; n < 3; ++n) {
            bf16x8 bfv = *(const bf16x8*)(pwb + (size_t)(n * 16 + fr) * DD + kt * 32 + fq * 8);
            acc[n] = __builtin_amdgcn_mfma_f32_16x16x32_bf16(af, bfv, acc[n], 0, 0, 0);
        }
    }
    #pragma unroll
    for (int n = 0; n < 3; ++n) {
        int col = n * 16 + fr;
        if (col < COUT) {
            float bias = pb[col];
            #pragma unroll
            for (int j = 0; j < 4; ++j) {
                int r = row0 + fq * 4 + j;
                out[(size_t)r * COUT + col] = acc[n][j] + bias;
            }
        }
    }
}

__global__ void sentinel_kernel(float* out, int n) {
    int i = blockIdx.x * 256 + threadIdx.x;
    if (i < n) out[i] = 1.0e4f;
}

extern "C" void kernel_launch(void* const* d_in, const int* in_sizes, int n_in,
                              void* d_out, int out_size, void* d_ws, size_t ws_size,
                              hipStream_t stream) {
    const float* x    = (const float*)d_in[0];
    const float* ew   = (const float*)d_in[1];
    const float* Wq   = (const float*)d_in[2];
    const float* bq   = (const float*)d_in[3];
    const float* Wk   = (const float*)d_in[4];
    const float* bk   = (const float*)d_in[5];
    const float* Wv   = (const float*)d_in[6];
    const float* bv   = (const float*)d_in[7];
    const float* Wo   = (const float*)d_in[8];
    const float* bo   = (const float*)d_in[9];
    const float* c1w  = (const float*)d_in[10];
    const float* c1b  = (const float*)d_in[11];
    const float* c2w  = (const float*)d_in[12];
    const float* c2b  = (const float*)d_in[13];
    const float* ln1s = (const float*)d_in[14];
    const float* ln1b = (const float*)d_in[15];
    const float* ln2s = (const float*)d_in[16];
    const float* ln2b = (const float*)d_in[17];
    const float* lnfs = (const float*)d_in[18];
    const float* lnfb = (const float*)d_in[19];
    const float* pw   = (const float*)d_in[20];
    const float* pb   = (const float*)d_in[21];
    const unsigned char* mraw = (const unsigned char*)d_in[22];

    const size_t NB   = (size_t)NTOK * DD;       // 13,107,200
    const size_t PWB  = 48 * DD;
    const size_t EWB  = (size_t)DD * 128;
    const size_t UB   = (size_t)NTOK * 128;
    const size_t need = (5 * NB + 6 * (size_t)WELEM + PWB + EWB + UB) * 2
                      + ((size_t)EE * QKVN + (size_t)LL * DD + (size_t)LL * LL) * 4;
    if (ws_size < need) {
        sentinel_kernel<<<(out_size + 255) / 256, 256, 0, stream>>>((float*)d_out, out_size);
        return;
    }
    unsigned short* h    = (unsigned short*)d_ws;
    unsigned short* qkv  = h + NB;               // 3*NB (QKV out; also FFN-mid scratch)
    unsigned short* t1   = qkv + 3 * NB;         // o-proj / ffn2 output
    unsigned short* wqkv = t1 + NB;              // 3*WELEM packed
    unsigned short* wo   = wqkv + 3 * WELEM;
    unsigned short* w1   = wo + WELEM;
    unsigned short* w2   = w1 + WELEM;
    unsigned short* pwb  = w2 + WELEM;
    unsigned short* ewb  = pwb + PWB;
    unsigned short* ub   = ewb + EWB;
    float* bqkv = (float*)(ub + UB);
    float* pe   = bqkv + EE * QKVN;
    float* mb   = pe + LL * DD;

    pe_kernel<<<(LL * DD + 255) / 256, 256, 0, stream>>>(pe);
    expand_mask_kernel<<<(LL * LL + 255) / 256, 256, 0, stream>>>(mraw, mb);
    cvt6<<<6 * (WELEM / 4) / 256, 256, 0, stream>>>(Wq, Wk, Wv, Wo, c1w, c2w, wqkv, wo, w1, w2);
    pack_bias<<<(EE * QKVN + 255) / 256, 256, 0, stream>>>(bq, bk, bv, bqkv);
    proj_cvt<<<(48 * DD / 4 + 255) / 256, 256, 0, stream>>>(pw, pwb);
    ewb_cvt<<<(DD * 128 + 255) / 256, 256, 0, stream>>>(ew, ewb);
    ub_build<<<(NTOK * 128 + 255) / 256, 256, 0, stream>>>(x, ub);

    // embed as MFMA GEMM: h = ub @ ewb^T + PE  (128^2 kernel, K=128)
    gemm_bf16<2><<<800, 256, 0, stream>>>(ub, ewb, nullptr, pe, h, NTOK, DD, 128, 128, DD, 4);

    for (int l = 0; l < EE; ++l) {
        const size_t wofs = (size_t)l * DD * DD;
        const size_t bof  = (size_t)l * DD;
        // QKV: pipelined 256^2, 600 blocks (T1-chunked), 3-slot ring
        gemm_pipe<0><<<600, 512, 0, stream>>>(h, wqkv + (size_t)l * 3 * DD * DD,
                                              bqkv + l * QKVN, qkv, DD, QKVN, 6);
        attn_mfma<<<BB * HH, 256, 0, stream>>>(qkv, mb);
        // o-proj: 128x256 pipe, 400 blocks, 2 blocks/CU (A = attn-out slice of qkv)
        gemm_pipe2<0><<<400, 512, 0, stream>>>(qkv, wo + wofs, bo + bof, t1, QKVN, DD, 2);
        add_ln<true><<<NTOK / 4, 256, 0, stream>>>(h, t1, ln1s + bof, ln1b + bof);
        // ffn1 + GELU: 128x256 pipe
        gemm_pipe2<1><<<400, 512, 0, stream>>>(h, w1 + wofs, c1b + bof, qkv, DD, DFF, 2);
        // ffn2: 128x256 pipe
        gemm_pipe2<0><<<400, 512, 0, stream>>>(qkv, w2 + wofs, c2b + bof, t1, DFF, DD, 2);
        add_ln<true><<<NTOK / 4, 256, 0, stream>>>(h, t1, ln2s + bof, ln2b + bof);
    }
    add_ln<false><<<NTOK / 4, 256, 0, stream>>>(h, nullptr, lnfs, lnfb);
    proj_mfma<<<NTOK / 64, 256, 0, stream>>>(h, pwb, pb, (float*)d_out);
}

// Round 17
// 580.514 us; speedup vs baseline: 1.3991x; 1.0301x over previous
//
#include <hip/hip_runtime.h>
#include <math.h>

#define BB   256
#define LL   100
#define CIN  38
#define COUT 38
#define DD   512
#define HH   8
#define EE   3
#define DFF  512
#define DHD  64
#define NTOK (BB*LL)     // 25600
#define WELEM (EE*DD*DD) // 786432 elements per weight family
#define QKVN 1536        // packed QKV width

typedef __attribute__((ext_vector_type(8))) short bf16x8;
typedef __attribute__((ext_vector_type(4))) float f32x4;

__device__ __forceinline__ unsigned short f2bf(float f) {
    unsigned int u = __float_as_uint(f);
    unsigned int r = (u + 0x7FFFu + ((u >> 16) & 1u)) >> 16;
    return (unsigned short)r;
}
__device__ __forceinline__ float bf2f(unsigned short s) {
    return __uint_as_float(((unsigned int)s) << 16);
}

__device__ __forceinline__ void gl2lds16(const unsigned short* g, unsigned short* l) {
    __builtin_amdgcn_global_load_lds(
        (const __attribute__((address_space(1))) void*)g,
        (__attribute__((address_space(3))) void*)l, 16, 0, 0);
}

// paired-row XOR swizzle: 16B-unit index for logical (row, chunk c in 0..3) of a [*][32]bf16 tile.
__device__ __forceinline__ int swz(int row, int c) {
    int rp = row >> 1;
    int ch = c + ((row & 1) << 2);
    return rp * 8 + (ch ^ (rp & 7));
}

// ---------------------------------------------------------------- PE table
__global__ __launch_bounds__(256) void pe_kernel(float* __restrict__ pe) {
    int idx = blockIdx.x * 256 + threadIdx.x;
    if (idx >= LL * DD) return;
    int l = idx / DD, d = idx % DD;
    float e = (float)(d & ~1) * (-9.210340371976184f / (float)DD);
    float ang = (float)l * expf(e);
    pe[idx] = (d & 1) ? cosf(ang) : sinf(ang);
}

// ------------------------------------------------- mask -> additive bias
__global__ void expand_mask_kernel(const unsigned char* __restrict__ mraw,
                                   float* __restrict__ mb) {
    int i = blockIdx.x * 256 + threadIdx.x;
    if (i >= LL * LL) return;
    unsigned char b0 = mraw[0], b1 = mraw[1], b2 = mraw[2], b3 = mraw[3];
    bool v;
    if (b0 == 1 && b1 == 1)                      v = mraw[i] != 0;
    else if (b0 == 1 && b1 == 0 && b2 == 0 && b3 == 0)
                                                 v = ((const int*)mraw)[i] != 0;
    else if (b0 == 0x80 && b1 == 0x3F)           v = ((const unsigned short*)mraw)[i] != 0;
    else if (b0 == 0 && b1 == 0x3C)              v = ((const unsigned short*)mraw)[i] != 0;
    else if (b0 == 0 && b1 == 0 && b2 == 0x80 && b3 == 0x3F)
                                                 v = ((const float*)mraw)[i] != 0.f;
    else                                         v = mraw[i] != 0;
    mb[i] = v ? 0.f : -1.0e30f;
}

// ------------------------------------------------- all six weight families -> bf16 (one dispatch)
__global__ __launch_bounds__(256) void cvt6(const float* __restrict__ Wq,
                                            const float* __restrict__ Wk,
                                            const float* __restrict__ Wv,
                                            const float* __restrict__ Wo,
                                            const float* __restrict__ c1w,
                                            const float* __restrict__ c2w,
                                            unsigned short* __restrict__ wqkv,
                                            unsigned short* __restrict__ wo,
                                            unsigned short* __restrict__ w1,
                                            unsigned short* __restrict__ w2) {
    const int Q4 = WELEM / 4;                    // 196608 8B-chunks per family
    int i = blockIdx.x * 256 + threadIdx.x;
    if (i >= 6 * Q4) return;
    int fam = i / Q4, j = i - fam * Q4;
    const float* src = (fam == 0) ? Wq : (fam == 1) ? Wk : (fam == 2) ? Wv
                     : (fam == 3) ? Wo : (fam == 4) ? c1w : c2w;
    float4 f = ((const float4*)src)[j];
    unsigned short o0 = f2bf(f.x), o1 = f2bf(f.y), o2 = f2bf(f.z), o3 = f2bf(f.w);
    unsigned long long packed = (unsigned long long)o0 | ((unsigned long long)o1 << 16)
                              | ((unsigned long long)o2 << 32) | ((unsigned long long)o3 << 48);
    if (fam < 3) {
        int l = j >> 16, jj = j & 65535;         // DD*DD/4 = 65536 chunks per layer
        ((unsigned long long*)wqkv)[(size_t)l * (3 * 65536) + (size_t)fam * 65536 + jj] = packed;
    } else {
        unsigned long long* dst = (fam == 3) ? (unsigned long long*)wo
                                : (fam == 4) ? (unsigned long long*)w1
                                             : (unsigned long long*)w2;
        dst[j] = packed;
    }
}

// ------------------------------------------------- bq/bk/bv -> packed [l][1536] fp32
__global__ __launch_bounds__(256) void pack_bias(const float* __restrict__ bq,
                                                 const float* __restrict__ bk,
                                                 const float* __restrict__ bv,
                                                 float* __restrict__ out) {
    int idx = blockIdx.x * 256 + threadIdx.x;    // EE*1536
    if (idx >= EE * QKVN) return;
    int l = idx / QKVN, r = idx % QKVN, f = r >> 9, d = r & 511;
    const float* src = (f == 0) ? bq : (f == 1) ? bk : bv;
    out[idx] = src[l * DD + d];
}

// ------------------------------------------------- proj weights -> bf16, padded [48][512]
__global__ __launch_bounds__(256) void proj_cvt(const float* __restrict__ in,
                                                unsigned short* __restrict__ outp) {
    int i = blockIdx.x * 256 + threadIdx.x;
    if (i >= 48 * DD / 4) return;
    if (i < COUT * DD / 4) {
        float4 f = ((const float4*)in)[i];
        unsigned short o0 = f2bf(f.x), o1 = f2bf(f.y), o2 = f2bf(f.z), o3 = f2bf(f.w);
        unsigned long long packed = (unsigned long long)o0 | ((unsigned long long)o1 << 16)
                                  | ((unsigned long long)o2 << 32) | ((unsigned long long)o3 << 48);
        ((unsigned long long*)outp)[i] = packed;
    } else {
        ((unsigned long long*)outp)[i] = 0ull;
    }
}

// ------------------------------------------------- emb_w [512][38*3] -> bf16 [512][128] (K-pad)
__global__ __launch_bounds__(256) void ewb_cvt(const float* __restrict__ ew,
                                               unsigned short* __restrict__ out) {
    int idx = blockIdx.x * 256 + threadIdx.x;    // 512*128
    if (idx >= DD * 128) return;
    int d = idx >> 7, k = idx & 127;
    out[idx] = (k < 114) ? f2bf(ew[d * 114 + k]) : (unsigned short)0;
}

// ------------------------------------------------- x -> ub[25600][128] bf16 (circular gather)
__global__ __launch_bounds__(256) void ub_build(const float* __restrict__ x,
                                               unsigned short* __restrict__ ub) {
    int idx = blockIdx.x * 256 + threadIdx.x;    // NTOK*128
    if (idx >= NTOK * 128) return;
    int n = idx >> 7, k = idx & 127;
    float v = 0.f;
    if (k < 114) {
        int c = k / 3, t = k - 3 * c;
        int l = n % LL, b = n / LL;
        int ls = l + t - 1;
        ls = (ls < 0) ? (LL - 1) : (ls >= LL ? ls - LL : ls);
        v = x[(size_t)(b * LL + ls) * CIN + c];
    }
    ub[idx] = f2bf(v);
}

// ------------------------------------------------- bf16 MFMA GEMM (128x128), T1 grid (embed)
template<int EPI>
__global__ __launch_bounds__(256) void gemm_bf16(const unsigned short* __restrict__ A,
                                                 const unsigned short* __restrict__ W,
                                                 const float* __restrict__ bias,
                                                 const float* __restrict__ pe2,
                                                 unsigned short* __restrict__ C,
                                                 int M, int N, int K, int lda, int ldc,
                                                 int nbn) {
    __shared__ unsigned short As[128 * 32];
    __shared__ unsigned short Bs[128 * 32];
    const int tid  = threadIdx.x;
    const int tile = (blockIdx.x & 7) * ((int)gridDim.x >> 3) + (blockIdx.x >> 3);
    const int bn   = tile % nbn, bm = tile / nbn;
    const int w    = tid >> 6, lane = tid & 63;
    const int wr   = w >> 1,  wc   = w & 1;
    const int sRow = tid >> 2;
    const int sK   = (tid & 3) * 8;
    const unsigned short* Ag = A + (size_t)(bm * 128 + sRow) * lda + sK;
    const unsigned short* Wg = W + (size_t)(bn * 128 + sRow) * K + sK;
    unsigned short* AsD = As + tid * 8;
    unsigned short* BsD = Bs + tid * 8;
    const int fr = lane & 15, fq = lane >> 4;
    const int fo = fq * 8;

    f32x4 acc[4][4] = {};
    for (int k0 = 0; k0 < K; k0 += 32) {
        gl2lds16(Ag + k0, AsD);
        gl2lds16(Ag + k0 + (size_t)64 * lda, AsD + 64 * 32);
        gl2lds16(Wg + k0, BsD);
        gl2lds16(Wg + k0 + (size_t)64 * K, BsD + 64 * 32);
        __syncthreads();
        bf16x8 af[4], bfv[4];
        #pragma unroll
        for (int m = 0; m < 4; ++m)
            af[m] = *(const bf16x8*)(As + (wr * 64 + m * 16 + fr) * 32 + fo);
        #pragma unroll
        for (int n = 0; n < 4; ++n)
            bfv[n] = *(const bf16x8*)(Bs + (wc * 64 + n * 16 + fr) * 32 + fo);
        #pragma unroll
        for (int m = 0; m < 4; ++m)
            #pragma unroll
            for (int n = 0; n < 4; ++n)
                acc[m][n] = __builtin_amdgcn_mfma_f32_16x16x32_bf16(af[m], bfv[n], acc[m][n], 0, 0, 0);
        __syncthreads();
    }
    #pragma unroll
    for (int n = 0; n < 4; ++n) {
        int col = bn * 128 + wc * 64 + n * 16 + fr;
        float bv = (EPI != 2) ? bias[col] : 0.f;
        #pragma unroll
        for (int m = 0; m < 4; ++m) {
            #pragma unroll
            for (int j = 0; j < 4; ++j) {
                int row = bm * 128 + wr * 64 + m * 16 + fq * 4 + j;
                float v = acc[m][n][j] + bv;
                if (EPI == 1)
                    v = 0.5f * v * (1.f + erff(v * 0.70710678118654752f));
                if (EPI == 2)
                    v += pe2[(row % LL) * DD + col];
                C[(size_t)row * ldc + col] = f2bf(v);
            }
        }
    }
}

// ------------------------------------------------- pipelined 128x256 GEMM, K=512 (all layer GEMMs)
// r11 ring discipline; 24KB/slot x3 = 72KB -> 2 blocks/CU. 3 loads/K-tile -> vmcnt(3).
// 8 waves (2M x 4N), per-wave 64x64 out, single 16-MFMA phase per K-tile; sector-merged epilogue.
template<int EPI>
__global__ __launch_bounds__(512) void gemm_pipe2(const unsigned short* __restrict__ A,
                                                  const unsigned short* __restrict__ W,
                                                  const float* __restrict__ bias,
                                                  unsigned short* __restrict__ C,
                                                  int lda, int ldc, int nbn) {
    __shared__ __align__(16) unsigned short lds[3 * 12288];   // 72 KB
    const int tid  = threadIdx.x;
    const int tile = ((int)blockIdx.x & 7) * ((int)gridDim.x >> 3) + ((int)blockIdx.x >> 3);
    const int bn   = tile % nbn, bm = tile / nbn;
    const int wid  = tid >> 6, lane = tid & 63;
    const int wr   = wid >> 2, wc = wid & 3;       // 2 x 4
    const int fr   = lane & 15, fq = lane >> 4;

    // staging decode (inverse swizzle): A unit = tid (128 rows); B units = tid, tid+512 (256 rows)
    int rowA, cA, rowB0, cB0, rowB1, cB1;
    { int u = tid;       int rp = u >> 3, q = u & 7, ch = q ^ (rp & 7); rowA  = (rp << 1) + (ch >> 2); cA  = ch & 3; }
    { int u = tid;       int rp = u >> 3, q = u & 7, ch = q ^ (rp & 7); rowB0 = (rp << 1) + (ch >> 2); cB0 = ch & 3; }
    { int u = tid + 512; int rp = u >> 3, q = u & 7, ch = q ^ (rp & 7); rowB1 = (rp << 1) + (ch >> 2); cB1 = ch & 3; }
    const unsigned short* Ag  = A + (size_t)(bm * 128 + rowA)  * lda + cA  * 8;
    const unsigned short* Wg0 = W + (size_t)(bn * 256 + rowB0) * 512 + cB0 * 8;
    const unsigned short* Wg1 = W + (size_t)(bn * 256 + rowB1) * 512 + cB1 * 8;
    unsigned short* dA = lds + tid * 8;            // A region [0,4096); B at +4096 (tid), +8192 (tid+512)

    int aoff[4], boff[4];
    #pragma unroll
    for (int m = 0; m < 4; ++m) aoff[m] = swz(wr * 64 + m * 16 + fr, fq) * 8;
    #pragma unroll
    for (int n = 0; n < 4; ++n) boff[n] = 4096 + swz(wc * 64 + n * 16 + fr, fq) * 8;

    f32x4 acc[4][4] = {};

    // prologue: tiles 0,1 (3 loads each); wait tile0, leave tile1's 3 in flight
    gl2lds16(Ag,       dA);
    gl2lds16(Wg0,      dA + 4096);
    gl2lds16(Wg1,      dA + 8192);
    gl2lds16(Ag  + 32, dA + 12288);
    gl2lds16(Wg0 + 32, dA + 12288 + 4096);
    gl2lds16(Wg1 + 32, dA + 12288 + 8192);
    asm volatile("s_waitcnt vmcnt(3)" ::: "memory");
    __builtin_amdgcn_s_barrier();

    int st = 0;
    for (int t = 0; t < 16; ++t) {
        const unsigned short* S = lds + st * 12288;
        int pt = st + 2; if (pt >= 3) pt -= 3;
        const int koff = (t + 2) * 32;
        bf16x8 bfv[4], af[4];
        #pragma unroll
        for (int n = 0; n < 4; ++n) bfv[n] = *(const bf16x8*)(S + boff[n]);
        #pragma unroll
        for (int m = 0; m < 4; ++m) af[m] = *(const bf16x8*)(S + aoff[m]);
        if (t < 14) {
            gl2lds16(Ag  + koff, dA + pt * 12288);
            gl2lds16(Wg0 + koff, dA + pt * 12288 + 4096);
            gl2lds16(Wg1 + koff, dA + pt * 12288 + 8192);
        }
        __builtin_amdgcn_s_barrier();
        __builtin_amdgcn_s_setprio(1);
        #pragma unroll
        for (int m = 0; m < 4; ++m)
            #pragma unroll
            for (int n = 0; n < 4; ++n)
                acc[m][n] = __builtin_amdgcn_mfma_f32_16x16x32_bf16(af[m], bfv[n], acc[m][n], 0, 0, 0);
        __builtin_amdgcn_s_setprio(0);
        if (t < 14) { asm volatile("s_waitcnt vmcnt(3)" ::: "memory"); }
        else        { asm volatile("s_waitcnt vmcnt(0)" ::: "memory"); }
        __builtin_amdgcn_s_barrier();
        if (++st == 3) st = 0;
    }

    float bvv[4];
    #pragma unroll
    for (int n = 0; n < 4; ++n) bvv[n] = bias[bn * 256 + wc * 64 + n * 16 + fr];
    #pragma unroll
    for (int m = 0; m < 4; ++m) {
        #pragma unroll
        for (int j = 0; j < 4; ++j) {
            int row = bm * 128 + wr * 64 + m * 16 + fq * 4 + j;
            unsigned short* Crow = C + (size_t)row * ldc + bn * 256 + wc * 64 + fr;
            #pragma unroll
            for (int n = 0; n < 4; ++n) {
                float v = acc[m][n][j] + bvv[n];
                if (EPI == 1)
                    v = 0.5f * v * (1.f + erff(v * 0.70710678118654752f));
                Crow[n * 16] = f2bf(v);
            }
        }
    }
}

// ------------------------------------------------- MFMA attention on packed qkv[n][1536]
__global__ __launch_bounds__(256) void attn_mfma(unsigned short* __restrict__ qkv,
                                                 const float* __restrict__ mbias) {
    __shared__ __align__(16) unsigned char lds[47104];
    const int KOFF = 0, VOFF = 14336, POFF = 30720;
    const int tid = threadIdx.x, wv = tid >> 6, lane = tid & 63;
    const int fr = lane & 15, fq = lane >> 4;
    const int b = blockIdx.x >> 3, hh = blockIdx.x & 7;
    unsigned short* qg = qkv + (size_t)(b * LL) * QKVN + hh * DHD;
    const unsigned short* kg = qg + 512;
    const unsigned short* vg = qg + 1024;

    for (int idx = tid; idx < 800; idx += 256) {
        int s = idx >> 3, c = idx & 7;
        uint4 kv = *(const uint4*)(kg + (size_t)s * QKVN + c * 8);
        uint4 vv = *(const uint4*)(vg + (size_t)s * QKVN + c * 8);
        int sw = (s & 7) << 4;
        *(uint4*)(lds + KOFF + s * 128 + ((c * 16) ^ sw)) = kv;
        unsigned int vs[4] = {vv.x, vv.y, vv.z, vv.w};
        #pragma unroll
        for (int e = 0; e < 4; ++e) {
            int d0 = c * 8 + e * 2, d1 = d0 + 1;
            *(unsigned short*)(lds + VOFF + d0 * 256 + ((s * 2) ^ ((d0 & 7) << 4))) = (unsigned short)(vs[e] & 0xFFFFu);
            *(unsigned short*)(lds + VOFF + d1 * 256 + ((s * 2) ^ ((d1 & 7) << 4))) = (unsigned short)(vs[e] >> 16);
        }
    }
    for (int idx = tid; idx < 96; idx += 256) {
        int r = 100 + (idx >> 3), c = idx & 7;
        *(uint4*)(lds + KOFF + r * 128 + ((c * 16) ^ ((r & 7) << 4))) = uint4{0u, 0u, 0u, 0u};
    }
    for (int idx = tid; idx < 896; idx += 256) {
        int d = idx / 14, s = 100 + 2 * (idx % 14);
        *(unsigned int*)(lds + VOFF + d * 256 + ((s * 2) ^ ((d & 7) << 4))) = 0u;
    }
    __syncthreads();

    const int pbase = POFF + wv * 4096;
    for (int bd = wv; bd < 7; bd += 4) {
        const unsigned short* qp = qg + (size_t)(bd * 16 + fr) * QKVN;
        bf16x8 aq0 = *(const bf16x8*)(qp + fq * 8);
        bf16x8 aq1 = *(const bf16x8*)(qp + 32 + fq * 8);
        f32x4 sv[7];
        #pragma unroll
        for (int ct = 0; ct < 7; ++ct) {
            int row = ct * 16 + fr, sw = (row & 7) << 4;
            bf16x8 bk0 = *(const bf16x8*)(lds + KOFF + row * 128 + ((fq * 16) ^ sw));
            bf16x8 bk1 = *(const bf16x8*)(lds + KOFF + row * 128 + ((64 + fq * 16) ^ sw));
            f32x4 a = {0.f, 0.f, 0.f, 0.f};
            a = __builtin_amdgcn_mfma_f32_16x16x32_bf16(aq0, bk0, a, 0, 0, 0);
            a = __builtin_amdgcn_mfma_f32_16x16x32_bf16(aq1, bk1, a, 0, 0, 0);
            sv[ct] = a;
        }
        const int rg0 = bd * 16 + fq * 4;
        #pragma unroll
        for (int ct = 0; ct < 7; ++ct) {
            int col = ct * 16 + fr;
            #pragma unroll
            for (int j = 0; j < 4; ++j) {
                int rg = rg0 + j;
                float bias = (rg < LL && col < LL) ? mbias[rg * LL + col] : -1.0e30f;
                sv[ct][j] = sv[ct][j] * 0.125f + bias;
            }
        }
        float inv[4];
        #pragma unroll
        for (int j = 0; j < 4; ++j) {
            float mx = sv[0][j];
            #pragma unroll
            for (int ct = 1; ct < 7; ++ct) mx = fmaxf(mx, sv[ct][j]);
            #pragma unroll
            for (int off = 8; off; off >>= 1) mx = fmaxf(mx, __shfl_xor(mx, off, 64));
            float sum = 0.f;
            #pragma unroll
            for (int ct = 0; ct < 7; ++ct) {
                float p = __expf(sv[ct][j] - mx);
                sv[ct][j] = p; sum += p;
            }
            #pragma unroll
            for (int off = 8; off; off >>= 1) sum += __shfl_xor(sum, off, 64);
            inv[j] = 1.f / sum;
        }
        asm volatile("s_waitcnt lgkmcnt(0)" ::: "memory");
        #pragma unroll
        for (int j = 0; j < 4; ++j) {
            int pr = fq * 4 + j, sw = (pr & 7) << 4;
            #pragma unroll
            for (int ct = 0; ct < 7; ++ct)
                *(unsigned short*)(lds + pbase + pr * 256 + ((ct * 32 + fr * 2) ^ sw)) = f2bf(sv[ct][j] * inv[j]);
            *(unsigned short*)(lds + pbase + pr * 256 + ((224 + fr * 2) ^ sw)) = 0;
        }
        asm volatile("s_waitcnt lgkmcnt(0)" ::: "memory");
        f32x4 oacc[4] = {};
        #pragma unroll
        for (int kt = 0; kt < 4; ++kt) {
            bf16x8 ap = *(const bf16x8*)(lds + pbase + fr * 256 + ((kt * 64 + fq * 16) ^ ((fr & 7) << 4)));
            #pragma unroll
            for (int n = 0; n < 4; ++n) {
                int d = n * 16 + fr, sw = (d & 7) << 4;
                bf16x8 bv = *(const bf16x8*)(lds + VOFF + d * 256 + ((kt * 64 + fq * 16) ^ sw));
                oacc[n] = __builtin_amdgcn_mfma_f32_16x16x32_bf16(ap, bv, oacc[n], 0, 0, 0);
            }
        }
        #pragma unroll
        for (int j = 0; j < 4; ++j) {
            int rg = rg0 + j;
            if (rg < LL) {
                #pragma unroll
                for (int n = 0; n < 4; ++n)
                    qg[(size_t)rg * QKVN + n * 16 + fr] = f2bf(oacc[n][j]);
            }
        }
    }
}

// ------------------------------------------------- residual + layernorm: wave-per-row, 4 rows/block
template<bool RES>
__global__ __launch_bounds__(256) void add_ln(unsigned short* __restrict__ h,
                                              const unsigned short* __restrict__ res,
                                              const float* __restrict__ sc,
                                              const float* __restrict__ bi) {
    const int wv = threadIdx.x >> 6, lane = threadIdx.x & 63;
    const int n = blockIdx.x * 4 + wv;
    unsigned short* hp = h + (size_t)n * DD + lane * 8;
    unsigned int u[4];
    *(uint4*)u = *(const uint4*)hp;
    float x[8];
    #pragma unroll
    for (int e = 0; e < 4; ++e) {
        x[2 * e]     = __uint_as_float(u[e] << 16);
        x[2 * e + 1] = __uint_as_float(u[e] & 0xFFFF0000u);
    }
    if (RES) {
        const unsigned short* rp = res + (size_t)n * DD + lane * 8;
        unsigned int r[4];
        *(uint4*)r = *(const uint4*)rp;
        #pragma unroll
        for (int e = 0; e < 4; ++e) {
            x[2 * e]     += __uint_as_float(r[e] << 16);
            x[2 * e + 1] += __uint_as_float(r[e] & 0xFFFF0000u);
        }
    }
    float s = 0.f, ss = 0.f;
    #pragma unroll
    for (int e = 0; e < 8; ++e) { s += x[e]; ss += x[e] * x[e]; }
    #pragma unroll
    for (int off = 32; off; off >>= 1) {
        s  += __shfl_xor(s, off, 64);
        ss += __shfl_xor(ss, off, 64);
    }
    float mean = s * (1.f / (float)DD);
    float var  = ss * (1.f / (float)DD) - mean * mean;
    float rstd = 1.f / sqrtf(var + 1e-5f);
    float4 s0 = *(const float4*)(sc + lane * 8), s1 = *(const float4*)(sc + lane * 8 + 4);
    float4 b0 = *(const float4*)(bi + lane * 8), b1 = *(const float4*)(bi + lane * 8 + 4);
    float scv[8] = {s0.x, s0.y, s0.z, s0.w, s1.x, s1.y, s1.z, s1.w};
    float biv[8] = {b0.x, b0.y, b0.z, b0.w, b1.x, b1.y, b1.z, b1.w};
    unsigned int o[4];
    #pragma unroll
    for (int e = 0; e < 4; ++e) {
        unsigned short lo = f2bf((x[2 * e]     - mean) * rstd * scv[2 * e]     + biv[2 * e]);
        unsigned short hi = f2bf((x[2 * e + 1] - mean) * rstd * scv[2 * e + 1] + biv[2 * e + 1]);
        o[e] = (unsigned int)lo | ((unsigned int)hi << 16);
    }
    *(uint4*)hp = *(uint4*)o;
}

// ------------------------------------------------- final projection via MFMA
__global__ __launch_bounds__(256) void proj_mfma(const unsigned short* __restrict__ hn,
                                                 const unsigned short* __restrict__ pwb,
                                                 const float* __restrict__ pb,
                                                 float* __restrict__ out) {
    const int tid = threadIdx.x, wv = tid >> 6, lane = tid & 63;
    const int fr = lane & 15, fq = lane >> 4;
    const int row0 = blockIdx.x * 64 + wv * 16;
    const unsigned short* aRow = hn + (size_t)(row0 + fr) * DD + fq * 8;
    f32x4 acc[3] = {};
    #pragma unroll 4
    for (int kt = 0; kt < 16; ++kt) {
        bf16x8 af = *(const bf16x8*)(aRow + kt * 32);
        #pragma unroll
        for (int n = 0; n < 3; ++n) {
            bf16x8 bfv = *(const bf16x8*)(pwb + (size_t)(n * 16 + fr) * DD + kt * 32 + fq * 8);
            acc[n] = __builtin_amdgcn_mfma_f32_16x16x32_bf16(af, bfv, acc[n], 0, 0, 0);
        }
    }
    #pragma unroll
    for (int n = 0; n < 3; ++n) {
        int col = n * 16 + fr;
        if (col < COUT) {
            float bias = pb[col];
            #pragma unroll
            for (int j = 0; j < 4; ++j) {
                int r = row0 + fq * 4 + j;
                out[(size_t)r * COUT + col] = acc[n][j] + bias;
            }
        }
    }
}

__global__ void sentinel_kernel(float* out, int n) {
    int i = blockIdx.x * 256 + threadIdx.x;
    if (i < n) out[i] = 1.0e4f;
}

extern "C" void kernel_launch(void* const* d_in, const int* in_sizes, int n_in,
                              void* d_out, int out_size, void* d_ws, size_t ws_size,
                              hipStream_t stream) {
    const float* x    = (const float*)d_in[0];
    const float* ew   = (const float*)d_in[1];
    const float* Wq   = (const float*)d_in[2];
    const float* bq   = (const float*)d_in[3];
    const float* Wk   = (const float*)d_in[4];
    const float* bk   = (const float*)d_in[5];
    const float* Wv   = (const float*)d_in[6];
    const float* bv   = (const float*)d_in[7];
    const float* Wo   = (const float*)d_in[8];
    const float* bo   = (const float*)d_in[9];
    const float* c1w  = (const float*)d_in[10];
    const float* c1b  = (const float*)d_in[11];
    const float* c2w  = (const float*)d_in[12];
    const float* c2b  = (const float*)d_in[13];
    const float* ln1s = (const float*)d_in[14];
    const float* ln1b = (const float*)d_in[15];
    const float* ln2s = (const float*)d_in[16];
    const float* ln2b = (const float*)d_in[17];
    const float* lnfs = (const float*)d_in[18];
    const float* lnfb = (const float*)d_in[19];
    const float* pw   = (const float*)d_in[20];
    const float* pb   = (const float*)d_in[21];
    const unsigned char* mraw = (const unsigned char*)d_in[22];

    const size_t NB   = (size_t)NTOK * DD;       // 13,107,200
    const size_t PWB  = 48 * DD;
    const size_t EWB  = (size_t)DD * 128;
    const size_t UB   = (size_t)NTOK * 128;
    const size_t need = (5 * NB + 6 * (size_t)WELEM + PWB + EWB + UB) * 2
                      + ((size_t)EE * QKVN + (size_t)LL * DD + (size_t)LL * LL) * 4;
    if (ws_size < need) {
        sentinel_kernel<<<(out_size + 255) / 256, 256, 0, stream>>>((float*)d_out, out_size);
        return;
    }
    unsigned short* h    = (unsigned short*)d_ws;
    unsigned short* qkv  = h + NB;               // 3*NB (QKV out; also FFN-mid scratch)
    unsigned short* t1   = qkv + 3 * NB;         // o-proj / ffn2 output
    unsigned short* wqkv = t1 + NB;              // 3*WELEM packed
    unsigned short* wo   = wqkv + 3 * WELEM;
    unsigned short* w1   = wo + WELEM;
    unsigned short* w2   = w1 + WELEM;
    unsigned short* pwb  = w2 + WELEM;
    unsigned short* ewb  = pwb + PWB;
    unsigned short* ub   = ewb + EWB;
    float* bqkv = (float*)(ub + UB);
    float* pe   = bqkv + EE * QKVN;
    float* mb   = pe + LL * DD;

    pe_kernel<<<(LL * DD + 255) / 256, 256, 0, stream>>>(pe);
    expand_mask_kernel<<<(LL * LL + 255) / 256, 256, 0, stream>>>(mraw, mb);
    cvt6<<<6 * (WELEM / 4) / 256, 256, 0, stream>>>(Wq, Wk, Wv, Wo, c1w, c2w, wqkv, wo, w1, w2);
    pack_bias<<<(EE * QKVN + 255) / 256, 256, 0, stream>>>(bq, bk, bv, bqkv);
    proj_cvt<<<(48 * DD / 4 + 255) / 256, 256, 0, stream>>>(pw, pwb);
    ewb_cvt<<<(DD * 128 + 255) / 256, 256, 0, stream>>>(ew, ewb);
    ub_build<<<(NTOK * 128 + 255) / 256, 256, 0, stream>>>(x, ub);

    // embed as MFMA GEMM: h = ub @ ewb^T + PE  (128^2 kernel, K=128)
    gemm_bf16<2><<<800, 256, 0, stream>>>(ub, ewb, nullptr, pe, h, NTOK, DD, 128, 128, DD, 4);

    for (int l = 0; l < EE; ++l) {
        const size_t wofs = (size_t)l * DD * DD;
        const size_t bof  = (size_t)l * DD;
        // QKV: 128x256 pipe, 1200 blocks (nbn=6), 2 blocks/CU
        gemm_pipe2<0><<<1200, 512, 0, stream>>>(h, wqkv + (size_t)l * 3 * DD * DD,
                                                bqkv + l * QKVN, qkv, DD, QKVN, 6);
        attn_mfma<<<BB * HH, 256, 0, stream>>>(qkv, mb);
        // o-proj: 128x256 pipe, 400 blocks (A = attn-out slice of qkv)
        gemm_pipe2<0><<<400, 512, 0, stream>>>(qkv, wo + wofs, bo + bof, t1, QKVN, DD, 2);
        add_ln<true><<<NTOK / 4, 256, 0, stream>>>(h, t1, ln1s + bof, ln1b + bof);
        // ffn1 + GELU: 128x256 pipe
        gemm_pipe2<1><<<400, 512, 0, stream>>>(h, w1 + wofs, c1b + bof, qkv, DD, DFF, 2);
        // ffn2: 128x256 pipe
        gemm_pipe2<0><<<400, 512, 0, stream>>>(qkv, w2 + wofs, c2b + bof, t1, DFF, DD, 2);
        add_ln<true><<<NTOK / 4, 256, 0, stream>>>(h, t1, ln2s + bof, ln2b + bof);
    }
    add_ln<false><<<NTOK / 4, 256, 0, stream>>>(h, nullptr, lnfs, lnfb);
    proj_mfma<<<NTOK / 64, 256, 0, stream>>>(h, pwb, pb, (float*)d_out);
}

// Round 18
// 566.970 us; speedup vs baseline: 1.4325x; 1.0239x over previous
//
#include <hip/hip_runtime.h>
#include <math.h>

#define BB   256
#define LL   100
#define CIN  38
#define COUT 38
#define DD   512
#define HH   8
#define EE   3
#define DFF  512
#define DHD  64
#define NTOK (BB*LL)     // 25600
#define WELEM (EE*DD*DD) // 786432 elements per weight family
#define QKVN 1536        // packed QKV width

typedef __attribute__((ext_vector_type(8))) short bf16x8;
typedef __attribute__((ext_vector_type(4))) float f32x4;

__device__ __forceinline__ unsigned short f2bf(float f) {
    unsigned int u = __float_as_uint(f);
    unsigned int r = (u + 0x7FFFu + ((u >> 16) & 1u)) >> 16;
    return (unsigned short)r;
}
__device__ __forceinline__ float bf2f(unsigned short s) {
    return __uint_as_float(((unsigned int)s) << 16);
}

__device__ __forceinline__ void gl2lds16(const unsigned short* g, unsigned short* l) {
    __builtin_amdgcn_global_load_lds(
        (const __attribute__((address_space(1))) void*)g,
        (__attribute__((address_space(3))) void*)l, 16, 0, 0);
}

// paired-row XOR swizzle: 16B-unit index for logical (row, chunk c in 0..3) of a [*][32]bf16 tile.
__device__ __forceinline__ int swz(int row, int c) {
    int rp = row >> 1;
    int ch = c + ((row & 1) << 2);
    return rp * 8 + (ch ^ (rp & 7));
}

// ------------------------------------------------- fused small prep: pe | mask | bias-pack | proj-cvt | ewb-cvt
__global__ __launch_bounds__(256) void prep_small(const float* __restrict__ ew,
                                                  const unsigned char* __restrict__ mraw,
                                                  const float* __restrict__ bq,
                                                  const float* __restrict__ bk,
                                                  const float* __restrict__ bv,
                                                  const float* __restrict__ pw,
                                                  float* __restrict__ pe,
                                                  float* __restrict__ mb,
                                                  float* __restrict__ bqkv,
                                                  unsigned short* __restrict__ pwb,
                                                  unsigned short* __restrict__ ewb) {
    const int blk = blockIdx.x, tid = threadIdx.x;
    if (blk < 200) {                                    // PE table: 51200 elems
        int idx = blk * 256 + tid;
        int l = idx / DD, d = idx % DD;
        float e = (float)(d & ~1) * (-9.210340371976184f / (float)DD);
        float ang = (float)l * expf(e);
        pe[idx] = (d & 1) ? cosf(ang) : sinf(ang);
    } else if (blk < 240) {                             // mask -> bias: 10000
        int i = (blk - 200) * 256 + tid;
        if (i >= LL * LL) return;
        unsigned char b0 = mraw[0], b1 = mraw[1], b2 = mraw[2], b3 = mraw[3];
        bool v;
        if (b0 == 1 && b1 == 1)                      v = mraw[i] != 0;
        else if (b0 == 1 && b1 == 0 && b2 == 0 && b3 == 0)
                                                     v = ((const int*)mraw)[i] != 0;
        else if (b0 == 0x80 && b1 == 0x3F)           v = ((const unsigned short*)mraw)[i] != 0;
        else if (b0 == 0 && b1 == 0x3C)              v = ((const unsigned short*)mraw)[i] != 0;
        else if (b0 == 0 && b1 == 0 && b2 == 0x80 && b3 == 0x3F)
                                                     v = ((const float*)mraw)[i] != 0.f;
        else                                         v = mraw[i] != 0;
        mb[i] = v ? 0.f : -1.0e30f;
    } else if (blk < 258) {                             // bias pack: 4608
        int idx = (blk - 240) * 256 + tid;
        int l = idx / QKVN, r = idx % QKVN, f = r >> 9, d = r & 511;
        const float* src = (f == 0) ? bq : (f == 1) ? bk : bv;
        bqkv[idx] = src[l * DD + d];
    } else if (blk < 282) {                             // proj weights: 6144 chunks
        int i = (blk - 258) * 256 + tid;
        if (i < COUT * DD / 4) {
            float4 f = ((const float4*)pw)[i];
            unsigned short o0 = f2bf(f.x), o1 = f2bf(f.y), o2 = f2bf(f.z), o3 = f2bf(f.w);
            unsigned long long packed = (unsigned long long)o0 | ((unsigned long long)o1 << 16)
                                      | ((unsigned long long)o2 << 32) | ((unsigned long long)o3 << 48);
            ((unsigned long long*)pwb)[i] = packed;
        } else {
            ((unsigned long long*)pwb)[i] = 0ull;
        }
    } else {                                            // ewb: 65536 elems
        int idx = (blk - 282) * 256 + tid;
        int d = idx >> 7, k = idx & 127;
        ewb[idx] = (k < 114) ? f2bf(ew[d * 114 + k]) : (unsigned short)0;
    }
}

// ------------------------------------------------- all six weight families -> bf16 (one dispatch)
__global__ __launch_bounds__(256) void cvt6(const float* __restrict__ Wq,
                                            const float* __restrict__ Wk,
                                            const float* __restrict__ Wv,
                                            const float* __restrict__ Wo,
                                            const float* __restrict__ c1w,
                                            const float* __restrict__ c2w,
                                            unsigned short* __restrict__ wqkv,
                                            unsigned short* __restrict__ wo,
                                            unsigned short* __restrict__ w1,
                                            unsigned short* __restrict__ w2) {
    const int Q4 = WELEM / 4;                    // 196608 8B-chunks per family
    int i = blockIdx.x * 256 + threadIdx.x;
    if (i >= 6 * Q4) return;
    int fam = i / Q4, j = i - fam * Q4;
    const float* src = (fam == 0) ? Wq : (fam == 1) ? Wk : (fam == 2) ? Wv
                     : (fam == 3) ? Wo : (fam == 4) ? c1w : c2w;
    float4 f = ((const float4*)src)[j];
    unsigned short o0 = f2bf(f.x), o1 = f2bf(f.y), o2 = f2bf(f.z), o3 = f2bf(f.w);
    unsigned long long packed = (unsigned long long)o0 | ((unsigned long long)o1 << 16)
                              | ((unsigned long long)o2 << 32) | ((unsigned long long)o3 << 48);
    if (fam < 3) {
        int l = j >> 16, jj = j & 65535;         // DD*DD/4 = 65536 chunks per layer
        ((unsigned long long*)wqkv)[(size_t)l * (3 * 65536) + (size_t)fam * 65536 + jj] = packed;
    } else {
        unsigned long long* dst = (fam == 3) ? (unsigned long long*)wo
                                : (fam == 4) ? (unsigned long long*)w1
                                             : (unsigned long long*)w2;
        dst[j] = packed;
    }
}

// ------------------------------------------------- x -> ub[25600][128] bf16 (circular gather)
__global__ __launch_bounds__(256) void ub_build(const float* __restrict__ x,
                                               unsigned short* __restrict__ ub) {
    int idx = blockIdx.x * 256 + threadIdx.x;    // NTOK*128
    if (idx >= NTOK * 128) return;
    int n = idx >> 7, k = idx & 127;
    float v = 0.f;
    if (k < 114) {
        int c = k / 3, t = k - 3 * c;
        int l = n % LL, b = n / LL;
        int ls = l + t - 1;
        ls = (ls < 0) ? (LL - 1) : (ls >= LL ? ls - LL : ls);
        v = x[(size_t)(b * LL + ls) * CIN + c];
    }
    ub[idx] = f2bf(v);
}

// ------------------------------------------------- bf16 MFMA GEMM (128x128), T1 grid (embed)
template<int EPI>
__global__ __launch_bounds__(256) void gemm_bf16(const unsigned short* __restrict__ A,
                                                 const unsigned short* __restrict__ W,
                                                 const float* __restrict__ bias,
                                                 const float* __restrict__ pe2,
                                                 unsigned short* __restrict__ C,
                                                 int M, int N, int K, int lda, int ldc,
                                                 int nbn) {
    __shared__ unsigned short As[128 * 32];
    __shared__ unsigned short Bs[128 * 32];
    const int tid  = threadIdx.x;
    const int tile = (blockIdx.x & 7) * ((int)gridDim.x >> 3) + (blockIdx.x >> 3);
    const int bn   = tile % nbn, bm = tile / nbn;
    const int w    = tid >> 6, lane = tid & 63;
    const int wr   = w >> 1,  wc   = w & 1;
    const int sRow = tid >> 2;
    const int sK   = (tid & 3) * 8;
    const unsigned short* Ag = A + (size_t)(bm * 128 + sRow) * lda + sK;
    const unsigned short* Wg = W + (size_t)(bn * 128 + sRow) * K + sK;
    unsigned short* AsD = As + tid * 8;
    unsigned short* BsD = Bs + tid * 8;
    const int fr = lane & 15, fq = lane >> 4;
    const int fo = fq * 8;

    f32x4 acc[4][4] = {};
    for (int k0 = 0; k0 < K; k0 += 32) {
        gl2lds16(Ag + k0, AsD);
        gl2lds16(Ag + k0 + (size_t)64 * lda, AsD + 64 * 32);
        gl2lds16(Wg + k0, BsD);
        gl2lds16(Wg + k0 + (size_t)64 * K, BsD + 64 * 32);
        __syncthreads();
        bf16x8 af[4], bfv[4];
        #pragma unroll
        for (int m = 0; m < 4; ++m)
            af[m] = *(const bf16x8*)(As + (wr * 64 + m * 16 + fr) * 32 + fo);
        #pragma unroll
        for (int n = 0; n < 4; ++n)
            bfv[n] = *(const bf16x8*)(Bs + (wc * 64 + n * 16 + fr) * 32 + fo);
        #pragma unroll
        for (int m = 0; m < 4; ++m)
            #pragma unroll
            for (int n = 0; n < 4; ++n)
                acc[m][n] = __builtin_amdgcn_mfma_f32_16x16x32_bf16(af[m], bfv[n], acc[m][n], 0, 0, 0);
        __syncthreads();
    }
    #pragma unroll
    for (int n = 0; n < 4; ++n) {
        int col = bn * 128 + wc * 64 + n * 16 + fr;
        float bv = (EPI != 2) ? bias[col] : 0.f;
        #pragma unroll
        for (int m = 0; m < 4; ++m) {
            #pragma unroll
            for (int j = 0; j < 4; ++j) {
                int row = bm * 128 + wr * 64 + m * 16 + fq * 4 + j;
                float v = acc[m][n][j] + bv;
                if (EPI == 1)
                    v = 0.5f * v * (1.f + erff(v * 0.70710678118654752f));
                if (EPI == 2)
                    v += pe2[(row % LL) * DD + col];
                C[(size_t)row * ldc + col] = f2bf(v);
            }
        }
    }
}

// ------------------------------------------------- pipelined 128x256 GEMM, K=512 (all layer GEMMs)
template<int EPI>
__global__ __launch_bounds__(512) void gemm_pipe2(const unsigned short* __restrict__ A,
                                                  const unsigned short* __restrict__ W,
                                                  const float* __restrict__ bias,
                                                  unsigned short* __restrict__ C,
                                                  int lda, int ldc, int nbn) {
    __shared__ __align__(16) unsigned short lds[3 * 12288];   // 72 KB
    const int tid  = threadIdx.x;
    const int tile = ((int)blockIdx.x & 7) * ((int)gridDim.x >> 3) + ((int)blockIdx.x >> 3);
    const int bn   = tile % nbn, bm = tile / nbn;
    const int wid  = tid >> 6, lane = tid & 63;
    const int wr   = wid >> 2, wc = wid & 3;       // 2 x 4
    const int fr   = lane & 15, fq = lane >> 4;

    int rowA, cA, rowB0, cB0, rowB1, cB1;
    { int u = tid;       int rp = u >> 3, q = u & 7, ch = q ^ (rp & 7); rowA  = (rp << 1) + (ch >> 2); cA  = ch & 3; }
    { int u = tid;       int rp = u >> 3, q = u & 7, ch = q ^ (rp & 7); rowB0 = (rp << 1) + (ch >> 2); cB0 = ch & 3; }
    { int u = tid + 512; int rp = u >> 3, q = u & 7, ch = q ^ (rp & 7); rowB1 = (rp << 1) + (ch >> 2); cB1 = ch & 3; }
    const unsigned short* Ag  = A + (size_t)(bm * 128 + rowA)  * lda + cA  * 8;
    const unsigned short* Wg0 = W + (size_t)(bn * 256 + rowB0) * 512 + cB0 * 8;
    const unsigned short* Wg1 = W + (size_t)(bn * 256 + rowB1) * 512 + cB1 * 8;
    unsigned short* dA = lds + tid * 8;

    int aoff[4], boff[4];
    #pragma unroll
    for (int m = 0; m < 4; ++m) aoff[m] = swz(wr * 64 + m * 16 + fr, fq) * 8;
    #pragma unroll
    for (int n = 0; n < 4; ++n) boff[n] = 4096 + swz(wc * 64 + n * 16 + fr, fq) * 8;

    f32x4 acc[4][4] = {};

    gl2lds16(Ag,       dA);
    gl2lds16(Wg0,      dA + 4096);
    gl2lds16(Wg1,      dA + 8192);
    gl2lds16(Ag  + 32, dA + 12288);
    gl2lds16(Wg0 + 32, dA + 12288 + 4096);
    gl2lds16(Wg1 + 32, dA + 12288 + 8192);
    asm volatile("s_waitcnt vmcnt(3)" ::: "memory");
    __builtin_amdgcn_s_barrier();

    int st = 0;
    for (int t = 0; t < 16; ++t) {
        const unsigned short* S = lds + st * 12288;
        int pt = st + 2; if (pt >= 3) pt -= 3;
        const int koff = (t + 2) * 32;
        bf16x8 bfv[4], af[4];
        #pragma unroll
        for (int n = 0; n < 4; ++n) bfv[n] = *(const bf16x8*)(S + boff[n]);
        #pragma unroll
        for (int m = 0; m < 4; ++m) af[m] = *(const bf16x8*)(S + aoff[m]);
        if (t < 14) {
            gl2lds16(Ag  + koff, dA + pt * 12288);
            gl2lds16(Wg0 + koff, dA + pt * 12288 + 4096);
            gl2lds16(Wg1 + koff, dA + pt * 12288 + 8192);
        }
        __builtin_amdgcn_s_barrier();
        __builtin_amdgcn_s_setprio(1);
        #pragma unroll
        for (int m = 0; m < 4; ++m)
            #pragma unroll
            for (int n = 0; n < 4; ++n)
                acc[m][n] = __builtin_amdgcn_mfma_f32_16x16x32_bf16(af[m], bfv[n], acc[m][n], 0, 0, 0);
        __builtin_amdgcn_s_setprio(0);
        if (t < 14) { asm volatile("s_waitcnt vmcnt(3)" ::: "memory"); }
        else        { asm volatile("s_waitcnt vmcnt(0)" ::: "memory"); }
        __builtin_amdgcn_s_barrier();
        if (++st == 3) st = 0;
    }

    float bvv[4];
    #pragma unroll
    for (int n = 0; n < 4; ++n) bvv[n] = bias[bn * 256 + wc * 64 + n * 16 + fr];
    #pragma unroll
    for (int m = 0; m < 4; ++m) {
        #pragma unroll
        for (int j = 0; j < 4; ++j) {
            int row = bm * 128 + wr * 64 + m * 16 + fq * 4 + j;
            unsigned short* Crow = C + (size_t)row * ldc + bn * 256 + wc * 64 + fr;
            #pragma unroll
            for (int n = 0; n < 4; ++n) {
                float v = acc[m][n][j] + bvv[n];
                if (EPI == 1)
                    v = 0.5f * v * (1.f + erff(v * 0.70710678118654752f));
                Crow[n * 16] = f2bf(v);
            }
        }
    }
}

// ------------------------------------------------- MFMA attention on packed qkv[n][1536]
__global__ __launch_bounds__(256) void attn_mfma(unsigned short* __restrict__ qkv,
                                                 const float* __restrict__ mbias) {
    __shared__ __align__(16) unsigned char lds[47104];
    const int KOFF = 0, VOFF = 14336, POFF = 30720;
    const int tid = threadIdx.x, wv = tid >> 6, lane = tid & 63;
    const int fr = lane & 15, fq = lane >> 4;
    const int b = blockIdx.x >> 3, hh = blockIdx.x & 7;
    unsigned short* qg = qkv + (size_t)(b * LL) * QKVN + hh * DHD;
    const unsigned short* kg = qg + 512;
    const unsigned short* vg = qg + 1024;

    for (int idx = tid; idx < 800; idx += 256) {
        int s = idx >> 3, c = idx & 7;
        uint4 kv = *(const uint4*)(kg + (size_t)s * QKVN + c * 8);
        uint4 vv = *(const uint4*)(vg + (size_t)s * QKVN + c * 8);
        int sw = (s & 7) << 4;
        *(uint4*)(lds + KOFF + s * 128 + ((c * 16) ^ sw)) = kv;
        unsigned int vs[4] = {vv.x, vv.y, vv.z, vv.w};
        #pragma unroll
        for (int e = 0; e < 4; ++e) {
            int d0 = c * 8 + e * 2, d1 = d0 + 1;
            *(unsigned short*)(lds + VOFF + d0 * 256 + ((s * 2) ^ ((d0 & 7) << 4))) = (unsigned short)(vs[e] & 0xFFFFu);
            *(unsigned short*)(lds + VOFF + d1 * 256 + ((s * 2) ^ ((d1 & 7) << 4))) = (unsigned short)(vs[e] >> 16);
        }
    }
    for (int idx = tid; idx < 96; idx += 256) {
        int r = 100 + (idx >> 3), c = idx & 7;
        *(uint4*)(lds + KOFF + r * 128 + ((c * 16) ^ ((r & 7) << 4))) = uint4{0u, 0u, 0u, 0u};
    }
    for (int idx = tid; idx < 896; idx += 256) {
        int d = idx / 14, s = 100 + 2 * (idx % 14);
        *(unsigned int*)(lds + VOFF + d * 256 + ((s * 2) ^ ((d & 7) << 4))) = 0u;
    }
    __syncthreads();

    const int pbase = POFF + wv * 4096;
    for (int bd = wv; bd < 7; bd += 4) {
        const unsigned short* qp = qg + (size_t)(bd * 16 + fr) * QKVN;
        bf16x8 aq0 = *(const bf16x8*)(qp + fq * 8);
        bf16x8 aq1 = *(const bf16x8*)(qp + 32 + fq * 8);
        f32x4 sv[7];
        #pragma unroll
        for (int ct = 0; ct < 7; ++ct) {
            int row = ct * 16 + fr, sw = (row & 7) << 4;
            bf16x8 bk0 = *(const bf16x8*)(lds + KOFF + row * 128 + ((fq * 16) ^ sw));
            bf16x8 bk1 = *(const bf16x8*)(lds + KOFF + row * 128 + ((64 + fq * 16) ^ sw));
            f32x4 a = {0.f, 0.f, 0.f, 0.f};
            a = __builtin_amdgcn_mfma_f32_16x16x32_bf16(aq0, bk0, a, 0, 0, 0);
            a = __builtin_amdgcn_mfma_f32_16x16x32_bf16(aq1, bk1, a, 0, 0, 0);
            sv[ct] = a;
        }
        const int rg0 = bd * 16 + fq * 4;
        #pragma unroll
        for (int ct = 0; ct < 7; ++ct) {
            int col = ct * 16 + fr;
            #pragma unroll
            for (int j = 0; j < 4; ++j) {
                int rg = rg0 + j;
                float bias = (rg < LL && col < LL) ? mbias[rg * LL + col] : -1.0e30f;
                sv[ct][j] = sv[ct][j] * 0.125f + bias;
            }
        }
        float inv[4];
        #pragma unroll
        for (int j = 0; j < 4; ++j) {
            float mx = sv[0][j];
            #pragma unroll
            for (int ct = 1; ct < 7; ++ct) mx = fmaxf(mx, sv[ct][j]);
            #pragma unroll
            for (int off = 8; off; off >>= 1) mx = fmaxf(mx, __shfl_xor(mx, off, 64));
            float sum = 0.f;
            #pragma unroll
            for (int ct = 0; ct < 7; ++ct) {
                float p = __expf(sv[ct][j] - mx);
                sv[ct][j] = p; sum += p;
            }
            #pragma unroll
            for (int off = 8; off; off >>= 1) sum += __shfl_xor(sum, off, 64);
            inv[j] = 1.f / sum;
        }
        asm volatile("s_waitcnt lgkmcnt(0)" ::: "memory");
        #pragma unroll
        for (int j = 0; j < 4; ++j) {
            int pr = fq * 4 + j, sw = (pr & 7) << 4;
            #pragma unroll
            for (int ct = 0; ct < 7; ++ct)
                *(unsigned short*)(lds + pbase + pr * 256 + ((ct * 32 + fr * 2) ^ sw)) = f2bf(sv[ct][j] * inv[j]);
            *(unsigned short*)(lds + pbase + pr * 256 + ((224 + fr * 2) ^ sw)) = 0;
        }
        asm volatile("s_waitcnt lgkmcnt(0)" ::: "memory");
        f32x4 oacc[4] = {};
        #pragma unroll
        for (int kt = 0; kt < 4; ++kt) {
            bf16x8 ap = *(const bf16x8*)(lds + pbase + fr * 256 + ((kt * 64 + fq * 16) ^ ((fr & 7) << 4)));
            #pragma unroll
            for (int n = 0; n < 4; ++n) {
                int d = n * 16 + fr, sw = (d & 7) << 4;
                bf16x8 bv = *(const bf16x8*)(lds + VOFF + d * 256 + ((kt * 64 + fq * 16) ^ sw));
                oacc[n] = __builtin_amdgcn_mfma_f32_16x16x32_bf16(ap, bv, oacc[n], 0, 0, 0);
            }
        }
        #pragma unroll
        for (int j = 0; j < 4; ++j) {
            int rg = rg0 + j;
            if (rg < LL) {
                #pragma unroll
                for (int n = 0; n < 4; ++n)
                    qg[(size_t)rg * QKVN + n * 16 + fr] = f2bf(oacc[n][j]);
            }
        }
    }
}

// ------------------------------------------------- residual + layernorm: wave-per-row, 4 rows/block
template<bool RES>
__global__ __launch_bounds__(256) void add_ln(unsigned short* __restrict__ h,
                                              const unsigned short* __restrict__ res,
                                              const float* __restrict__ sc,
                                              const float* __restrict__ bi) {
    const int wv = threadIdx.x >> 6, lane = threadIdx.x & 63;
    const int n = blockIdx.x * 4 + wv;
    unsigned short* hp = h + (size_t)n * DD + lane * 8;
    unsigned int u[4];
    *(uint4*)u = *(const uint4*)hp;
    float x[8];
    #pragma unroll
    for (int e = 0; e < 4; ++e) {
        x[2 * e]     = __uint_as_float(u[e] << 16);
        x[2 * e + 1] = __uint_as_float(u[e] & 0xFFFF0000u);
    }
    if (RES) {
        const unsigned short* rp = res + (size_t)n * DD + lane * 8;
        unsigned int r[4];
        *(uint4*)r = *(const uint4*)rp;
        #pragma unroll
        for (int e = 0; e < 4; ++e) {
            x[2 * e]     += __uint_as_float(r[e] << 16);
            x[2 * e + 1] += __uint_as_float(r[e] & 0xFFFF0000u);
        }
    }
    float s = 0.f, ss = 0.f;
    #pragma unroll
    for (int e = 0; e < 8; ++e) { s += x[e]; ss += x[e] * x[e]; }
    #pragma unroll
    for (int off = 32; off; off >>= 1) {
        s  += __shfl_xor(s, off, 64);
        ss += __shfl_xor(ss, off, 64);
    }
    float mean = s * (1.f / (float)DD);
    float var  = ss * (1.f / (float)DD) - mean * mean;
    float rstd = 1.f / sqrtf(var + 1e-5f);
    float4 s0 = *(const float4*)(sc + lane * 8), s1 = *(const float4*)(sc + lane * 8 + 4);
    float4 b0 = *(const float4*)(bi + lane * 8), b1 = *(const float4*)(bi + lane * 8 + 4);
    float scv[8] = {s0.x, s0.y, s0.z, s0.w, s1.x, s1.y, s1.z, s1.w};
    float biv[8] = {b0.x, b0.y, b0.z, b0.w, b1.x, b1.y, b1.z, b1.w};
    unsigned int o[4];
    #pragma unroll
    for (int e = 0; e < 4; ++e) {
        unsigned short lo = f2bf((x[2 * e]     - mean) * rstd * scv[2 * e]     + biv[2 * e]);
        unsigned short hi = f2bf((x[2 * e + 1] - mean) * rstd * scv[2 * e + 1] + biv[2 * e + 1]);
        o[e] = (unsigned int)lo | ((unsigned int)hi << 16);
    }
    *(uint4*)hp = *(uint4*)o;
}

// ------------------------------------------------- final LN + projection, fused
// wave handles 16 rows; row stats via per-lane partials + shfl_xor over the 4 fq-lanes.
__global__ __launch_bounds__(256) void proj_ln_mfma(const unsigned short* __restrict__ hn,
                                                    const float* __restrict__ lns,
                                                    const float* __restrict__ lnb,
                                                    const unsigned short* __restrict__ pwb,
                                                    const float* __restrict__ pb,
                                                    float* __restrict__ out) {
    const int tid = threadIdx.x, wv = tid >> 6, lane = tid & 63;
    const int fr = lane & 15, fq = lane >> 4;
    const int row0 = blockIdx.x * 64 + wv * 16;
    const unsigned short* aRow = hn + (size_t)(row0 + fr) * DD + fq * 8;

    // pass 1: load this lane's 16 fragments (its row's cols kt*32 + fq*8 .. +8), partial stats
    bf16x8 araw[16];
    float s = 0.f, ss = 0.f;
    #pragma unroll
    for (int kt = 0; kt < 16; ++kt) {
        araw[kt] = *(const bf16x8*)(aRow + kt * 32);
        #pragma unroll
        for (int e = 0; e < 8; ++e) {
            float v = bf2f((unsigned short)araw[kt][e]);
            s += v; ss += v * v;
        }
    }
    // reduce across the 4 fq-lanes of this row (lanes fr, fr+16, fr+32, fr+48)
    s  += __shfl_xor(s, 16, 64);  s  += __shfl_xor(s, 32, 64);
    ss += __shfl_xor(ss, 16, 64); ss += __shfl_xor(ss, 32, 64);
    float mean = s * (1.f / (float)DD);
    float var  = ss * (1.f / (float)DD) - mean * mean;
    float rstd = 1.f / sqrtf(var + 1e-5f);

    // pass 2: normalize in-register and MFMA against proj weights
    f32x4 acc[3] = {};
    #pragma unroll
    for (int kt = 0; kt < 16; ++kt) {
        int c0 = kt * 32 + fq * 8;
        float4 l0 = *(const float4*)(lns + c0), l1 = *(const float4*)(lns + c0 + 4);
        float4 g0 = *(const float4*)(lnb + c0), g1 = *(const float4*)(lnb + c0 + 4);
        float scv[8] = {l0.x, l0.y, l0.z, l0.w, l1.x, l1.y, l1.z, l1.w};
        float biv[8] = {g0.x, g0.y, g0.z, g0.w, g1.x, g1.y, g1.z, g1.w};
        bf16x8 af;
        #pragma unroll
        for (int e = 0; e < 8; ++e) {
            float v = (bf2f((unsigned short)araw[kt][e]) - mean) * rstd * scv[e] + biv[e];
            af[e] = (short)f2bf(v);
        }
        #pragma unroll
        for (int n = 0; n < 3; ++n) {
            bf16x8 bfv = *(const bf16x8*)(pwb + (size_t)(n * 16 + fr) * DD + kt * 32 + fq * 8);
            acc[n] = __builtin_amdgcn_mfma_f32_16x16x32_bf16(af, bfv, acc[n], 0, 0, 0);
        }
    }
    #pragma unroll
    for (int n = 0; n < 3; ++n) {
        int col = n * 16 + fr;
        if (col < COUT) {
            float bias = pb[col];
            #pragma unroll
            for (int j = 0; j < 4; ++j) {
                int r = row0 + fq * 4 + j;
                out[(size_t)r * COUT + col] = acc[n][j] + bias;
            }
        }
    }
}

__global__ void sentinel_kernel(float* out, int n) {
    int i = blockIdx.x * 256 + threadIdx.x;
    if (i < n) out[i] = 1.0e4f;
}

extern "C" void kernel_launch(void* const* d_in, const int* in_sizes, int n_in,
                              void* d_out, int out_size, void* d_ws, size_t ws_size,
                              hipStream_t stream) {
    const float* x    = (const float*)d_in[0];
    const float* ew   = (const float*)d_in[1];
    const float* Wq   = (const float*)d_in[2];
    const float* bq   = (const float*)d_in[3];
    const float* Wk   = (const float*)d_in[4];
    const float* bk   = (const float*)d_in[5];
    const float* Wv   = (const float*)d_in[6];
    const float* bv   = (const float*)d_in[7];
    const float* Wo   = (const float*)d_in[8];
    const float* bo   = (const float*)d_in[9];
    const float* c1w  = (const float*)d_in[10];
    const float* c1b  = (const float*)d_in[11];
    const float* c2w  = (const float*)d_in[12];
    const float* c2b  = (const float*)d_in[13];
    const float* ln1s = (const float*)d_in[14];
    const float* ln1b = (const float*)d_in[15];
    const float* ln2s = (const float*)d_in[16];
    const float* ln2b = (const float*)d_in[17];
    const float* lnfs = (const float*)d_in[18];
    const float* lnfb = (const float*)d_in[19];
    const float* pw   = (const float*)d_in[20];
    const float* pb   = (const float*)d_in[21];
    const unsigned char* mraw = (const unsigned char*)d_in[22];

    const size_t NB   = (size_t)NTOK * DD;       // 13,107,200
    const size_t PWB  = 48 * DD;
    const size_t EWB  = (size_t)DD * 128;
    const size_t UB   = (size_t)NTOK * 128;
    const size_t need = (5 * NB + 6 * (size_t)WELEM + PWB + EWB + UB) * 2
                      + ((size_t)EE * QKVN + (size_t)LL * DD + (size_t)LL * LL) * 4;
    if (ws_size < need) {
        sentinel_kernel<<<(out_size + 255) / 256, 256, 0, stream>>>((float*)d_out, out_size);
        return;
    }
    unsigned short* h    = (unsigned short*)d_ws;
    unsigned short* qkv  = h + NB;               // 3*NB (QKV out; also FFN-mid scratch)
    unsigned short* t1   = qkv + 3 * NB;         // o-proj / ffn2 output
    unsigned short* wqkv = t1 + NB;              // 3*WELEM packed
    unsigned short* wo   = wqkv + 3 * WELEM;
    unsigned short* w1   = wo + WELEM;
    unsigned short* w2   = w1 + WELEM;
    unsigned short* pwb  = w2 + WELEM;
    unsigned short* ewb  = pwb + PWB;
    unsigned short* ub   = ewb + EWB;
    float* bqkv = (float*)(ub + UB);
    float* pe   = bqkv + EE * QKVN;
    float* mb   = pe + LL * DD;

    prep_small<<<538, 256, 0, stream>>>(ew, mraw, bq, bk, bv, pw, pe, mb, bqkv, pwb, ewb);
    cvt6<<<6 * (WELEM / 4) / 256, 256, 0, stream>>>(Wq, Wk, Wv, Wo, c1w, c2w, wqkv, wo, w1, w2);
    ub_build<<<(NTOK * 128 + 255) / 256, 256, 0, stream>>>(x, ub);

    // embed as MFMA GEMM: h = ub @ ewb^T + PE  (128^2 kernel, K=128)
    gemm_bf16<2><<<800, 256, 0, stream>>>(ub, ewb, nullptr, pe, h, NTOK, DD, 128, 128, DD, 4);

    for (int l = 0; l < EE; ++l) {
        const size_t wofs = (size_t)l * DD * DD;
        const size_t bof  = (size_t)l * DD;
        // QKV: 128x256 pipe, 1200 blocks (nbn=6), 2 blocks/CU
        gemm_pipe2<0><<<1200, 512, 0, stream>>>(h, wqkv + (size_t)l * 3 * DD * DD,
                                                bqkv + l * QKVN, qkv, DD, QKVN, 6);
        attn_mfma<<<BB * HH, 256, 0, stream>>>(qkv, mb);
        // o-proj: 128x256 pipe, 400 blocks (A = attn-out slice of qkv)
        gemm_pipe2<0><<<400, 512, 0, stream>>>(qkv, wo + wofs, bo + bof, t1, QKVN, DD, 2);
        add_ln<true><<<NTOK / 4, 256, 0, stream>>>(h, t1, ln1s + bof, ln1b + bof);
        // ffn1 + GELU: 128x256 pipe
        gemm_pipe2<1><<<400, 512, 0, stream>>>(h, w1 + wofs, c1b + bof, qkv, DD, DFF, 2);
        // ffn2: 128x256 pipe
        gemm_pipe2<0><<<400, 512, 0, stream>>>(qkv, w2 + wofs, c2b + bof, t1, DFF, DD, 2);
        add_ln<true><<<NTOK / 4, 256, 0, stream>>>(h, t1, ln2s + bof, ln2b + bof);
    }
    // final LN fused into the projection
    proj_ln_mfma<<<NTOK / 64, 256, 0, stream>>>(h, lnfs, lnfb, pwb, pb, (float*)d_out);
}